// Round 1
// baseline (956.314 us; speedup 1.0000x reference)
//
#include <hip/hip_runtime.h>
#include <hip/hip_bf16.h>

typedef __hip_bfloat16 bf16_t;
typedef __attribute__((ext_vector_type(8))) short bfrag8;   // 8 bf16 (4 VGPRs)
typedef __attribute__((ext_vector_type(4))) float floatx4;  // MFMA acc

#define DM     1024
#define DI     2048
#define NHD    32
#define HD     64
#define DSTATE 128
#define CONVD  2304
#define NPROJ  4384
#define NPAD   4480
#define MR     4096      // B*L
#define LL     2048
#define EPSF   1e-5f

// ---------------- async global->LDS 16B ----------------
__device__ __forceinline__ void gl_lds16(const void* g, void* l) {
  __builtin_amdgcn_global_load_lds((const __attribute__((address_space(1))) void*)g,
                                   (__attribute__((address_space(3))) void*)l, 16, 0, 0);
}

__device__ __forceinline__ unsigned pack_bf16_rn(float a, float b) {
  unsigned ua = (__float_as_uint(a) + 0x8000u) >> 16;
  unsigned ub = (__float_as_uint(b) + 0x8000u) >> 16;
  return ua | (ub << 16);
}

// ---------------- rmsnorm(x) -> u (bf16) + 1/rms ----------------
__global__ void rms1_kernel(const float* __restrict__ x, const float* __restrict__ w,
                            bf16_t* __restrict__ ub, float* __restrict__ rsi) {
  int row = blockIdx.x, t = threadIdx.x;
  float4 v = ((const float4*)(x + (long)row * DM))[t];
  float ss = v.x*v.x + v.y*v.y + v.z*v.z + v.w*v.w;
#pragma unroll
  for (int off = 32; off > 0; off >>= 1) ss += __shfl_down(ss, off, 64);
  __shared__ float red[4];
  if ((t & 63) == 0) red[t >> 6] = ss;
  __syncthreads();
  float tot = red[0] + red[1] + red[2] + red[3];
  float rs = rsqrtf(tot * (1.f / DM) + EPSF);
  if (t == 0) rsi[row] = rs;
  float4 wv = ((const float4*)w)[t];
  bf16_t* o = ub + (long)row * DM + t * 4;
  o[0] = __float2bfloat16(v.x * rs * wv.x);
  o[1] = __float2bfloat16(v.y * rs * wv.y);
  o[2] = __float2bfloat16(v.z * rs * wv.z);
  o[3] = __float2bfloat16(v.w * rs * wv.w);
}

// ---------------- weight fp32->bf16 (W1 padded to NPAD rows) ----------------
__global__ void cvtw1_kernel(const float* __restrict__ w, bf16_t* __restrict__ o) {
  int i4 = blockIdx.x * 256 + threadIdx.x;  // < NPAD*DM/4
  int idx = i4 * 4;
  int row = idx >> 10;
  float4 v = make_float4(0.f, 0.f, 0.f, 0.f);
  if (row < NPROJ) v = *(const float4*)(w + idx);
  bf16_t* d = o + idx;
  d[0] = __float2bfloat16(v.x); d[1] = __float2bfloat16(v.y);
  d[2] = __float2bfloat16(v.z); d[3] = __float2bfloat16(v.w);
}

__global__ void cvtw2_kernel(const float* __restrict__ w, bf16_t* __restrict__ o) {
  int i4 = blockIdx.x * 256 + threadIdx.x;  // < DM*DI/4
  int idx = i4 * 4;
  float4 v = *(const float4*)(w + idx);
  bf16_t* d = o + idx;
  d[0] = __float2bfloat16(v.x); d[1] = __float2bfloat16(v.y);
  d[2] = __float2bfloat16(v.z); d[3] = __float2bfloat16(v.w);
}

// ---------------- MFMA bf16 GEMM: C[M,N] = A[M,K] @ B[N,K]^T (+resid) ----------------
template<bool DO_RES>
__global__ __launch_bounds__(256) void gemm_bt_kernel(const bf16_t* __restrict__ A,
                const bf16_t* __restrict__ Bw, const float* __restrict__ resid,
                float* __restrict__ C, int N, int K) {
  __shared__ bf16_t As[128 * 32];
  __shared__ bf16_t Bs[128 * 32];
  const int tid = threadIdx.x;
  const int lane = tid & 63;
  const int wv = tid >> 6;
  const int wm = (wv >> 1) << 6;
  const int wn = (wv & 1) << 6;
  const int tm = blockIdx.x << 7;
  const int tn = blockIdx.y << 7;
  const int l15 = lane & 15;
  const int l4 = lane >> 4;

  floatx4 acc[4][4];
#pragma unroll
  for (int i = 0; i < 4; i++)
#pragma unroll
    for (int j = 0; j < 4; j++) acc[i][j] = (floatx4){0.f, 0.f, 0.f, 0.f};

  const int arow = tid >> 2;
  const int acol = (tid & 3) << 3;
  const bf16_t* Ag = A + (long)(tm + arow) * K + acol;
  const bf16_t* Bg = Bw + (long)(tn + arow) * K + acol;
  bf16_t* AsD  = &As[tid * 8];
  bf16_t* AsD2 = &As[2048 + tid * 8];
  bf16_t* BsD  = &Bs[tid * 8];
  bf16_t* BsD2 = &Bs[2048 + tid * 8];
  const long k64 = (long)64 * K;

  for (int k0 = 0; k0 < K; k0 += 32) {
    gl_lds16(Ag + k0, AsD);
    gl_lds16(Ag + k64 + k0, AsD2);
    gl_lds16(Bg + k0, BsD);
    gl_lds16(Bg + k64 + k0, BsD2);
    __syncthreads();
    bfrag8 af[4], bfr[4];
#pragma unroll
    for (int i = 0; i < 4; i++)
      af[i] = *(const bfrag8*)&As[(wm + i * 16 + l15) * 32 + l4 * 8];
#pragma unroll
    for (int j = 0; j < 4; j++)
      bfr[j] = *(const bfrag8*)&Bs[(wn + j * 16 + l15) * 32 + l4 * 8];
#pragma unroll
    for (int i = 0; i < 4; i++)
#pragma unroll
      for (int j = 0; j < 4; j++)
        acc[i][j] = __builtin_amdgcn_mfma_f32_16x16x32_bf16(af[i], bfr[j], acc[i][j], 0, 0, 0);
    __syncthreads();
  }
#pragma unroll
  for (int i = 0; i < 4; i++)
#pragma unroll
    for (int j = 0; j < 4; j++)
#pragma unroll
      for (int r = 0; r < 4; r++) {
        int row = tm + wm + i * 16 + l4 * 4 + r;
        int col = tn + wn + j * 16 + l15;
        float v = acc[i][j][r];
        if (DO_RES) v += resid[(long)row * N + col];
        C[(long)row * N + col] = v;
      }
}

// ---------------- depthwise causal conv4 + bias + silu, split ----------------
__global__ void conv_kernel(const float* __restrict__ zx, const float* __restrict__ cw,
                            const float* __restrict__ cb, float* __restrict__ xh,
                            float* __restrict__ Bm, float* __restrict__ Cm) {
  int idx = blockIdx.x * 256 + threadIdx.x;  // < MR*CONVD
  int c = idx % CONVD;
  int bl = idx / CONVD;
  int l = bl & (LL - 1);
  const float* base = zx + (long)(bl - l) * NPAD + DI + c;  // batch-row start, col c of xBC
  float acc = cb[c];
#pragma unroll
  for (int k = 0; k < 4; k++) {
    int ls = l + k - 3;
    if (ls >= 0) acc += base[(long)ls * NPAD] * cw[c * 4 + k];
  }
  float s = acc / (1.f + __expf(-acc));
  if (c < DI)               xh[(long)bl * DI + c] = s;
  else if (c < DI + DSTATE) Bm[(long)bl * DSTATE + (c - DI)] = s;
  else                      Cm[(long)bl * DSTATE + (c - DI - DSTATE)] = s;
}

// ---------------- fp32 dt projection (precision-critical path) ----------------
__global__ __launch_bounds__(256) void dtproj_kernel(const float* __restrict__ x,
     const float* __restrict__ rsi, const float* __restrict__ nw,
     const float* __restrict__ w1, const float* __restrict__ dtb,
     float* __restrict__ dt) {
  __shared__ float us[16 * 1024];
  int r0 = blockIdx.x * 16, t = threadIdx.x;
#pragma unroll
  for (int i = 0; i < 16; i++) {
    float4 v = ((const float4*)(x + (long)(r0 + i) * DM))[t];
    float rs = rsi[r0 + i];
    float4 wv = ((const float4*)nw)[t];
    *(float4*)&us[i * 1024 + t * 4] =
        make_float4(v.x * rs * wv.x, v.y * rs * wv.y, v.z * rs * wv.z, v.w * rs * wv.w);
  }
  __syncthreads();
  for (int o = t; o < 512; o += 256) {
    int r = o >> 5, h = o & 31;
    const float4* wr = (const float4*)(w1 + (long)(NPROJ - 32 + h) * DM);
    const float4* ur = (const float4*)&us[r * 1024];
    float s = 0.f;
    for (int k = 0; k < 256; k++) {
      float4 a = ur[k], b = wr[k];
      s += a.x * b.x + a.y * b.y + a.z * b.z + a.w * b.w;
    }
    float vv = s + dtb[h];
    float sp = fmaxf(vv, 0.f) + log1pf(__expf(-fabsf(vv)));  // stable softplus
    dt[(r0 + r) * 32 + h] = sp;
  }
}

// ---------------- per-(b,c,h) inclusive cumsum of a = dt*A ----------------
__global__ void acs_kernel(const float* __restrict__ dt, const float* __restrict__ A_log,
                           float* __restrict__ acs, float* __restrict__ ctot) {
  int blk = blockIdx.x;           // (b*8+c)*32+h
  int h = blk & 31, bc = blk >> 5;
  int t = threadIdx.x;
  float Ah = -__expf(A_log[h]);
  __shared__ float sc[256];
  sc[t] = dt[(bc * 256 + t) * 32 + h] * Ah;
  __syncthreads();
  for (int off = 1; off < 256; off <<= 1) {
    float v = (t >= off) ? sc[t - off] : 0.f;
    __syncthreads();
    sc[t] += v;
    __syncthreads();
  }
  acs[blk * 256 + t] = sc[t];
  if (t == 255) ctot[blk] = sc[255];
}

// ---------------- chunk states: S[p][n] = sum_l dt*decay*xh[l][p]*Bm[l][n] ----------------
__global__ __launch_bounds__(256) void states_kernel(const float* __restrict__ xhp,
    const float* __restrict__ Bmp, const float* __restrict__ dt,
    const float* __restrict__ acs, float* __restrict__ states) {
  int blk = blockIdx.x;
  int h = blk & 31, bc = blk >> 5;
  int t = threadIdx.x;
  int p = t & 63, wv = t >> 6;
  __shared__ float Bs[64 * 128];
  __shared__ float Xs[64 * 64];
  float atot = acs[blk * 256 + 255];
  float acc[32];
#pragma unroll
  for (int j = 0; j < 32; j++) acc[j] = 0.f;
  for (int lt = 0; lt < 4; lt++) {
    __syncthreads();
    const float4* Bg = (const float4*)(Bmp + (long)(bc * 256 + lt * 64) * DSTATE);
#pragma unroll
    for (int i = 0; i < 8; i++) {
      int f4 = t + i * 256;
      ((float4*)Bs)[f4] = Bg[f4];
    }
#pragma unroll
    for (int i = 0; i < 4; i++) {
      int f4 = t + i * 256;       // 0..1023
      int lr = f4 >> 4, p4 = f4 & 15;
      int gl = bc * 256 + lt * 64 + lr;
      float w = dt[gl * 32 + h] * __expf(atot - acs[blk * 256 + lt * 64 + lr]);
      float4 v = ((const float4*)(xhp + (long)gl * DI + h * HD))[p4];
      v.x *= w; v.y *= w; v.z *= w; v.w *= w;
      ((float4*)Xs)[f4] = v;
    }
    __syncthreads();
    for (int l = 0; l < 64; l++) {
      float xv = Xs[l * 64 + p];                          // conflict-free (2-way)
      const float4* br = (const float4*)&Bs[l * 128 + wv * 32];  // wave-uniform broadcast
#pragma unroll
      for (int j = 0; j < 8; j++) {
        float4 b4 = br[j];
        acc[j * 4 + 0] += xv * b4.x; acc[j * 4 + 1] += xv * b4.y;
        acc[j * 4 + 2] += xv * b4.z; acc[j * 4 + 3] += xv * b4.w;
      }
    }
  }
  float4* sp = (float4*)(states + (long)blk * 8192 + p * 128 + wv * 32);
#pragma unroll
  for (int j = 0; j < 8; j++)
    sp[j] = make_float4(acc[j * 4], acc[j * 4 + 1], acc[j * 4 + 2], acc[j * 4 + 3]);
}

// ---------------- inter-chunk scan: init_state recurrence ----------------
__global__ void scan_kernel(const float* __restrict__ states, const float* __restrict__ ctot,
                            float* __restrict__ inits) {
  int id = blockIdx.x * 256 + threadIdx.x;   // < 2*32*8192
  int pn = id & 8191;
  int bh = id >> 13;
  int b = bh >> 5, h = bh & 31;
  float S = 0.f;
#pragma unroll
  for (int c = 0; c < 8; c++) {
    int blk = (b * 8 + c) * 32 + h;
    inits[(long)blk * 8192 + pn] = S;
    S = __expf(ctot[blk]) * S + states[(long)blk * 8192 + pn];
  }
}

// ---------------- Y = (CB .* L) @ xd  +  exp(acs)*Cm @ init^T ----------------
__global__ __launch_bounds__(256, 2) void yk_kernel(const float* __restrict__ xhp,
     const float* __restrict__ Bmp, const float* __restrict__ Cmp,
     const float* __restrict__ dt, const float* __restrict__ acs,
     const float* __restrict__ inits, float* __restrict__ y) {
  int blk = blockIdx.x;
  int h = blk & 31, bc = blk >> 5;
  int t = threadIdx.x;               // = l within chunk
  int rowbase = bc * 256;
  __shared__ float acsS[256];
  __shared__ float sbuf[8704];       // union: {BmT[128*36] + Xs[32*68]} / stT[128*68]
  float* BmT = sbuf;
  float* Xs  = sbuf + 128 * 36;
  float* stT = sbuf;

  // Cm row (this thread's l) packed bf16 into 64 VGPRs
  unsigned cmp[64];
  {
    const float4* Cg = (const float4*)(Cmp + (long)(rowbase + t) * DSTATE);
#pragma unroll
    for (int q = 0; q < 32; q++) {
      float4 v = Cg[q];
      cmp[q * 2 + 0] = pack_bf16_rn(v.x, v.y);
      cmp[q * 2 + 1] = pack_bf16_rn(v.z, v.w);
    }
  }
  acsS[t] = acs[blk * 256 + t];
  __syncthreads();
  float al = acsS[t];
  float eAl = __expf(al);
  float accv[64];
#pragma unroll
  for (int p = 0; p < 64; p++) accv[p] = 0.f;

  for (int st = 0; st < 8; st++) {
    __syncthreads();
    {   // stage BmT[n][s] (transposed) and Xs[s][p] = xh*dt
      const float4* Bg = (const float4*)(Bmp + (long)(rowbase + st * 32) * DSTATE);
#pragma unroll
      for (int i = 0; i < 4; i++) {
        int f4 = t + i * 256;      // 0..1023
        int s = f4 >> 5, n4 = f4 & 31;
        float4 v = Bg[f4];
        BmT[(n4 * 4 + 0) * 36 + s] = v.x;
        BmT[(n4 * 4 + 1) * 36 + s] = v.y;
        BmT[(n4 * 4 + 2) * 36 + s] = v.z;
        BmT[(n4 * 4 + 3) * 36 + s] = v.w;
      }
#pragma unroll
      for (int i = 0; i < 2; i++) {
        int f4 = t + i * 256;      // 0..511
        int s = f4 >> 4, p4 = f4 & 15;
        int gl = rowbase + st * 32 + s;
        float w = dt[gl * 32 + h];
        float4 v = ((const float4*)(xhp + (long)gl * DI + h * HD))[p4];
        v.x *= w; v.y *= w; v.z *= w; v.w *= w;
        ((float4*)&Xs[s * 68])[p4] = v;
      }
    }
    __syncthreads();
    if (t >= st * 32) {
      float macc[32];
#pragma unroll
      for (int s = 0; s < 32; s++) macc[s] = 0.f;
      // phase A: macc[s] = Cm[l] . Bm[s]   (Bm reads are wave-uniform broadcasts)
      for (int n2 = 0; n2 < 64; n2++) {
        unsigned pr = cmp[n2];
        float c0 = __uint_as_float(pr << 16);
        float c1 = __uint_as_float(pr & 0xffff0000u);
        const float4* b0 = (const float4*)&BmT[(2 * n2) * 36];
        const float4* b1 = (const float4*)&BmT[(2 * n2 + 1) * 36];
#pragma unroll
        for (int j = 0; j < 8; j++) {
          float4 x0 = b0[j], x1 = b1[j];
          macc[j * 4 + 0] += c0 * x0.x + c1 * x1.x;
          macc[j * 4 + 1] += c0 * x0.y + c1 * x1.y;
          macc[j * 4 + 2] += c0 * x0.z + c1 * x1.z;
          macc[j * 4 + 3] += c0 * x0.w + c1 * x1.w;
        }
      }
      // phase B: accv[p] += exp(acs[l]-acs[s]) * macc[s] * xd[s][p]
#pragma unroll 4
      for (int s = 0; s < 32; s++) {
        int sg = st * 32 + s;
        float d = al - acsS[sg];
        float m = (sg <= t) ? macc[s] * __expf(fminf(d, 0.f)) : 0.f;
        const float4* xr = (const float4*)&Xs[s * 68];
#pragma unroll
        for (int j = 0; j < 16; j++) {
          float4 x4 = xr[j];
          accv[j * 4 + 0] += m * x4.x; accv[j * 4 + 1] += m * x4.y;
          accv[j * 4 + 2] += m * x4.z; accv[j * 4 + 3] += m * x4.w;
        }
      }
    }
  }
  // Y_off: accv[p] += eAl * Cm[l] . init_state[p][:]
  __syncthreads();
  {
    const float4* Sg = (const float4*)(inits + (long)blk * 8192);
#pragma unroll
    for (int i = 0; i < 8; i++) {
      int f4 = t + i * 256;        // 0..2047
      int p = f4 >> 5, n4 = f4 & 31;
      float4 v = Sg[f4];
      stT[(n4 * 4 + 0) * 68 + p] = v.x;
      stT[(n4 * 4 + 1) * 68 + p] = v.y;
      stT[(n4 * 4 + 2) * 68 + p] = v.z;
      stT[(n4 * 4 + 3) * 68 + p] = v.w;
    }
  }
  __syncthreads();
  for (int n2 = 0; n2 < 64; n2++) {
    unsigned pr = cmp[n2];
    float c0 = __uint_as_float(pr << 16) * eAl;
    float c1 = __uint_as_float(pr & 0xffff0000u) * eAl;
    const float4* s0 = (const float4*)&stT[(2 * n2) * 68];
    const float4* s1 = (const float4*)&stT[(2 * n2 + 1) * 68];
#pragma unroll
    for (int j = 0; j < 16; j++) {
      float4 a4 = s0[j], b4 = s1[j];
      accv[j * 4 + 0] += c0 * a4.x + c1 * b4.x;
      accv[j * 4 + 1] += c0 * a4.y + c1 * b4.y;
      accv[j * 4 + 2] += c0 * a4.z + c1 * b4.z;
      accv[j * 4 + 3] += c0 * a4.w + c1 * b4.w;
    }
  }
  float4* yo = (float4*)(y + (long)(rowbase + t) * DI + h * HD);
#pragma unroll
  for (int j = 0; j < 16; j++)
    yo[j] = make_float4(accv[j * 4], accv[j * 4 + 1], accv[j * 4 + 2], accv[j * 4 + 3]);
}

// ---------------- gated rmsnorm: yn = rmsnorm((y + D*xh)*silu(z))*gw -> bf16 ----------------
__global__ void gnorm_kernel(const float* __restrict__ y, const float* __restrict__ xhp,
     const float* __restrict__ zx, const float* __restrict__ Dp,
     const float* __restrict__ gw, bf16_t* __restrict__ yn) {
  int row = blockIdx.x, t = threadIdx.x;
  float vals[8];
  float ss = 0.f;
#pragma unroll
  for (int i = 0; i < 2; i++) {
    int c4 = t + i * 256;
    float4 yv = ((const float4*)(y + (long)row * DI))[c4];
    float4 xv = ((const float4*)(xhp + (long)row * DI))[c4];
    float4 zv = ((const float4*)(zx + (long)row * NPAD))[c4];
    float Dh = Dp[c4 >> 4];
    float a0 = yv.x + Dh * xv.x, a1 = yv.y + Dh * xv.y;
    float a2 = yv.z + Dh * xv.z, a3 = yv.w + Dh * xv.w;
    float s0 = zv.x / (1.f + __expf(-zv.x)), s1 = zv.y / (1.f + __expf(-zv.y));
    float s2 = zv.z / (1.f + __expf(-zv.z)), s3 = zv.w / (1.f + __expf(-zv.w));
    float v0 = a0 * s0, v1 = a1 * s1, v2 = a2 * s2, v3 = a3 * s3;
    ss += v0 * v0 + v1 * v1 + v2 * v2 + v3 * v3;
    vals[i * 4 + 0] = v0; vals[i * 4 + 1] = v1; vals[i * 4 + 2] = v2; vals[i * 4 + 3] = v3;
  }
#pragma unroll
  for (int off = 32; off > 0; off >>= 1) ss += __shfl_down(ss, off, 64);
  __shared__ float red[4];
  if ((t & 63) == 0) red[t >> 6] = ss;
  __syncthreads();
  float tot = red[0] + red[1] + red[2] + red[3];
  float rs = rsqrtf(tot * (1.f / DI) + EPSF);
#pragma unroll
  for (int i = 0; i < 2; i++) {
    int c4 = t + i * 256;
    float4 gv = ((const float4*)gw)[c4];
    bf16_t* o = yn + (long)row * DI + c4 * 4;
    o[0] = __float2bfloat16(vals[i * 4 + 0] * rs * gv.x);
    o[1] = __float2bfloat16(vals[i * 4 + 1] * rs * gv.y);
    o[2] = __float2bfloat16(vals[i * 4 + 2] * rs * gv.z);
    o[3] = __float2bfloat16(vals[i * 4 + 3] * rs * gv.w);
  }
}

extern "C" void kernel_launch(void* const* d_in, const int* in_sizes, int n_in,
                              void* d_out, int out_size, void* d_ws, size_t ws_size,
                              hipStream_t stream) {
  const float* x    = (const float*)d_in[0];
  const float* nw   = (const float*)d_in[1];
  const float* w1   = (const float*)d_in[2];
  const float* cw   = (const float*)d_in[3];
  const float* cb   = (const float*)d_in[4];
  const float* dtb  = (const float*)d_in[5];
  const float* alog = (const float*)d_in[6];
  const float* Dp   = (const float*)d_in[7];
  const float* gw   = (const float*)d_in[8];
  const float* w2   = (const float*)d_in[9];
  float* out = (float*)d_out;

  char* ws = (char*)d_ws;
  size_t off = 0;
  auto alloc = [&](size_t bytes) -> void* {
    void* p = ws + off;
    off += (bytes + 255) & ~(size_t)255;
    return p;
  };
  bf16_t* ub    = (bf16_t*)alloc((size_t)MR * DM * 2);
  bf16_t* w1b   = (bf16_t*)alloc((size_t)NPAD * DM * 2);
  bf16_t* w2b   = (bf16_t*)alloc((size_t)DM * DI * 2);
  float* zx     = (float*)alloc((size_t)MR * NPAD * 4);
  float* xh     = (float*)alloc((size_t)MR * DI * 4);
  float* Bm     = (float*)alloc((size_t)MR * DSTATE * 4);
  float* Cm     = (float*)alloc((size_t)MR * DSTATE * 4);
  float* dt     = (float*)alloc((size_t)MR * NHD * 4);
  float* rsi    = (float*)alloc((size_t)MR * 4);
  float* acs    = (float*)alloc((size_t)512 * 256 * 4);
  float* ctot   = (float*)alloc((size_t)512 * 4);
  float* states = (float*)alloc((size_t)512 * 8192 * 4);
  float* inits  = (float*)alloc((size_t)512 * 8192 * 4);
  float* yb     = (float*)alloc((size_t)MR * DI * 4);
  bf16_t* yn    = (bf16_t*)alloc((size_t)MR * DI * 2);
  if (off > ws_size) return;  // workspace too small -> bench will show absmax fail

  rms1_kernel<<<MR, 256, 0, stream>>>(x, nw, ub, rsi);
  cvtw1_kernel<<<(NPAD * DM / 4) / 256, 256, 0, stream>>>(w1, w1b);
  cvtw2_kernel<<<(DM * DI / 4) / 256, 256, 0, stream>>>(w2, w2b);
  gemm_bt_kernel<false><<<dim3(MR / 128, NPAD / 128), 256, 0, stream>>>(ub, w1b, nullptr, zx, NPAD, DM);
  conv_kernel<<<(MR * CONVD) / 256, 256, 0, stream>>>(zx, cw, cb, xh, Bm, Cm);
  dtproj_kernel<<<MR / 16, 256, 0, stream>>>(x, rsi, nw, w1, dtb, dt);
  acs_kernel<<<512, 256, 0, stream>>>(dt, alog, acs, ctot);
  states_kernel<<<512, 256, 0, stream>>>(xh, Bm, dt, acs, states);
  scan_kernel<<<(512 * 8192 / 16) / 256, 256, 0, stream>>>(states, ctot, inits);
  yk_kernel<<<512, 256, 0, stream>>>(xh, Bm, Cm, dt, acs, inits, yb);
  gnorm_kernel<<<MR, 256, 0, stream>>>(yb, xh, zx, Dp, gw, yn);
  gemm_bt_kernel<true><<<dim3(MR / 128, DM / 128), 256, 0, stream>>>(yn, w2b, x, out, DM, DI);
}

// Round 2
// 437.568 us; speedup vs baseline: 2.1855x; 2.1855x over previous
//
#include <hip/hip_runtime.h>
#include <hip/hip_bf16.h>

typedef __hip_bfloat16 bf16_t;
typedef __attribute__((ext_vector_type(8))) short bfrag8;   // 8 bf16 (4 VGPRs)
typedef __attribute__((ext_vector_type(4))) float floatx4;  // MFMA acc

#define DM     1024
#define DI     2048
#define NHD    32
#define HD     64
#define DSTATE 128
#define CONVD  2304
#define NPROJ  4384
#define NPAD   4480
#define MR     4096      // B*L
#define LL     2048
#define EPSF   1e-5f
#define PSTR   40        // LDS row stride (bf16) for P/X tiles

// ---------------- async global->LDS 16B ----------------
__device__ __forceinline__ void gl_lds16(const void* g, void* l) {
  __builtin_amdgcn_global_load_lds((const __attribute__((address_space(1))) void*)g,
                                   (__attribute__((address_space(3))) void*)l, 16, 0, 0);
}

__device__ __forceinline__ unsigned pack_bf16_rn(float a, float b) {
  unsigned ua = (__float_as_uint(a) + 0x8000u) >> 16;
  unsigned ub = (__float_as_uint(b) + 0x8000u) >> 16;
  return ua | (ub << 16);
}

// ---------------- rmsnorm(x) -> u (bf16) + 1/rms ----------------
__global__ void rms1_kernel(const float* __restrict__ x, const float* __restrict__ w,
                            bf16_t* __restrict__ ub, float* __restrict__ rsi) {
  int row = blockIdx.x, t = threadIdx.x;
  float4 v = ((const float4*)(x + (long)row * DM))[t];
  float ss = v.x*v.x + v.y*v.y + v.z*v.z + v.w*v.w;
#pragma unroll
  for (int off = 32; off > 0; off >>= 1) ss += __shfl_down(ss, off, 64);
  __shared__ float red[4];
  if ((t & 63) == 0) red[t >> 6] = ss;
  __syncthreads();
  float tot = red[0] + red[1] + red[2] + red[3];
  float rs = rsqrtf(tot * (1.f / DM) + EPSF);
  if (t == 0) rsi[row] = rs;
  float4 wv = ((const float4*)w)[t];
  bf16_t* o = ub + (long)row * DM + t * 4;
  o[0] = __float2bfloat16(v.x * rs * wv.x);
  o[1] = __float2bfloat16(v.y * rs * wv.y);
  o[2] = __float2bfloat16(v.z * rs * wv.z);
  o[3] = __float2bfloat16(v.w * rs * wv.w);
}

// ---------------- weight fp32->bf16 (W1 padded to NPAD rows) ----------------
__global__ void cvtw1_kernel(const float* __restrict__ w, bf16_t* __restrict__ o) {
  int i4 = blockIdx.x * 256 + threadIdx.x;  // < NPAD*DM/4
  int idx = i4 * 4;
  int row = idx >> 10;
  float4 v = make_float4(0.f, 0.f, 0.f, 0.f);
  if (row < NPROJ) v = *(const float4*)(w + idx);
  bf16_t* d = o + idx;
  d[0] = __float2bfloat16(v.x); d[1] = __float2bfloat16(v.y);
  d[2] = __float2bfloat16(v.z); d[3] = __float2bfloat16(v.w);
}

__global__ void cvtw2_kernel(const float* __restrict__ w, bf16_t* __restrict__ o) {
  int i4 = blockIdx.x * 256 + threadIdx.x;  // < DM*DI/4
  int idx = i4 * 4;
  float4 v = *(const float4*)(w + idx);
  bf16_t* d = o + idx;
  d[0] = __float2bfloat16(v.x); d[1] = __float2bfloat16(v.y);
  d[2] = __float2bfloat16(v.z); d[3] = __float2bfloat16(v.w);
}

// ---------------- MFMA bf16 GEMM: C[M,N] = A[M,K] @ B[N,K]^T (+resid) ----------------
template<bool DO_RES>
__global__ __launch_bounds__(256) void gemm_bt_kernel(const bf16_t* __restrict__ A,
                const bf16_t* __restrict__ Bw, const float* __restrict__ resid,
                float* __restrict__ C, int N, int K) {
  __shared__ bf16_t As[128 * 32];
  __shared__ bf16_t Bs[128 * 32];
  const int tid = threadIdx.x;
  const int lane = tid & 63;
  const int wv = tid >> 6;
  const int wm = (wv >> 1) << 6;
  const int wn = (wv & 1) << 6;
  const int tm = blockIdx.x << 7;
  const int tn = blockIdx.y << 7;
  const int l15 = lane & 15;
  const int l4 = lane >> 4;

  floatx4 acc[4][4];
#pragma unroll
  for (int i = 0; i < 4; i++)
#pragma unroll
    for (int j = 0; j < 4; j++) acc[i][j] = (floatx4){0.f, 0.f, 0.f, 0.f};

  const int arow = tid >> 2;
  const int acol = (tid & 3) << 3;
  const bf16_t* Ag = A + (long)(tm + arow) * K + acol;
  const bf16_t* Bg = Bw + (long)(tn + arow) * K + acol;
  bf16_t* AsD  = &As[tid * 8];
  bf16_t* AsD2 = &As[2048 + tid * 8];
  bf16_t* BsD  = &Bs[tid * 8];
  bf16_t* BsD2 = &Bs[2048 + tid * 8];
  const long k64 = (long)64 * K;

  for (int k0 = 0; k0 < K; k0 += 32) {
    gl_lds16(Ag + k0, AsD);
    gl_lds16(Ag + k64 + k0, AsD2);
    gl_lds16(Bg + k0, BsD);
    gl_lds16(Bg + k64 + k0, BsD2);
    __syncthreads();
    bfrag8 af[4], bfr[4];
#pragma unroll
    for (int i = 0; i < 4; i++)
      af[i] = *(const bfrag8*)&As[(wm + i * 16 + l15) * 32 + l4 * 8];
#pragma unroll
    for (int j = 0; j < 4; j++)
      bfr[j] = *(const bfrag8*)&Bs[(wn + j * 16 + l15) * 32 + l4 * 8];
#pragma unroll
    for (int i = 0; i < 4; i++)
#pragma unroll
      for (int j = 0; j < 4; j++)
        acc[i][j] = __builtin_amdgcn_mfma_f32_16x16x32_bf16(af[i], bfr[j], acc[i][j], 0, 0, 0);
    __syncthreads();
  }
#pragma unroll
  for (int i = 0; i < 4; i++)
#pragma unroll
    for (int j = 0; j < 4; j++)
#pragma unroll
      for (int r = 0; r < 4; r++) {
        int row = tm + wm + i * 16 + l4 * 4 + r;
        int col = tn + wn + j * 16 + l15;
        float v = acc[i][j][r];
        if (DO_RES) v += resid[(long)row * N + col];
        C[(long)row * N + col] = v;
      }
}

// ---------------- batched S GEMM: SL[bc][l][s] = Cm[l] . Bm[s]  (M=N=256,K=128) ---------
__global__ __launch_bounds__(256) void gemm_s_kernel(const bf16_t* __restrict__ Cmh,
                const bf16_t* __restrict__ Bmh, float* __restrict__ SL) {
  __shared__ bf16_t As[128 * 32];
  __shared__ bf16_t Bs[128 * 32];
  const int tid = threadIdx.x;
  const int lane = tid & 63;
  const int wv = tid >> 6;
  const int wm = (wv >> 1) << 6;
  const int wn = (wv & 1) << 6;
  const int bc = blockIdx.z;
  const int tm = blockIdx.x << 7;
  const int tn = blockIdx.y << 7;
  const int l15 = lane & 15;
  const int l4 = lane >> 4;

  floatx4 acc[4][4];
#pragma unroll
  for (int i = 0; i < 4; i++)
#pragma unroll
    for (int j = 0; j < 4; j++) acc[i][j] = (floatx4){0.f, 0.f, 0.f, 0.f};

  const int arow = tid >> 2;
  const int acol = (tid & 3) << 3;
  const bf16_t* Ag = Cmh + (long)bc * 256 * DSTATE + (long)(tm + arow) * DSTATE + acol;
  const bf16_t* Bg = Bmh + (long)bc * 256 * DSTATE + (long)(tn + arow) * DSTATE + acol;
  bf16_t* AsD  = &As[tid * 8];
  bf16_t* AsD2 = &As[2048 + tid * 8];
  bf16_t* BsD  = &Bs[tid * 8];
  bf16_t* BsD2 = &Bs[2048 + tid * 8];
  const long k64 = (long)64 * DSTATE;

  for (int k0 = 0; k0 < DSTATE; k0 += 32) {
    gl_lds16(Ag + k0, AsD);
    gl_lds16(Ag + k64 + k0, AsD2);
    gl_lds16(Bg + k0, BsD);
    gl_lds16(Bg + k64 + k0, BsD2);
    __syncthreads();
    bfrag8 af[4], bfr[4];
#pragma unroll
    for (int i = 0; i < 4; i++)
      af[i] = *(const bfrag8*)&As[(wm + i * 16 + l15) * 32 + l4 * 8];
#pragma unroll
    for (int j = 0; j < 4; j++)
      bfr[j] = *(const bfrag8*)&Bs[(wn + j * 16 + l15) * 32 + l4 * 8];
#pragma unroll
    for (int i = 0; i < 4; i++)
#pragma unroll
      for (int j = 0; j < 4; j++)
        acc[i][j] = __builtin_amdgcn_mfma_f32_16x16x32_bf16(af[i], bfr[j], acc[i][j], 0, 0, 0);
    __syncthreads();
  }
  float* Cb = SL + (long)bc * 65536;
#pragma unroll
  for (int i = 0; i < 4; i++)
#pragma unroll
    for (int j = 0; j < 4; j++)
#pragma unroll
      for (int r = 0; r < 4; r++) {
        int row = tm + wm + i * 16 + l4 * 4 + r;   // l
        int col = tn + wn + j * 16 + l15;          // s
        Cb[(long)row * 256 + col] = acc[i][j][r];
      }
}

// ---------------- depthwise causal conv4 + bias + silu, split ----------------
__global__ void conv_kernel(const float* __restrict__ zx, const float* __restrict__ cw,
                            const float* __restrict__ cb, float* __restrict__ xh,
                            float* __restrict__ Bm, float* __restrict__ Cm,
                            bf16_t* __restrict__ Bmh, bf16_t* __restrict__ Cmh) {
  int idx = blockIdx.x * 256 + threadIdx.x;  // < MR*CONVD
  int c = idx % CONVD;
  int bl = idx / CONVD;
  int l = bl & (LL - 1);
  const float* base = zx + (long)(bl - l) * NPAD + DI + c;  // batch-row start, col c of xBC
  float acc = cb[c];
#pragma unroll
  for (int k = 0; k < 4; k++) {
    int ls = l + k - 3;
    if (ls >= 0) acc += base[(long)ls * NPAD] * cw[c * 4 + k];
  }
  float s = acc / (1.f + __expf(-acc));
  if (c < DI) {
    xh[(long)bl * DI + c] = s;
  } else if (c < DI + DSTATE) {
    Bm[(long)bl * DSTATE + (c - DI)] = s;
    Bmh[(long)bl * DSTATE + (c - DI)] = __float2bfloat16(s);
  } else {
    Cm[(long)bl * DSTATE + (c - DI - DSTATE)] = s;
    Cmh[(long)bl * DSTATE + (c - DI - DSTATE)] = __float2bfloat16(s);
  }
}

// ---------------- fp32 dt projection (precision-critical path) ----------------
__global__ __launch_bounds__(256) void dtproj_kernel(const float* __restrict__ x,
     const float* __restrict__ rsi, const float* __restrict__ nw,
     const float* __restrict__ w1, const float* __restrict__ dtb,
     float* __restrict__ dt) {
  __shared__ float us[16 * 1024];
  int r0 = blockIdx.x * 16, t = threadIdx.x;
#pragma unroll
  for (int i = 0; i < 16; i++) {
    float4 v = ((const float4*)(x + (long)(r0 + i) * DM))[t];
    float rs = rsi[r0 + i];
    float4 wv = ((const float4*)nw)[t];
    *(float4*)&us[i * 1024 + t * 4] =
        make_float4(v.x * rs * wv.x, v.y * rs * wv.y, v.z * rs * wv.z, v.w * rs * wv.w);
  }
  __syncthreads();
  for (int o = t; o < 512; o += 256) {
    int r = o >> 5, h = o & 31;
    const float4* wr = (const float4*)(w1 + (long)(NPROJ - 32 + h) * DM);
    const float4* ur = (const float4*)&us[r * 1024];
    float s = 0.f;
    for (int k = 0; k < 256; k++) {
      float4 a = ur[k], b = wr[k];
      s += a.x * b.x + a.y * b.y + a.z * b.z + a.w * b.w;
    }
    float vv = s + dtb[h];
    float sp = fmaxf(vv, 0.f) + log1pf(__expf(-fabsf(vv)));  // stable softplus
    dt[(r0 + r) * 32 + h] = sp;
  }
}

// ---------------- per-(b,c,h) inclusive cumsum of a = dt*A ----------------
__global__ void acs_kernel(const float* __restrict__ dt, const float* __restrict__ A_log,
                           float* __restrict__ acs, float* __restrict__ ctot) {
  int blk = blockIdx.x;           // (b*8+c)*32+h
  int h = blk & 31, bc = blk >> 5;
  int t = threadIdx.x;
  float Ah = -__expf(A_log[h]);
  __shared__ float sc[256];
  sc[t] = dt[(bc * 256 + t) * 32 + h] * Ah;
  __syncthreads();
  for (int off = 1; off < 256; off <<= 1) {
    float v = (t >= off) ? sc[t - off] : 0.f;
    __syncthreads();
    sc[t] += v;
    __syncthreads();
  }
  acs[blk * 256 + t] = sc[t];
  if (t == 255) ctot[blk] = sc[255];
}

// ---------------- chunk states: S[p][n] = sum_l dt*decay*xh[l][p]*Bm[l][n] ----------------
__global__ __launch_bounds__(256) void states_kernel(const float* __restrict__ xhp,
    const float* __restrict__ Bmp, const float* __restrict__ dt,
    const float* __restrict__ acs, float* __restrict__ states) {
  int blk = blockIdx.x;
  int h = blk & 31, bc = blk >> 5;
  int t = threadIdx.x;
  int p = t & 63, wv = t >> 6;
  __shared__ float Bs[64 * 128];
  __shared__ float Xs[64 * 64];
  float atot = acs[blk * 256 + 255];
  float acc[32];
#pragma unroll
  for (int j = 0; j < 32; j++) acc[j] = 0.f;
  for (int lt = 0; lt < 4; lt++) {
    __syncthreads();
    const float4* Bg = (const float4*)(Bmp + (long)(bc * 256 + lt * 64) * DSTATE);
#pragma unroll
    for (int i = 0; i < 8; i++) {
      int f4 = t + i * 256;
      ((float4*)Bs)[f4] = Bg[f4];
    }
#pragma unroll
    for (int i = 0; i < 4; i++) {
      int f4 = t + i * 256;       // 0..1023
      int lr = f4 >> 4, p4 = f4 & 15;
      int gl = bc * 256 + lt * 64 + lr;
      float w = dt[gl * 32 + h] * __expf(atot - acs[blk * 256 + lt * 64 + lr]);
      float4 v = ((const float4*)(xhp + (long)gl * DI + h * HD))[p4];
      v.x *= w; v.y *= w; v.z *= w; v.w *= w;
      ((float4*)Xs)[f4] = v;
    }
    __syncthreads();
    for (int l = 0; l < 64; l++) {
      float xv = Xs[l * 64 + p];                          // conflict-free (2-way)
      const float4* br = (const float4*)&Bs[l * 128 + wv * 32];  // wave-uniform broadcast
#pragma unroll
      for (int j = 0; j < 8; j++) {
        float4 b4 = br[j];
        acc[j * 4 + 0] += xv * b4.x; acc[j * 4 + 1] += xv * b4.y;
        acc[j * 4 + 2] += xv * b4.z; acc[j * 4 + 3] += xv * b4.w;
      }
    }
  }
  float4* sp = (float4*)(states + (long)blk * 8192 + p * 128 + wv * 32);
#pragma unroll
  for (int j = 0; j < 8; j++)
    sp[j] = make_float4(acc[j * 4], acc[j * 4 + 1], acc[j * 4 + 2], acc[j * 4 + 3]);
}

// ---------------- inter-chunk scan: init_state recurrence ----------------
__global__ void scan_kernel(const float* __restrict__ states, const float* __restrict__ ctot,
                            float* __restrict__ inits) {
  int id = blockIdx.x * 256 + threadIdx.x;   // < 2*32*8192
  int pn = id & 8191;
  int bh = id >> 13;
  int b = bh >> 5, h = bh & 31;
  float S = 0.f;
#pragma unroll
  for (int c = 0; c < 8; c++) {
    int blk = (b * 8 + c) * 32 + h;
    inits[(long)blk * 8192 + pn] = S;
    S = __expf(ctot[blk]) * S + states[(long)blk * 8192 + pn];
  }
}

// ---------------- MFMA Y: Y = (S.*L) @ xd  +  (exp(acs)*Cm) @ init^T ----------------
// grid: bi = ((bc*32 + h)<<1) | mh ; block handles 128 l-rows (mh half), all 64 p.
__global__ __launch_bounds__(256, 4) void yk2_kernel(const float* __restrict__ SL,
     const float* __restrict__ Cmp, const float* __restrict__ xhp,
     const float* __restrict__ dt, const float* __restrict__ acs,
     const float* __restrict__ inits, float* __restrict__ y) {
  int bi = blockIdx.x;
  int mh = bi & 1, h = (bi >> 1) & 31, bc = bi >> 6;
  int ablk = bc * 32 + h;
  int t = threadIdx.x;
  int lane = t & 63, wv = t >> 6;
  int l15 = lane & 15, l4 = lane >> 4;
  __shared__ float acsS[256];
  __shared__ bf16_t Ps[128 * PSTR];
  __shared__ bf16_t Xs[64 * PSTR];

  acsS[t] = acs[ablk * 256 + t];
  __syncthreads();
  const int l_loc = t >> 1, half = t & 1;
  const int l = mh * 128 + l_loc;
  const float al = acsS[l];
  const float eAl = __expf(al);
  const int rowbase = bc * 256;
  const float* SLb = SL + (long)bc * 65536 + (long)l * 256;

  floatx4 acc[2][4];
#pragma unroll
  for (int i = 0; i < 2; i++)
#pragma unroll
    for (int j = 0; j < 4; j++) acc[i][j] = (floatx4){0.f, 0.f, 0.f, 0.f};

  const int nkd = (mh + 1) * 4;          // # diagonal k-tiles
  for (int kt = 0; kt < nkd + 4; kt++) {
    __syncthreads();
    if (kt < nkd) {
      // ---- stage P[l_loc][s] = (s<=l) * exp(acs_l - acs_s) * S[l][s], bf16 ----
      int s0 = kt * 32 + half * 16;
      unsigned pk[8];
      const float4* Sg = (const float4*)(SLb + s0);
#pragma unroll
      for (int q = 0; q < 4; q++) {
        float4 v = Sg[q];
        int sb = s0 + q * 4;
        float p0 = (sb + 0 <= l) ? v.x * __expf(al - acsS[sb + 0]) : 0.f;
        float p1 = (sb + 1 <= l) ? v.y * __expf(al - acsS[sb + 1]) : 0.f;
        float p2 = (sb + 2 <= l) ? v.z * __expf(al - acsS[sb + 2]) : 0.f;
        float p3 = (sb + 3 <= l) ? v.w * __expf(al - acsS[sb + 3]) : 0.f;
        pk[q * 2 + 0] = pack_bf16_rn(p0, p1);
        pk[q * 2 + 1] = pack_bf16_rn(p2, p3);
      }
      uint4* pw = (uint4*)&Ps[l_loc * PSTR + half * 16];
      pw[0] = make_uint4(pk[0], pk[1], pk[2], pk[3]);
      pw[1] = make_uint4(pk[4], pk[5], pk[6], pk[7]);
      // ---- stage Xs[p][s] = xh[s][p] * dt[s]  (transpose) ----
      int p4 = t & 15, sh = t >> 4;
#pragma unroll
      for (int r = 0; r < 2; r++) {
        int s = sh + r * 16;
        int gl = rowbase + kt * 32 + s;
        float w = dt[gl * 32 + h];
        float4 v = ((const float4*)(xhp + (long)gl * DI + h * HD))[p4];
        Xs[(p4 * 4 + 0) * PSTR + s] = __float2bfloat16(v.x * w);
        Xs[(p4 * 4 + 1) * PSTR + s] = __float2bfloat16(v.y * w);
        Xs[(p4 * 4 + 2) * PSTR + s] = __float2bfloat16(v.z * w);
        Xs[(p4 * 4 + 3) * PSTR + s] = __float2bfloat16(v.w * w);
      }
    } else {
      // ---- stage P[l_loc][n] = exp(acs_l) * Cm[l][n], bf16 ----
      int n0 = (kt - nkd) * 32;
      unsigned pk[8];
      const float4* Cg = (const float4*)(Cmp + (long)(rowbase + l) * DSTATE + n0 + half * 16);
#pragma unroll
      for (int q = 0; q < 4; q++) {
        float4 v = Cg[q];
        pk[q * 2 + 0] = pack_bf16_rn(v.x * eAl, v.y * eAl);
        pk[q * 2 + 1] = pack_bf16_rn(v.z * eAl, v.w * eAl);
      }
      uint4* pw = (uint4*)&Ps[l_loc * PSTR + half * 16];
      pw[0] = make_uint4(pk[0], pk[1], pk[2], pk[3]);
      pw[1] = make_uint4(pk[4], pk[5], pk[6], pk[7]);
      // ---- stage Xs[p][n] = inits[p][n], bf16 ----
      int p_loc = t >> 2;
      const float4* Ig = (const float4*)(inits + (long)ablk * 8192 + p_loc * 128 + n0);
#pragma unroll
      for (int r = 0; r < 2; r++) {
        int nn = (t & 3) * 8 + r * 4;
        float4 v = Ig[(t & 3) * 2 + r];
        unsigned* xw = (unsigned*)&Xs[p_loc * PSTR + nn];
        xw[0] = pack_bf16_rn(v.x, v.y);
        xw[1] = pack_bf16_rn(v.z, v.w);
      }
    }
    __syncthreads();
    // ---- MFMA: 2 m-tiles x 4 n-tiles ----
    bfrag8 bfr[4];
#pragma unroll
    for (int j = 0; j < 4; j++)
      bfr[j] = *(const bfrag8*)&Xs[(j * 16 + l15) * PSTR + l4 * 8];
#pragma unroll
    for (int i = 0; i < 2; i++) {
      bfrag8 af = *(const bfrag8*)&Ps[(wv * 32 + i * 16 + l15) * PSTR + l4 * 8];
#pragma unroll
      for (int j = 0; j < 4; j++)
        acc[i][j] = __builtin_amdgcn_mfma_f32_16x16x32_bf16(af, bfr[j], acc[i][j], 0, 0, 0);
    }
  }
  // ---- write Y ----
#pragma unroll
  for (int i = 0; i < 2; i++)
#pragma unroll
    for (int j = 0; j < 4; j++)
#pragma unroll
      for (int r = 0; r < 4; r++) {
        int row = rowbase + mh * 128 + wv * 32 + i * 16 + l4 * 4 + r;
        int col = j * 16 + l15;
        y[(long)row * DI + h * HD + col] = acc[i][j][r];
      }
}

// ---------------- gated rmsnorm: yn = rmsnorm((y + D*xh)*silu(z))*gw -> bf16 ----------------
__global__ void gnorm_kernel(const float* __restrict__ y, const float* __restrict__ xhp,
     const float* __restrict__ zx, const float* __restrict__ Dp,
     const float* __restrict__ gw, bf16_t* __restrict__ yn) {
  int row = blockIdx.x, t = threadIdx.x;
  float vals[8];
  float ss = 0.f;
#pragma unroll
  for (int i = 0; i < 2; i++) {
    int c4 = t + i * 256;
    float4 yv = ((const float4*)(y + (long)row * DI))[c4];
    float4 xv = ((const float4*)(xhp + (long)row * DI))[c4];
    float4 zv = ((const float4*)(zx + (long)row * NPAD))[c4];
    float Dh = Dp[c4 >> 4];
    float a0 = yv.x + Dh * xv.x, a1 = yv.y + Dh * xv.y;
    float a2 = yv.z + Dh * xv.z, a3 = yv.w + Dh * xv.w;
    float s0 = zv.x / (1.f + __expf(-zv.x)), s1 = zv.y / (1.f + __expf(-zv.y));
    float s2 = zv.z / (1.f + __expf(-zv.z)), s3 = zv.w / (1.f + __expf(-zv.w));
    float v0 = a0 * s0, v1 = a1 * s1, v2 = a2 * s2, v3 = a3 * s3;
    ss += v0 * v0 + v1 * v1 + v2 * v2 + v3 * v3;
    vals[i * 4 + 0] = v0; vals[i * 4 + 1] = v1; vals[i * 4 + 2] = v2; vals[i * 4 + 3] = v3;
  }
#pragma unroll
  for (int off = 32; off > 0; off >>= 1) ss += __shfl_down(ss, off, 64);
  __shared__ float red[4];
  if ((t & 63) == 0) red[t >> 6] = ss;
  __syncthreads();
  float tot = red[0] + red[1] + red[2] + red[3];
  float rs = rsqrtf(tot * (1.f / DI) + EPSF);
#pragma unroll
  for (int i = 0; i < 2; i++) {
    int c4 = t + i * 256;
    float4 gv = ((const float4*)gw)[c4];
    bf16_t* o = yn + (long)row * DI + c4 * 4;
    o[0] = __float2bfloat16(vals[i * 4 + 0] * rs * gv.x);
    o[1] = __float2bfloat16(vals[i * 4 + 1] * rs * gv.y);
    o[2] = __float2bfloat16(vals[i * 4 + 2] * rs * gv.z);
    o[3] = __float2bfloat16(vals[i * 4 + 3] * rs * gv.w);
  }
}

extern "C" void kernel_launch(void* const* d_in, const int* in_sizes, int n_in,
                              void* d_out, int out_size, void* d_ws, size_t ws_size,
                              hipStream_t stream) {
  const float* x    = (const float*)d_in[0];
  const float* nw   = (const float*)d_in[1];
  const float* w1   = (const float*)d_in[2];
  const float* cw   = (const float*)d_in[3];
  const float* cb   = (const float*)d_in[4];
  const float* dtb  = (const float*)d_in[5];
  const float* alog = (const float*)d_in[6];
  const float* Dp   = (const float*)d_in[7];
  const float* gw   = (const float*)d_in[8];
  const float* w2   = (const float*)d_in[9];
  float* out = (float*)d_out;

  char* ws = (char*)d_ws;
  size_t off = 0;
  auto alloc = [&](size_t bytes) -> void* {
    void* p = ws + off;
    off += (bytes + 255) & ~(size_t)255;
    return p;
  };
  bf16_t* ub    = (bf16_t*)alloc((size_t)MR * DM * 2);
  bf16_t* w1b   = (bf16_t*)alloc((size_t)NPAD * DM * 2);
  bf16_t* w2b   = (bf16_t*)alloc((size_t)DM * DI * 2);
  float* zx     = (float*)alloc((size_t)MR * NPAD * 4);
  float* xh     = (float*)alloc((size_t)MR * DI * 4);
  float* Bm     = (float*)alloc((size_t)MR * DSTATE * 4);
  float* Cm     = (float*)alloc((size_t)MR * DSTATE * 4);
  bf16_t* Bmh   = (bf16_t*)alloc((size_t)MR * DSTATE * 2);
  bf16_t* Cmh   = (bf16_t*)alloc((size_t)MR * DSTATE * 2);
  float* SL     = (float*)alloc((size_t)16 * 256 * 256 * 4);
  float* dt     = (float*)alloc((size_t)MR * NHD * 4);
  float* rsi    = (float*)alloc((size_t)MR * 4);
  float* acs    = (float*)alloc((size_t)512 * 256 * 4);
  float* ctot   = (float*)alloc((size_t)512 * 4);
  float* states = (float*)alloc((size_t)512 * 8192 * 4);
  float* inits  = (float*)alloc((size_t)512 * 8192 * 4);
  float* yb     = (float*)alloc((size_t)MR * DI * 4);
  bf16_t* yn    = (bf16_t*)alloc((size_t)MR * DI * 2);
  if (off > ws_size) return;

  rms1_kernel<<<MR, 256, 0, stream>>>(x, nw, ub, rsi);
  cvtw1_kernel<<<(NPAD * DM / 4) / 256, 256, 0, stream>>>(w1, w1b);
  cvtw2_kernel<<<(DM * DI / 4) / 256, 256, 0, stream>>>(w2, w2b);
  gemm_bt_kernel<false><<<dim3(MR / 128, NPAD / 128), 256, 0, stream>>>(ub, w1b, nullptr, zx, NPAD, DM);
  conv_kernel<<<(MR * CONVD) / 256, 256, 0, stream>>>(zx, cw, cb, xh, Bm, Cm, Bmh, Cmh);
  dtproj_kernel<<<MR / 16, 256, 0, stream>>>(x, rsi, nw, w1, dtb, dt);
  acs_kernel<<<512, 256, 0, stream>>>(dt, alog, acs, ctot);
  gemm_s_kernel<<<dim3(2, 2, 16), 256, 0, stream>>>(Cmh, Bmh, SL);
  states_kernel<<<512, 256, 0, stream>>>(xh, Bm, dt, acs, states);
  scan_kernel<<<(2 * 32 * 8192) / 256, 256, 0, stream>>>(states, ctot, inits);
  yk2_kernel<<<1024, 256, 0, stream>>>(SL, Cm, xh, dt, acs, inits, yb);
  gnorm_kernel<<<MR, 256, 0, stream>>>(yb, xh, zx, Dp, gw, yn);
  gemm_bt_kernel<true><<<dim3(MR / 128, DM / 128), 256, 0, stream>>>(yn, w2b, x, out, DM, DI);
}

// Round 3
// 337.378 us; speedup vs baseline: 2.8346x; 1.2970x over previous
//
#include <hip/hip_runtime.h>
#include <hip/hip_bf16.h>

typedef __hip_bfloat16 bf16_t;
typedef __attribute__((ext_vector_type(8))) short bfrag8;   // 8 bf16 (4 VGPRs)
typedef __attribute__((ext_vector_type(4))) float floatx4;  // MFMA acc

#define DM     1024
#define DI     2048
#define NHD    32
#define HD     64
#define DSTATE 128
#define CONVD  2304
#define NPROJ  4384
#define NPAD   4480
#define MR     4096      // B*L
#define LL     2048
#define EPSF   1e-5f
#define PSTR   40        // LDS row stride (bf16) for P/X tiles

__device__ __forceinline__ void gl_lds16(const void* g, void* l) {
  __builtin_amdgcn_global_load_lds((const __attribute__((address_space(1))) void*)g,
                                   (__attribute__((address_space(3))) void*)l, 16, 0, 0);
}
__device__ __forceinline__ unsigned pack_bf16_rn(float a, float b) {
  unsigned ua = (__float_as_uint(a) + 0x8000u) >> 16;
  unsigned ub = (__float_as_uint(b) + 0x8000u) >> 16;
  return ua | (ub << 16);
}
__device__ __forceinline__ float blo(unsigned u){ return __uint_as_float(u << 16); }
__device__ __forceinline__ float bhi(unsigned u){ return __uint_as_float(u & 0xffff0000u); }

// ---------------- rmsnorm(x) -> u (bf16) ----------------
__global__ void rms1_kernel(const float* __restrict__ x, const float* __restrict__ w,
                            bf16_t* __restrict__ ub) {
  int row = blockIdx.x, t = threadIdx.x;
  float4 v = ((const float4*)(x + (long)row * DM))[t];
  float ss = v.x*v.x + v.y*v.y + v.z*v.z + v.w*v.w;
#pragma unroll
  for (int off = 32; off > 0; off >>= 1) ss += __shfl_down(ss, off, 64);
  __shared__ float red[4];
  if ((t & 63) == 0) red[t >> 6] = ss;
  __syncthreads();
  float tot = red[0] + red[1] + red[2] + red[3];
  float rs = rsqrtf(tot * (1.f / DM) + EPSF);
  float4 wv = ((const float4*)w)[t];
  bf16_t* o = ub + (long)row * DM + t * 4;
  o[0] = __float2bfloat16(v.x * rs * wv.x);
  o[1] = __float2bfloat16(v.y * rs * wv.y);
  o[2] = __float2bfloat16(v.z * rs * wv.z);
  o[3] = __float2bfloat16(v.w * rs * wv.w);
}

// ---------------- weight fp32->bf16 ----------------
__global__ void cvtw1_kernel(const float* __restrict__ w, bf16_t* __restrict__ o) {
  int i4 = blockIdx.x * 256 + threadIdx.x;
  int idx = i4 * 4;
  int row = idx >> 10;
  float4 v = make_float4(0.f, 0.f, 0.f, 0.f);
  if (row < NPROJ) v = *(const float4*)(w + idx);
  bf16_t* d = o + idx;
  d[0] = __float2bfloat16(v.x); d[1] = __float2bfloat16(v.y);
  d[2] = __float2bfloat16(v.z); d[3] = __float2bfloat16(v.w);
}
__global__ void cvtw2_kernel(const float* __restrict__ w, bf16_t* __restrict__ o) {
  int i4 = blockIdx.x * 256 + threadIdx.x;
  int idx = i4 * 4;
  float4 v = *(const float4*)(w + idx);
  bf16_t* d = o + idx;
  d[0] = __float2bfloat16(v.x); d[1] = __float2bfloat16(v.y);
  d[2] = __float2bfloat16(v.z); d[3] = __float2bfloat16(v.w);
}

// ---------------- BK=64 swizzled MFMA GEMM: C[M,N] = A[M,K] @ B[N,K]^T ----------------
// LDS layout: row r's 16B k-chunk kc stored at chunk index kc ^ (r&7)  -> conflict-free frag reads
template<int TN, bool DO_RES, bool OUT_BF16>
__global__ __launch_bounds__(256) void gemm64_kernel(const bf16_t* __restrict__ A,
    const bf16_t* __restrict__ Bw, const float* __restrict__ resid,
    void* __restrict__ Cout, int N, int K) {
  __shared__ bf16_t As[128 * 64];
  __shared__ bf16_t Bs[TN * 64];
  const int tid = threadIdx.x;
  const int lane = tid & 63;
  const int wv = tid >> 6;
  const int l15 = lane & 15;
  const int l4 = lane >> 4;
  constexpr int MF = (TN == 128) ? 4 : 2;
  const int wm = (TN == 128) ? ((wv >> 1) << 6) : (wv << 5);
  const int wn = (TN == 128) ? ((wv & 1) << 6) : 0;
  const int tm = blockIdx.x << 7;
  const int tn = blockIdx.y * TN;

  floatx4 acc[MF][4];
#pragma unroll
  for (int i = 0; i < MF; i++)
#pragma unroll
    for (int j = 0; j < 4; j++) acc[i][j] = (floatx4){0.f, 0.f, 0.f, 0.f};

  const int r = tid >> 3;          // staging row 0..31
  const int c8 = tid & 7;          // staging chunk slot
  const int scol = ((c8 ^ (r & 7)) << 3);   // swizzled source k-offset
  const bf16_t* Ag = A + (long)(tm + r) * K + scol;
  const bf16_t* Bg = Bw + (long)(tn + r) * K + scol;
  const int swz = l15 & 7;

  for (int k0 = 0; k0 < K; k0 += 64) {
#pragma unroll
    for (int q = 0; q < 4; q++)
      gl_lds16(Ag + (long)(q * 32) * K + k0, &As[q * 2048 + tid * 8]);
#pragma unroll
    for (int q = 0; q < TN / 32; q++)
      gl_lds16(Bg + (long)(q * 32) * K + k0, &Bs[q * 2048 + tid * 8]);
    __syncthreads();
#pragma unroll
    for (int kk = 0; kk < 2; kk++) {
      bfrag8 af[MF], bfr[4];
      const int ch = ((kk << 2) | l4) ^ swz;
#pragma unroll
      for (int j = 0; j < 4; j++)
        bfr[j] = *(const bfrag8*)&Bs[(wn + j * 16 + l15) * 64 + ch * 8];
#pragma unroll
      for (int i = 0; i < MF; i++)
        af[i] = *(const bfrag8*)&As[(wm + i * 16 + l15) * 64 + ch * 8];
#pragma unroll
      for (int i = 0; i < MF; i++)
#pragma unroll
        for (int j = 0; j < 4; j++)
          acc[i][j] = __builtin_amdgcn_mfma_f32_16x16x32_bf16(af[i], bfr[j], acc[i][j], 0, 0, 0);
    }
    __syncthreads();
  }
#pragma unroll
  for (int i = 0; i < MF; i++)
#pragma unroll
    for (int j = 0; j < 4; j++)
#pragma unroll
      for (int r2 = 0; r2 < 4; r2++) {
        int row = tm + wm + i * 16 + l4 * 4 + r2;
        int col = tn + wn + j * 16 + l15;
        float v = acc[i][j][r2];
        if (OUT_BF16) {
          ((bf16_t*)Cout)[(long)row * N + col] = __float2bfloat16(v);
        } else {
          if (DO_RES) v += resid[(long)row * N + col];
          ((float*)Cout)[(long)row * N + col] = v;
        }
      }
}

// ---------------- batched S GEMM: SL[bc][l][s] = Cm[l].Bm[s] (M=N=256,K=128) ----------
__global__ __launch_bounds__(256) void gemm_s_kernel(const bf16_t* __restrict__ Cmh,
                const bf16_t* __restrict__ Bmh, float* __restrict__ SL) {
  __shared__ bf16_t As[128 * 32];
  __shared__ bf16_t Bs[128 * 32];
  const int tid = threadIdx.x;
  const int lane = tid & 63;
  const int wv = tid >> 6;
  const int wm = (wv >> 1) << 6;
  const int wn = (wv & 1) << 6;
  const int bc = blockIdx.z;
  const int tm = blockIdx.x << 7;
  const int tn = blockIdx.y << 7;
  const int l15 = lane & 15;
  const int l4 = lane >> 4;
  floatx4 acc[4][4];
#pragma unroll
  for (int i = 0; i < 4; i++)
#pragma unroll
    for (int j = 0; j < 4; j++) acc[i][j] = (floatx4){0.f, 0.f, 0.f, 0.f};
  const int arow = tid >> 2;
  const int acol = (tid & 3) << 3;
  const bf16_t* Ag = Cmh + (long)bc * 256 * DSTATE + (long)(tm + arow) * DSTATE + acol;
  const bf16_t* Bg = Bmh + (long)bc * 256 * DSTATE + (long)(tn + arow) * DSTATE + acol;
  const long k64 = (long)64 * DSTATE;
  for (int k0 = 0; k0 < DSTATE; k0 += 32) {
    gl_lds16(Ag + k0, &As[tid * 8]);
    gl_lds16(Ag + k64 + k0, &As[2048 + tid * 8]);
    gl_lds16(Bg + k0, &Bs[tid * 8]);
    gl_lds16(Bg + k64 + k0, &Bs[2048 + tid * 8]);
    __syncthreads();
    bfrag8 af[4], bfr[4];
#pragma unroll
    for (int i = 0; i < 4; i++)
      af[i] = *(const bfrag8*)&As[(wm + i * 16 + l15) * 32 + l4 * 8];
#pragma unroll
    for (int j = 0; j < 4; j++)
      bfr[j] = *(const bfrag8*)&Bs[(wn + j * 16 + l15) * 32 + l4 * 8];
#pragma unroll
    for (int i = 0; i < 4; i++)
#pragma unroll
      for (int j = 0; j < 4; j++)
        acc[i][j] = __builtin_amdgcn_mfma_f32_16x16x32_bf16(af[i], bfr[j], acc[i][j], 0, 0, 0);
    __syncthreads();
  }
  float* Cb = SL + (long)bc * 65536;
#pragma unroll
  for (int i = 0; i < 4; i++)
#pragma unroll
    for (int j = 0; j < 4; j++)
#pragma unroll
      for (int r = 0; r < 4; r++)
        Cb[(long)(tm + wm + i * 16 + l4 * 4 + r) * 256 + tn + wn + j * 16 + l15] = acc[i][j][r];
}

// ---------------- depthwise causal conv4 + bias + silu (bf16 in) ----------------
__global__ void conv_kernel(const bf16_t* __restrict__ zxh, const float* __restrict__ cw,
                            const float* __restrict__ cb, bf16_t* __restrict__ xhb,
                            float* __restrict__ Bm, float* __restrict__ Cm,
                            bf16_t* __restrict__ Bmh, bf16_t* __restrict__ Cmh) {
  int idx = blockIdx.x * 256 + threadIdx.x;
  int c = idx % CONVD;
  int bl = idx / CONVD;
  int l = bl & (LL - 1);
  const bf16_t* base = zxh + (long)(bl - l) * NPAD + DI + c;
  float acc = cb[c];
#pragma unroll
  for (int k = 0; k < 4; k++) {
    int ls = l + k - 3;
    if (ls >= 0) acc += __bfloat162float(base[(long)ls * NPAD]) * cw[c * 4 + k];
  }
  float s = acc / (1.f + __expf(-acc));
  if (c < DI) {
    xhb[(long)bl * DI + c] = __float2bfloat16(s);
  } else if (c < DI + DSTATE) {
    Bm[(long)bl * DSTATE + (c - DI)] = s;
    Bmh[(long)bl * DSTATE + (c - DI)] = __float2bfloat16(s);
  } else {
    Cm[(long)bl * DSTATE + (c - DI - DSTATE)] = s;
    Cmh[(long)bl * DSTATE + (c - DI - DSTATE)] = __float2bfloat16(s);
  }
}

// ---------------- softplus(dt)+cumsum(dt*A) per (b,c,h) ----------------
__global__ void acs_kernel(const bf16_t* __restrict__ zxh, const float* __restrict__ A_log,
                           const float* __restrict__ dtb,
                           float* __restrict__ acs, float* __restrict__ ctot,
                           float* __restrict__ dtout) {
  int blk = blockIdx.x;           // (b*8+c)*32+h
  int h = blk & 31, bc = blk >> 5;
  int t = threadIdx.x;
  float Ah = -__expf(A_log[h]);
  int gl = bc * 256 + t;
  float vv = __bfloat162float(zxh[(long)gl * NPAD + (NPROJ - 32) + h]) + dtb[h];
  float sp = fmaxf(vv, 0.f) + log1pf(__expf(-fabsf(vv)));
  dtout[gl * 32 + h] = sp;
  __shared__ float sc[256];
  sc[t] = sp * Ah;
  __syncthreads();
  for (int off = 1; off < 256; off <<= 1) {
    float v = (t >= off) ? sc[t - off] : 0.f;
    __syncthreads();
    sc[t] += v;
    __syncthreads();
  }
  acs[blk * 256 + t] = sc[t];
  if (t == 255) ctot[blk] = sc[255];
}

// ---------------- chunk states: S[p][n] = sum_l dt*decay*xh[l][p]*Bm[l][n] ------------
__global__ __launch_bounds__(256) void states_kernel(const bf16_t* __restrict__ xhb,
    const float* __restrict__ Bmp, const float* __restrict__ dt,
    const float* __restrict__ acs, float* __restrict__ states) {
  int blk = blockIdx.x;
  int h = blk & 31, bc = blk >> 5;
  int t = threadIdx.x;
  int p = t & 63, wv = t >> 6;
  __shared__ float Bs[64 * 128];
  __shared__ float Xs[64 * 64];
  float atot = acs[blk * 256 + 255];
  float acc[32];
#pragma unroll
  for (int j = 0; j < 32; j++) acc[j] = 0.f;
  for (int lt = 0; lt < 4; lt++) {
    __syncthreads();
    const float4* Bg = (const float4*)(Bmp + (long)(bc * 256 + lt * 64) * DSTATE);
#pragma unroll
    for (int i = 0; i < 8; i++) {
      int f4 = t + i * 256;
      ((float4*)Bs)[f4] = Bg[f4];
    }
#pragma unroll
    for (int i = 0; i < 2; i++) {
      int f8 = t + i * 256;       // 0..511
      int lr = f8 >> 3, p8 = f8 & 7;
      int gl = bc * 256 + lt * 64 + lr;
      float w = dt[gl * 32 + h] * __expf(atot - acs[blk * 256 + lt * 64 + lr]);
      uint4 u = *(const uint4*)(xhb + (long)gl * DI + h * HD + p8 * 8);
      float4 a = make_float4(blo(u.x) * w, bhi(u.x) * w, blo(u.y) * w, bhi(u.y) * w);
      float4 b = make_float4(blo(u.z) * w, bhi(u.z) * w, blo(u.w) * w, bhi(u.w) * w);
      ((float4*)&Xs[lr * 64 + p8 * 8])[0] = a;
      ((float4*)&Xs[lr * 64 + p8 * 8])[1] = b;
    }
    __syncthreads();
    for (int l = 0; l < 64; l++) {
      float xv = Xs[l * 64 + p];
      const float4* br = (const float4*)&Bs[l * 128 + wv * 32];
#pragma unroll
      for (int j = 0; j < 8; j++) {
        float4 b4 = br[j];
        acc[j * 4 + 0] += xv * b4.x; acc[j * 4 + 1] += xv * b4.y;
        acc[j * 4 + 2] += xv * b4.z; acc[j * 4 + 3] += xv * b4.w;
      }
    }
  }
  float4* sp = (float4*)(states + (long)blk * 8192 + p * 128 + wv * 32);
#pragma unroll
  for (int j = 0; j < 8; j++)
    sp[j] = make_float4(acc[j * 4], acc[j * 4 + 1], acc[j * 4 + 2], acc[j * 4 + 3]);
}

// ---------------- inter-chunk scan -> init states (bf16 out) ----------------
__global__ void scan_kernel(const float* __restrict__ states, const float* __restrict__ ctot,
                            bf16_t* __restrict__ initsb) {
  int id = blockIdx.x * 256 + threadIdx.x;   // < 2*32*8192
  int pn = id & 8191;
  int bh = id >> 13;
  int b = bh >> 5, h = bh & 31;
  float S = 0.f;
#pragma unroll
  for (int c = 0; c < 8; c++) {
    int blk = (b * 8 + c) * 32 + h;
    initsb[(long)blk * 8192 + pn] = __float2bfloat16(S);
    S = __expf(ctot[blk]) * S + states[(long)blk * 8192 + pn];
  }
}

// ---------------- MFMA Y + fused gating epilogue ----------------
// Y = (S.*L)@xd + (exp(acs)*Cm)@init^T ; then v=(Y+D*xh)*silu(z); yg=bf16(v); ssqp[row][h]=sum v^2
__global__ __launch_bounds__(256, 4) void yk2_kernel(const float* __restrict__ SL,
     const float* __restrict__ Cmp, const bf16_t* __restrict__ xhb,
     const bf16_t* __restrict__ zxh, const float* __restrict__ dt,
     const float* __restrict__ acs, const bf16_t* __restrict__ initsb,
     const float* __restrict__ Dp, bf16_t* __restrict__ yg, float* __restrict__ ssqp) {
  int bi = blockIdx.x;
  int mh = bi & 1, h = (bi >> 1) & 31, bc = bi >> 6;
  int ablk = bc * 32 + h;
  int t = threadIdx.x;
  int lane = t & 63, wv = t >> 6;
  int l15 = lane & 15, l4 = lane >> 4;
  __shared__ float acsS[256];
  __shared__ bf16_t Ps[128 * PSTR];
  __shared__ bf16_t Xs[64 * PSTR];

  acsS[t] = acs[ablk * 256 + t];
  __syncthreads();
  const int l_loc = t >> 1, half = t & 1;
  const int l = mh * 128 + l_loc;
  const float al = acsS[l];
  const float eAl = __expf(al);
  const int rowbase = bc * 256;
  const float* SLb = SL + (long)bc * 65536 + (long)l * 256;

  floatx4 acc[2][4];
#pragma unroll
  for (int i = 0; i < 2; i++)
#pragma unroll
    for (int j = 0; j < 4; j++) acc[i][j] = (floatx4){0.f, 0.f, 0.f, 0.f};

  const int nkd = (mh + 1) * 4;
  for (int kt = 0; kt < nkd + 4; kt++) {
    __syncthreads();
    if (kt < nkd) {
      int s0 = kt * 32 + half * 16;
      unsigned pk[8];
      const float4* Sg = (const float4*)(SLb + s0);
#pragma unroll
      for (int q = 0; q < 4; q++) {
        float4 v = Sg[q];
        int sb = s0 + q * 4;
        float p0 = (sb + 0 <= l) ? v.x * __expf(al - acsS[sb + 0]) : 0.f;
        float p1 = (sb + 1 <= l) ? v.y * __expf(al - acsS[sb + 1]) : 0.f;
        float p2 = (sb + 2 <= l) ? v.z * __expf(al - acsS[sb + 2]) : 0.f;
        float p3 = (sb + 3 <= l) ? v.w * __expf(al - acsS[sb + 3]) : 0.f;
        pk[q * 2 + 0] = pack_bf16_rn(p0, p1);
        pk[q * 2 + 1] = pack_bf16_rn(p2, p3);
      }
      uint4* pw = (uint4*)&Ps[l_loc * PSTR + half * 16];
      pw[0] = make_uint4(pk[0], pk[1], pk[2], pk[3]);
      pw[1] = make_uint4(pk[4], pk[5], pk[6], pk[7]);
      int p4 = t & 15, sh = t >> 4;
#pragma unroll
      for (int r = 0; r < 2; r++) {
        int s = sh + r * 16;
        int gl = rowbase + kt * 32 + s;
        float w = dt[gl * 32 + h];
        uint2 u = *(const uint2*)(xhb + (long)gl * DI + h * HD + p4 * 4);
        Xs[(p4 * 4 + 0) * PSTR + s] = __float2bfloat16(blo(u.x) * w);
        Xs[(p4 * 4 + 1) * PSTR + s] = __float2bfloat16(bhi(u.x) * w);
        Xs[(p4 * 4 + 2) * PSTR + s] = __float2bfloat16(blo(u.y) * w);
        Xs[(p4 * 4 + 3) * PSTR + s] = __float2bfloat16(bhi(u.y) * w);
      }
    } else {
      int n0 = (kt - nkd) * 32;
      unsigned pk[8];
      const float4* Cg = (const float4*)(Cmp + (long)(rowbase + l) * DSTATE + n0 + half * 16);
#pragma unroll
      for (int q = 0; q < 4; q++) {
        float4 v = Cg[q];
        pk[q * 2 + 0] = pack_bf16_rn(v.x * eAl, v.y * eAl);
        pk[q * 2 + 1] = pack_bf16_rn(v.z * eAl, v.w * eAl);
      }
      uint4* pw = (uint4*)&Ps[l_loc * PSTR + half * 16];
      pw[0] = make_uint4(pk[0], pk[1], pk[2], pk[3]);
      pw[1] = make_uint4(pk[4], pk[5], pk[6], pk[7]);
      int p_loc = t >> 2, quad = t & 3;
      uint4 u = *(const uint4*)(initsb + (long)ablk * 8192 + p_loc * 128 + n0 + quad * 8);
      *(uint4*)&Xs[p_loc * PSTR + quad * 8] = u;
    }
    __syncthreads();
    bfrag8 bfr[4];
#pragma unroll
    for (int j = 0; j < 4; j++)
      bfr[j] = *(const bfrag8*)&Xs[(j * 16 + l15) * PSTR + l4 * 8];
#pragma unroll
    for (int i = 0; i < 2; i++) {
      bfrag8 af = *(const bfrag8*)&Ps[(wv * 32 + i * 16 + l15) * PSTR + l4 * 8];
#pragma unroll
      for (int j = 0; j < 4; j++)
        acc[i][j] = __builtin_amdgcn_mfma_f32_16x16x32_bf16(af, bfr[j], acc[i][j], 0, 0, 0);
    }
  }
  // fused epilogue: v = (Y + D*xh) * silu(z); write bf16 + per-(row,h) ssq partial
  float Dh = Dp[h];
#pragma unroll
  for (int i = 0; i < 2; i++) {
#pragma unroll
    for (int r = 0; r < 4; r++) {
      int row = rowbase + mh * 128 + wv * 32 + i * 16 + l4 * 4 + r;
      float ss = 0.f;
#pragma unroll
      for (int j = 0; j < 4; j++) {
        int col = j * 16 + l15;
        float xv = __bfloat162float(xhb[(long)row * DI + h * HD + col]);
        float zv = __bfloat162float(zxh[(long)row * NPAD + h * HD + col]);
        float sz = zv / (1.f + __expf(-zv));
        float v = (acc[i][j][r] + Dh * xv) * sz;
        ss += v * v;
        yg[(long)row * DI + h * HD + col] = __float2bfloat16(v);
      }
      ss += __shfl_xor(ss, 1, 64);
      ss += __shfl_xor(ss, 2, 64);
      ss += __shfl_xor(ss, 4, 64);
      ss += __shfl_xor(ss, 8, 64);
      if (l15 == 0) ssqp[row * 32 + h] = ss;
    }
  }
}

// ---------------- light gated-rmsnorm finish ----------------
__global__ void gnorm2_kernel(const bf16_t* __restrict__ yg, const float* __restrict__ ssqp,
                              const float* __restrict__ gw, bf16_t* __restrict__ yn) {
  int row = blockIdx.x, t = threadIdx.x;
  __shared__ float rsS;
  if (t < 64) {
    float v = (t < 32) ? ssqp[row * 32 + t] : 0.f;
#pragma unroll
    for (int off = 16; off > 0; off >>= 1) v += __shfl_down(v, off, 64);
    if (t == 0) rsS = rsqrtf(v * (1.f / DI) + EPSF);
  }
  __syncthreads();
  float rs = rsS;
  uint4 u = *(const uint4*)(yg + (long)row * DI + t * 8);
  float4 g0 = ((const float4*)gw)[t * 2];
  float4 g1 = ((const float4*)gw)[t * 2 + 1];
  unsigned o0 = pack_bf16_rn(blo(u.x) * rs * g0.x, bhi(u.x) * rs * g0.y);
  unsigned o1 = pack_bf16_rn(blo(u.y) * rs * g0.z, bhi(u.y) * rs * g0.w);
  unsigned o2 = pack_bf16_rn(blo(u.z) * rs * g1.x, bhi(u.z) * rs * g1.y);
  unsigned o3 = pack_bf16_rn(blo(u.w) * rs * g1.z, bhi(u.w) * rs * g1.w);
  *(uint4*)(yn + (long)row * DI + t * 8) = make_uint4(o0, o1, o2, o3);
}

extern "C" void kernel_launch(void* const* d_in, const int* in_sizes, int n_in,
                              void* d_out, int out_size, void* d_ws, size_t ws_size,
                              hipStream_t stream) {
  const float* x    = (const float*)d_in[0];
  const float* nw   = (const float*)d_in[1];
  const float* w1   = (const float*)d_in[2];
  const float* cw   = (const float*)d_in[3];
  const float* cb   = (const float*)d_in[4];
  const float* dtb  = (const float*)d_in[5];
  const float* alog = (const float*)d_in[6];
  const float* Dp   = (const float*)d_in[7];
  const float* gw   = (const float*)d_in[8];
  const float* w2   = (const float*)d_in[9];
  float* out = (float*)d_out;

  char* ws = (char*)d_ws;
  size_t off = 0;
  auto alloc = [&](size_t bytes) -> void* {
    void* p = ws + off;
    off += (bytes + 255) & ~(size_t)255;
    return p;
  };
  bf16_t* ub     = (bf16_t*)alloc((size_t)MR * DM * 2);
  bf16_t* w1b    = (bf16_t*)alloc((size_t)NPAD * DM * 2);
  bf16_t* w2b    = (bf16_t*)alloc((size_t)DM * DI * 2);
  bf16_t* zxh    = (bf16_t*)alloc((size_t)MR * NPAD * 2);
  bf16_t* xhb    = (bf16_t*)alloc((size_t)MR * DI * 2);
  float* Bm      = (float*)alloc((size_t)MR * DSTATE * 4);
  float* Cm      = (float*)alloc((size_t)MR * DSTATE * 4);
  bf16_t* Bmh    = (bf16_t*)alloc((size_t)MR * DSTATE * 2);
  bf16_t* Cmh    = (bf16_t*)alloc((size_t)MR * DSTATE * 2);
  float* SL      = (float*)alloc((size_t)16 * 256 * 256 * 4);
  float* dt      = (float*)alloc((size_t)MR * NHD * 4);
  float* acs     = (float*)alloc((size_t)512 * 256 * 4);
  float* ctot    = (float*)alloc((size_t)512 * 4);
  float* states  = (float*)alloc((size_t)512 * 8192 * 4);
  bf16_t* initsb = (bf16_t*)alloc((size_t)512 * 8192 * 2);
  bf16_t* yg     = (bf16_t*)alloc((size_t)MR * DI * 2);
  float* ssqp    = (float*)alloc((size_t)MR * NHD * 4);
  bf16_t* yn     = (bf16_t*)alloc((size_t)MR * DI * 2);
  if (off > ws_size) return;

  rms1_kernel<<<MR, 256, 0, stream>>>(x, nw, ub);
  cvtw1_kernel<<<(NPAD * DM / 4) / 256, 256, 0, stream>>>(w1, w1b);
  cvtw2_kernel<<<(DM * DI / 4) / 256, 256, 0, stream>>>(w2, w2b);
  gemm64_kernel<128, false, true><<<dim3(MR / 128, NPAD / 128), 256, 0, stream>>>(
      ub, w1b, nullptr, zxh, NPAD, DM);
  conv_kernel<<<(MR * CONVD) / 256, 256, 0, stream>>>(zxh, cw, cb, xhb, Bm, Cm, Bmh, Cmh);
  acs_kernel<<<512, 256, 0, stream>>>(zxh, alog, dtb, acs, ctot, dt);
  gemm_s_kernel<<<dim3(2, 2, 16), 256, 0, stream>>>(Cmh, Bmh, SL);
  states_kernel<<<512, 256, 0, stream>>>(xhb, Bm, dt, acs, states);
  scan_kernel<<<(2 * 32 * 8192) / 256, 256, 0, stream>>>(states, ctot, initsb);
  yk2_kernel<<<1024, 256, 0, stream>>>(SL, Cm, xhb, zxh, dt, acs, initsb, Dp, yg, ssqp);
  gnorm2_kernel<<<MR, 256, 0, stream>>>(yg, ssqp, gw, yn);
  gemm64_kernel<64, true, false><<<dim3(MR / 128, DM / 64), 256, 0, stream>>>(
      yn, w2b, x, out, DM, DI);
}

// Round 4
// 306.379 us; speedup vs baseline: 3.1213x; 1.1012x over previous
//
#include <hip/hip_runtime.h>
#include <hip/hip_bf16.h>

typedef __hip_bfloat16 bf16_t;
typedef __attribute__((ext_vector_type(8))) short bfrag8;   // 8 bf16 (4 VGPRs)
typedef __attribute__((ext_vector_type(4))) float floatx4;  // MFMA acc

#define DM     1024
#define DI     2048
#define NHD    32
#define HD     64
#define DSTATE 128
#define CONVD  2304
#define NPROJ  4384
#define NPAD   4480
#define MR     4096      // B*L
#define LL     2048
#define EPSF   1e-5f
#define PSTR   40        // LDS row stride (bf16) for P/X tiles

__device__ __forceinline__ void gl_lds16(const void* g, void* l) {
  __builtin_amdgcn_global_load_lds((const __attribute__((address_space(1))) void*)g,
                                   (__attribute__((address_space(3))) void*)l, 16, 0, 0);
}
__device__ __forceinline__ unsigned pack_bf16_rn(float a, float b) {
  unsigned ua = (__float_as_uint(a) + 0x8000u) >> 16;
  unsigned ub = (__float_as_uint(b) + 0x8000u) >> 16;
  return ua | (ub << 16);
}
__device__ __forceinline__ unsigned short bf16u(float a) {
  return (unsigned short)((__float_as_uint(a) + 0x8000u) >> 16);
}
__device__ __forceinline__ float blo(unsigned u){ return __uint_as_float(u << 16); }
__device__ __forceinline__ float bhi(unsigned u){ return __uint_as_float(u & 0xffff0000u); }

// ---------------- rmsnorm(x) -> u (bf16) ----------------
__global__ void rms1_kernel(const float* __restrict__ x, const float* __restrict__ w,
                            bf16_t* __restrict__ ub) {
  int row = blockIdx.x, t = threadIdx.x;
  float4 v = ((const float4*)(x + (long)row * DM))[t];
  float ss = v.x*v.x + v.y*v.y + v.z*v.z + v.w*v.w;
#pragma unroll
  for (int off = 32; off > 0; off >>= 1) ss += __shfl_down(ss, off, 64);
  __shared__ float red[4];
  if ((t & 63) == 0) red[t >> 6] = ss;
  __syncthreads();
  float tot = red[0] + red[1] + red[2] + red[3];
  float rs = rsqrtf(tot * (1.f / DM) + EPSF);
  float4 wv = ((const float4*)w)[t];
  bf16_t* o = ub + (long)row * DM + t * 4;
  o[0] = __float2bfloat16(v.x * rs * wv.x);
  o[1] = __float2bfloat16(v.y * rs * wv.y);
  o[2] = __float2bfloat16(v.z * rs * wv.z);
  o[3] = __float2bfloat16(v.w * rs * wv.w);
}

// ---------------- weight fp32->bf16 ----------------
__global__ void cvtw1_kernel(const float* __restrict__ w, bf16_t* __restrict__ o) {
  int i4 = blockIdx.x * 256 + threadIdx.x;
  int idx = i4 * 4;
  int row = idx >> 10;
  float4 v = make_float4(0.f, 0.f, 0.f, 0.f);
  if (row < NPROJ) v = *(const float4*)(w + idx);
  bf16_t* d = o + idx;
  d[0] = __float2bfloat16(v.x); d[1] = __float2bfloat16(v.y);
  d[2] = __float2bfloat16(v.z); d[3] = __float2bfloat16(v.w);
}
__global__ void cvtw2_kernel(const float* __restrict__ w, bf16_t* __restrict__ o) {
  int i4 = blockIdx.x * 256 + threadIdx.x;
  int idx = i4 * 4;
  float4 v = *(const float4*)(w + idx);
  bf16_t* d = o + idx;
  d[0] = __float2bfloat16(v.x); d[1] = __float2bfloat16(v.y);
  d[2] = __float2bfloat16(v.z); d[3] = __float2bfloat16(v.w);
}

// ---------------- BK=64 swizzled MFMA GEMM: C[M,N] = A[M,K] @ B[N,K]^T ----------------
template<int TN, bool DO_RES, bool OUT_BF16>
__global__ __launch_bounds__(256) void gemm64_kernel(const bf16_t* __restrict__ A,
    const bf16_t* __restrict__ Bw, const float* __restrict__ resid,
    void* __restrict__ Cout, int N, int K) {
  __shared__ bf16_t As[128 * 64];
  __shared__ bf16_t Bs[TN * 64];
  const int tid = threadIdx.x;
  const int lane = tid & 63;
  const int wv = tid >> 6;
  const int l15 = lane & 15;
  const int l4 = lane >> 4;
  constexpr int MF = (TN == 128) ? 4 : 2;
  const int wm = (TN == 128) ? ((wv >> 1) << 6) : (wv << 5);
  const int wn = (TN == 128) ? ((wv & 1) << 6) : 0;
  const int tm = blockIdx.x << 7;
  const int tn = blockIdx.y * TN;

  floatx4 acc[MF][4];
#pragma unroll
  for (int i = 0; i < MF; i++)
#pragma unroll
    for (int j = 0; j < 4; j++) acc[i][j] = (floatx4){0.f, 0.f, 0.f, 0.f};

  const int r = tid >> 3;
  const int c8 = tid & 7;
  const int scol = ((c8 ^ (r & 7)) << 3);
  const bf16_t* Ag = A + (long)(tm + r) * K + scol;
  const bf16_t* Bg = Bw + (long)(tn + r) * K + scol;
  const int swz = l15 & 7;

  for (int k0 = 0; k0 < K; k0 += 64) {
#pragma unroll
    for (int q = 0; q < 4; q++)
      gl_lds16(Ag + (long)(q * 32) * K + k0, &As[q * 2048 + tid * 8]);
#pragma unroll
    for (int q = 0; q < TN / 32; q++)
      gl_lds16(Bg + (long)(q * 32) * K + k0, &Bs[q * 2048 + tid * 8]);
    __syncthreads();
#pragma unroll
    for (int kk = 0; kk < 2; kk++) {
      bfrag8 af[MF], bfr[4];
      const int ch = ((kk << 2) | l4) ^ swz;
#pragma unroll
      for (int j = 0; j < 4; j++)
        bfr[j] = *(const bfrag8*)&Bs[(wn + j * 16 + l15) * 64 + ch * 8];
#pragma unroll
      for (int i = 0; i < MF; i++)
        af[i] = *(const bfrag8*)&As[(wm + i * 16 + l15) * 64 + ch * 8];
#pragma unroll
      for (int i = 0; i < MF; i++)
#pragma unroll
        for (int j = 0; j < 4; j++)
          acc[i][j] = __builtin_amdgcn_mfma_f32_16x16x32_bf16(af[i], bfr[j], acc[i][j], 0, 0, 0);
    }
    __syncthreads();
  }
#pragma unroll
  for (int i = 0; i < MF; i++)
#pragma unroll
    for (int j = 0; j < 4; j++)
#pragma unroll
      for (int r2 = 0; r2 < 4; r2++) {
        int row = tm + wm + i * 16 + l4 * 4 + r2;
        int col = tn + wn + j * 16 + l15;
        float v = acc[i][j][r2];
        if (OUT_BF16) {
          ((bf16_t*)Cout)[(long)row * N + col] = __float2bfloat16(v);
        } else {
          if (DO_RES) v += resid[(long)row * N + col];
          ((float*)Cout)[(long)row * N + col] = v;
        }
      }
}

// ---------------- batched S GEMM: SL[bc][l][s] = Cm[l].Bm[s] (M=N=256,K=128) ----------
__global__ __launch_bounds__(256) void gemm_s_kernel(const bf16_t* __restrict__ Cmh,
                const bf16_t* __restrict__ Bmh, float* __restrict__ SL) {
  __shared__ bf16_t As[128 * 32];
  __shared__ bf16_t Bs[128 * 32];
  const int tid = threadIdx.x;
  const int lane = tid & 63;
  const int wv = tid >> 6;
  const int wm = (wv >> 1) << 6;
  const int wn = (wv & 1) << 6;
  const int bc = blockIdx.z;
  const int tm = blockIdx.x << 7;
  const int tn = blockIdx.y << 7;
  const int l15 = lane & 15;
  const int l4 = lane >> 4;
  floatx4 acc[4][4];
#pragma unroll
  for (int i = 0; i < 4; i++)
#pragma unroll
    for (int j = 0; j < 4; j++) acc[i][j] = (floatx4){0.f, 0.f, 0.f, 0.f};
  const int arow = tid >> 2;
  const int acol = (tid & 3) << 3;
  const bf16_t* Ag = Cmh + (long)bc * 256 * DSTATE + (long)(tm + arow) * DSTATE + acol;
  const bf16_t* Bg = Bmh + (long)bc * 256 * DSTATE + (long)(tn + arow) * DSTATE + acol;
  const long k64 = (long)64 * DSTATE;
  for (int k0 = 0; k0 < DSTATE; k0 += 32) {
    gl_lds16(Ag + k0, &As[tid * 8]);
    gl_lds16(Ag + k64 + k0, &As[2048 + tid * 8]);
    gl_lds16(Bg + k0, &Bs[tid * 8]);
    gl_lds16(Bg + k64 + k0, &Bs[2048 + tid * 8]);
    __syncthreads();
    bfrag8 af[4], bfr[4];
#pragma unroll
    for (int i = 0; i < 4; i++)
      af[i] = *(const bfrag8*)&As[(wm + i * 16 + l15) * 32 + l4 * 8];
#pragma unroll
    for (int j = 0; j < 4; j++)
      bfr[j] = *(const bfrag8*)&Bs[(wn + j * 16 + l15) * 32 + l4 * 8];
#pragma unroll
    for (int i = 0; i < 4; i++)
#pragma unroll
      for (int j = 0; j < 4; j++)
        acc[i][j] = __builtin_amdgcn_mfma_f32_16x16x32_bf16(af[i], bfr[j], acc[i][j], 0, 0, 0);
    __syncthreads();
  }
  float* Cb = SL + (long)bc * 65536;
#pragma unroll
  for (int i = 0; i < 4; i++)
#pragma unroll
    for (int j = 0; j < 4; j++)
#pragma unroll
      for (int r = 0; r < 4; r++)
        Cb[(long)(tm + wm + i * 16 + l4 * 4 + r) * 256 + tn + wn + j * 16 + l15] = acc[i][j][r];
}

// ---------------- depthwise causal conv4 + bias + silu (bf16 in) ----------------
__global__ void conv_kernel(const bf16_t* __restrict__ zxh, const float* __restrict__ cw,
                            const float* __restrict__ cb, bf16_t* __restrict__ xhb,
                            float* __restrict__ Cm,
                            bf16_t* __restrict__ Bmh, bf16_t* __restrict__ Cmh) {
  int idx = blockIdx.x * 256 + threadIdx.x;
  int c = idx % CONVD;
  int bl = idx / CONVD;
  int l = bl & (LL - 1);
  const bf16_t* base = zxh + (long)(bl - l) * NPAD + DI + c;
  float acc = cb[c];
#pragma unroll
  for (int k = 0; k < 4; k++) {
    int ls = l + k - 3;
    if (ls >= 0) acc += __bfloat162float(base[(long)ls * NPAD]) * cw[c * 4 + k];
  }
  float s = acc / (1.f + __expf(-acc));
  if (c < DI) {
    xhb[(long)bl * DI + c] = __float2bfloat16(s);
  } else if (c < DI + DSTATE) {
    Bmh[(long)bl * DSTATE + (c - DI)] = __float2bfloat16(s);
  } else {
    Cm[(long)bl * DSTATE + (c - DI - DSTATE)] = s;
    Cmh[(long)bl * DSTATE + (c - DI - DSTATE)] = __float2bfloat16(s);
  }
}

// ---------------- softplus(dt)+cumsum(dt*A) per (b,c,h) — shfl scan ----------------
__global__ void acs_kernel(const bf16_t* __restrict__ zxh, const float* __restrict__ A_log,
                           const float* __restrict__ dtb,
                           float* __restrict__ acs, float* __restrict__ ctot,
                           float* __restrict__ dtout) {
  int blk = blockIdx.x;           // (b*8+c)*32+h
  int h = blk & 31, bc = blk >> 5;
  int t = threadIdx.x, lane = t & 63, w = t >> 6;
  float Ah = -__expf(A_log[h]);
  int gl = bc * 256 + t;
  float vv = __bfloat162float(zxh[(long)gl * NPAD + (NPROJ - 32) + h]) + dtb[h];
  float sp = fmaxf(vv, 0.f) + log1pf(__expf(-fabsf(vv)));
  dtout[gl * 32 + h] = sp;
  float a = sp * Ah;
#pragma unroll
  for (int off = 1; off < 64; off <<= 1) {
    float v = __shfl_up(a, off, 64);
    if (lane >= off) a += v;
  }
  __shared__ float wsum[4];
  if (lane == 63) wsum[w] = a;
  __syncthreads();
  float base = 0.f;
  for (int i = 0; i < 4; i++) base += (i < w) ? wsum[i] : 0.f;
  a += base;
  acs[blk * 256 + t] = a;
  if (t == 255) ctot[blk] = a;
}

// ---------------- MFMA chunk states: states[p][n] = sum_l xd_w[l][p]*Bm[l][n] ---------
__global__ __launch_bounds__(256) void states2_kernel(const bf16_t* __restrict__ xhb,
    const bf16_t* __restrict__ Bmh, const float* __restrict__ dt,
    const float* __restrict__ acs, float* __restrict__ states) {
  int blk = blockIdx.x;
  int h = blk & 31, bc = blk >> 5;
  int t = threadIdx.x, lane = t & 63, wv = t >> 6;
  int l15 = lane & 15, l4 = lane >> 4;
  __shared__ unsigned short Asb[128 * 40];   // BmT[n][l]
  __shared__ unsigned short Bsb[64 * 40];    // XdT[p][l]
  float atot = acs[blk * 256 + 255];
  const int rowbase = bc * 256;
  floatx4 acc[2][4];
#pragma unroll
  for (int i = 0; i < 2; i++)
#pragma unroll
    for (int j = 0; j < 4; j++) acc[i][j] = (floatx4){0.f, 0.f, 0.f, 0.f};

  const int ls = t & 31;      // l within k-tile
  const int grp = t >> 5;     // 0..7
  for (int kt = 0; kt < 8; kt++) {
    __syncthreads();
    int gl = rowbase + kt * 32 + ls;
    {   // BmT: 16 n-values per thread
      const uint4* src = (const uint4*)(Bmh + (long)gl * DSTATE + grp * 16);
      uint4 u0 = src[0], u1 = src[1];
      int n0 = grp * 16;
      Asb[(n0 + 0) * 40 + ls] = (unsigned short)(u0.x & 0xffff);
      Asb[(n0 + 1) * 40 + ls] = (unsigned short)(u0.x >> 16);
      Asb[(n0 + 2) * 40 + ls] = (unsigned short)(u0.y & 0xffff);
      Asb[(n0 + 3) * 40 + ls] = (unsigned short)(u0.y >> 16);
      Asb[(n0 + 4) * 40 + ls] = (unsigned short)(u0.z & 0xffff);
      Asb[(n0 + 5) * 40 + ls] = (unsigned short)(u0.z >> 16);
      Asb[(n0 + 6) * 40 + ls] = (unsigned short)(u0.w & 0xffff);
      Asb[(n0 + 7) * 40 + ls] = (unsigned short)(u0.w >> 16);
      Asb[(n0 + 8) * 40 + ls] = (unsigned short)(u1.x & 0xffff);
      Asb[(n0 + 9) * 40 + ls] = (unsigned short)(u1.x >> 16);
      Asb[(n0 + 10) * 40 + ls] = (unsigned short)(u1.y & 0xffff);
      Asb[(n0 + 11) * 40 + ls] = (unsigned short)(u1.y >> 16);
      Asb[(n0 + 12) * 40 + ls] = (unsigned short)(u1.z & 0xffff);
      Asb[(n0 + 13) * 40 + ls] = (unsigned short)(u1.z >> 16);
      Asb[(n0 + 14) * 40 + ls] = (unsigned short)(u1.w & 0xffff);
      Asb[(n0 + 15) * 40 + ls] = (unsigned short)(u1.w >> 16);
    }
    {   // XdT: 8 p-values per thread, scaled by dt*decay
      float w = dt[gl * 32 + h] * __expf(atot - acs[blk * 256 + kt * 32 + ls]);
      uint4 u = *(const uint4*)(xhb + (long)gl * DI + h * HD + grp * 8);
      int p0 = grp * 8;
      Bsb[(p0 + 0) * 40 + ls] = bf16u(blo(u.x) * w);
      Bsb[(p0 + 1) * 40 + ls] = bf16u(bhi(u.x) * w);
      Bsb[(p0 + 2) * 40 + ls] = bf16u(blo(u.y) * w);
      Bsb[(p0 + 3) * 40 + ls] = bf16u(bhi(u.y) * w);
      Bsb[(p0 + 4) * 40 + ls] = bf16u(blo(u.z) * w);
      Bsb[(p0 + 5) * 40 + ls] = bf16u(bhi(u.z) * w);
      Bsb[(p0 + 6) * 40 + ls] = bf16u(blo(u.w) * w);
      Bsb[(p0 + 7) * 40 + ls] = bf16u(bhi(u.w) * w);
    }
    __syncthreads();
    bfrag8 af[2], bfr[4];
#pragma unroll
    for (int i = 0; i < 2; i++)
      af[i] = *(const bfrag8*)&Asb[(wv * 32 + i * 16 + l15) * 40 + l4 * 8];
#pragma unroll
    for (int j = 0; j < 4; j++)
      bfr[j] = *(const bfrag8*)&Bsb[(j * 16 + l15) * 40 + l4 * 8];
#pragma unroll
    for (int i = 0; i < 2; i++)
#pragma unroll
      for (int j = 0; j < 4; j++)
        acc[i][j] = __builtin_amdgcn_mfma_f32_16x16x32_bf16(af[i], bfr[j], acc[i][j], 0, 0, 0);
  }
  // D rows = n (m-dim), cols = p: states[p][n] -> float4 along n
#pragma unroll
  for (int i = 0; i < 2; i++)
#pragma unroll
    for (int j = 0; j < 4; j++) {
      int n_base = wv * 32 + i * 16 + l4 * 4;
      int p = j * 16 + l15;
      *(float4*)&states[(long)blk * 8192 + p * 128 + n_base] =
          make_float4(acc[i][j][0], acc[i][j][1], acc[i][j][2], acc[i][j][3]);
    }
}

// ---------------- inter-chunk scan -> init states (bf16 out) ----------------
__global__ void scan_kernel(const float* __restrict__ states, const float* __restrict__ ctot,
                            bf16_t* __restrict__ initsb) {
  int id = blockIdx.x * 256 + threadIdx.x;   // < 2*32*8192
  int pn = id & 8191;
  int bh = id >> 13;
  int b = bh >> 5, h = bh & 31;
  float S = 0.f;
#pragma unroll
  for (int c = 0; c < 8; c++) {
    int blk = (b * 8 + c) * 32 + h;
    initsb[(long)blk * 8192 + pn] = __float2bfloat16(S);
    S = __expf(ctot[blk]) * S + states[(long)blk * 8192 + pn];
  }
}

// ---------------- MFMA Y + LDS-roundtrip fused gating epilogue ----------------
__global__ __launch_bounds__(256, 4) void yk2_kernel(const float* __restrict__ SL,
     const float* __restrict__ Cmp, const bf16_t* __restrict__ xhb,
     const bf16_t* __restrict__ zxh, const float* __restrict__ dt,
     const float* __restrict__ acs, const bf16_t* __restrict__ initsb,
     const float* __restrict__ Dp, bf16_t* __restrict__ yg, float* __restrict__ ssqp) {
  int bi = blockIdx.x;
  int mh = bi & 1, h = (bi >> 1) & 31, bc = bi >> 6;
  int ablk = bc * 32 + h;
  int t = threadIdx.x;
  int lane = t & 63, wv = t >> 6;
  int l15 = lane & 15, l4 = lane >> 4;
  __shared__ float acsS[256];
  __shared__ __align__(16) char ubuf[128 * 66 * 4];   // union: {Ps,Xs} / Ytile
  bf16_t* Ps = (bf16_t*)ubuf;                          // [128][PSTR]
  bf16_t* Xs = (bf16_t*)(ubuf + 128 * PSTR * 2);       // [64][PSTR]
  float* Yt = (float*)ubuf;                            // [128][66]

  acsS[t] = acs[ablk * 256 + t];
  __syncthreads();
  const int l_loc = t >> 1, half = t & 1;
  const int l = mh * 128 + l_loc;
  const float al = acsS[l];
  const float eAl = __expf(al);
  const int rowbase = bc * 256;
  const float* SLb = SL + (long)bc * 65536 + (long)l * 256;

  floatx4 acc[2][4];
#pragma unroll
  for (int i = 0; i < 2; i++)
#pragma unroll
    for (int j = 0; j < 4; j++) acc[i][j] = (floatx4){0.f, 0.f, 0.f, 0.f};

  const int nkd = (mh + 1) * 4;
  for (int kt = 0; kt < nkd + 4; kt++) {
    __syncthreads();
    if (kt < nkd) {
      int s0 = kt * 32 + half * 16;
      unsigned pk[8];
      const float4* Sg = (const float4*)(SLb + s0);
#pragma unroll
      for (int q = 0; q < 4; q++) {
        float4 v = Sg[q];
        int sb = s0 + q * 4;
        float p0 = (sb + 0 <= l) ? v.x * __expf(al - acsS[sb + 0]) : 0.f;
        float p1 = (sb + 1 <= l) ? v.y * __expf(al - acsS[sb + 1]) : 0.f;
        float p2 = (sb + 2 <= l) ? v.z * __expf(al - acsS[sb + 2]) : 0.f;
        float p3 = (sb + 3 <= l) ? v.w * __expf(al - acsS[sb + 3]) : 0.f;
        pk[q * 2 + 0] = pack_bf16_rn(p0, p1);
        pk[q * 2 + 1] = pack_bf16_rn(p2, p3);
      }
      uint4* pw = (uint4*)&Ps[l_loc * PSTR + half * 16];
      pw[0] = make_uint4(pk[0], pk[1], pk[2], pk[3]);
      pw[1] = make_uint4(pk[4], pk[5], pk[6], pk[7]);
      int p4 = t & 15, sh = t >> 4;
#pragma unroll
      for (int r = 0; r < 2; r++) {
        int s = sh + r * 16;
        int gl = rowbase + kt * 32 + s;
        float w = dt[gl * 32 + h];
        uint2 u = *(const uint2*)(xhb + (long)gl * DI + h * HD + p4 * 4);
        Xs[(p4 * 4 + 0) * PSTR + s] = __float2bfloat16(blo(u.x) * w);
        Xs[(p4 * 4 + 1) * PSTR + s] = __float2bfloat16(bhi(u.x) * w);
        Xs[(p4 * 4 + 2) * PSTR + s] = __float2bfloat16(blo(u.y) * w);
        Xs[(p4 * 4 + 3) * PSTR + s] = __float2bfloat16(bhi(u.y) * w);
      }
    } else {
      int n0 = (kt - nkd) * 32;
      unsigned pk[8];
      const float4* Cg = (const float4*)(Cmp + (long)(rowbase + l) * DSTATE + n0 + half * 16);
#pragma unroll
      for (int q = 0; q < 4; q++) {
        float4 v = Cg[q];
        pk[q * 2 + 0] = pack_bf16_rn(v.x * eAl, v.y * eAl);
        pk[q * 2 + 1] = pack_bf16_rn(v.z * eAl, v.w * eAl);
      }
      uint4* pw = (uint4*)&Ps[l_loc * PSTR + half * 16];
      pw[0] = make_uint4(pk[0], pk[1], pk[2], pk[3]);
      pw[1] = make_uint4(pk[4], pk[5], pk[6], pk[7]);
      int p_loc = t >> 2, quad = t & 3;
      uint4 u = *(const uint4*)(initsb + (long)ablk * 8192 + p_loc * 128 + n0 + quad * 8);
      *(uint4*)&Xs[p_loc * PSTR + quad * 8] = u;
    }
    __syncthreads();
    bfrag8 bfr[4];
#pragma unroll
    for (int j = 0; j < 4; j++)
      bfr[j] = *(const bfrag8*)&Xs[(j * 16 + l15) * PSTR + l4 * 8];
#pragma unroll
    for (int i = 0; i < 2; i++) {
      bfrag8 af = *(const bfrag8*)&Ps[(wv * 32 + i * 16 + l15) * PSTR + l4 * 8];
#pragma unroll
      for (int j = 0; j < 4; j++)
        acc[i][j] = __builtin_amdgcn_mfma_f32_16x16x32_bf16(af, bfr[j], acc[i][j], 0, 0, 0);
    }
  }
  // ---- epilogue: dump Y to LDS, re-read row-major, vectorized gating ----
  __syncthreads();
#pragma unroll
  for (int i = 0; i < 2; i++)
#pragma unroll
    for (int j = 0; j < 4; j++)
#pragma unroll
      for (int r = 0; r < 4; r++)
        Yt[(wv * 32 + i * 16 + l4 * 4 + r) * 66 + j * 16 + l15] = acc[i][j][r];
  __syncthreads();
  {
    int row_l = t >> 1;
    int ch = (t & 1) * 32;
    long rowg = rowbase + mh * 128 + row_l;
    float Dh = Dp[h];
    float ss = 0.f;
#pragma unroll
    for (int it = 0; it < 4; it++) {
      int c = ch + it * 8;
      float4 y0 = *(const float4*)&Yt[row_l * 66 + c];
      float4 y1 = *(const float4*)&Yt[row_l * 66 + c + 4];
      uint4 ux = *(const uint4*)(xhb + rowg * DI + h * HD + c);
      uint4 uz = *(const uint4*)(zxh + rowg * NPAD + h * HD + c);
      float xv[8] = {blo(ux.x), bhi(ux.x), blo(ux.y), bhi(ux.y),
                     blo(ux.z), bhi(ux.z), blo(ux.w), bhi(ux.w)};
      float zv[8] = {blo(uz.x), bhi(uz.x), blo(uz.y), bhi(uz.y),
                     blo(uz.z), bhi(uz.z), blo(uz.w), bhi(uz.w)};
      float yv[8] = {y0.x, y0.y, y0.z, y0.w, y1.x, y1.y, y1.z, y1.w};
      unsigned o[4];
#pragma unroll
      for (int q = 0; q < 4; q++) {
        float v0 = (yv[q * 2 + 0] + Dh * xv[q * 2 + 0]) *
                   (zv[q * 2 + 0] / (1.f + __expf(-zv[q * 2 + 0])));
        float v1 = (yv[q * 2 + 1] + Dh * xv[q * 2 + 1]) *
                   (zv[q * 2 + 1] / (1.f + __expf(-zv[q * 2 + 1])));
        ss += v0 * v0 + v1 * v1;
        o[q] = pack_bf16_rn(v0, v1);
      }
      *(uint4*)(yg + rowg * DI + h * HD + c) = make_uint4(o[0], o[1], o[2], o[3]);
    }
    ss += __shfl_xor(ss, 1, 64);
    if ((t & 1) == 0) ssqp[rowg * 32 + h] = ss;
  }
}

// ---------------- light gated-rmsnorm finish ----------------
__global__ void gnorm2_kernel(const bf16_t* __restrict__ yg, const float* __restrict__ ssqp,
                              const float* __restrict__ gw, bf16_t* __restrict__ yn) {
  int row = blockIdx.x, t = threadIdx.x;
  __shared__ float rsS;
  if (t < 64) {
    float v = (t < 32) ? ssqp[row * 32 + t] : 0.f;
#pragma unroll
    for (int off = 16; off > 0; off >>= 1) v += __shfl_down(v, off, 64);
    if (t == 0) rsS = rsqrtf(v * (1.f / DI) + EPSF);
  }
  __syncthreads();
  float rs = rsS;
  uint4 u = *(const uint4*)(yg + (long)row * DI + t * 8);
  float4 g0 = ((const float4*)gw)[t * 2];
  float4 g1 = ((const float4*)gw)[t * 2 + 1];
  unsigned o0 = pack_bf16_rn(blo(u.x) * rs * g0.x, bhi(u.x) * rs * g0.y);
  unsigned o1 = pack_bf16_rn(blo(u.y) * rs * g0.z, bhi(u.y) * rs * g0.w);
  unsigned o2 = pack_bf16_rn(blo(u.z) * rs * g1.x, bhi(u.z) * rs * g1.y);
  unsigned o3 = pack_bf16_rn(blo(u.w) * rs * g1.z, bhi(u.w) * rs * g1.w);
  *(uint4*)(yn + (long)row * DI + t * 8) = make_uint4(o0, o1, o2, o3);
}

extern "C" void kernel_launch(void* const* d_in, const int* in_sizes, int n_in,
                              void* d_out, int out_size, void* d_ws, size_t ws_size,
                              hipStream_t stream) {
  const float* x    = (const float*)d_in[0];
  const float* nw   = (const float*)d_in[1];
  const float* w1   = (const float*)d_in[2];
  const float* cw   = (const float*)d_in[3];
  const float* cb   = (const float*)d_in[4];
  const float* dtb  = (const float*)d_in[5];
  const float* alog = (const float*)d_in[6];
  const float* Dp   = (const float*)d_in[7];
  const float* gw   = (const float*)d_in[8];
  const float* w2   = (const float*)d_in[9];
  float* out = (float*)d_out;

  char* ws = (char*)d_ws;
  size_t off = 0;
  auto alloc = [&](size_t bytes) -> void* {
    void* p = ws + off;
    off += (bytes + 255) & ~(size_t)255;
    return p;
  };
  bf16_t* ub     = (bf16_t*)alloc((size_t)MR * DM * 2);
  bf16_t* w1b    = (bf16_t*)alloc((size_t)NPAD * DM * 2);
  bf16_t* w2b    = (bf16_t*)alloc((size_t)DM * DI * 2);
  bf16_t* zxh    = (bf16_t*)alloc((size_t)MR * NPAD * 2);
  bf16_t* xhb    = (bf16_t*)alloc((size_t)MR * DI * 2);
  float* Cm      = (float*)alloc((size_t)MR * DSTATE * 4);
  bf16_t* Bmh    = (bf16_t*)alloc((size_t)MR * DSTATE * 2);
  bf16_t* Cmh    = (bf16_t*)alloc((size_t)MR * DSTATE * 2);
  float* SL      = (float*)alloc((size_t)16 * 256 * 256 * 4);
  float* dt      = (float*)alloc((size_t)MR * NHD * 4);
  float* acs     = (float*)alloc((size_t)512 * 256 * 4);
  float* ctot    = (float*)alloc((size_t)512 * 4);
  float* states  = (float*)alloc((size_t)512 * 8192 * 4);
  bf16_t* initsb = (bf16_t*)alloc((size_t)512 * 8192 * 2);
  bf16_t* yg     = (bf16_t*)alloc((size_t)MR * DI * 2);
  float* ssqp    = (float*)alloc((size_t)MR * NHD * 4);
  bf16_t* yn     = (bf16_t*)alloc((size_t)MR * DI * 2);
  if (off > ws_size) return;

  rms1_kernel<<<MR, 256, 0, stream>>>(x, nw, ub);
  cvtw1_kernel<<<(NPAD * DM / 4) / 256, 256, 0, stream>>>(w1, w1b);
  cvtw2_kernel<<<(DM * DI / 4) / 256, 256, 0, stream>>>(w2, w2b);
  gemm64_kernel<128, false, true><<<dim3(MR / 128, NPAD / 128), 256, 0, stream>>>(
      ub, w1b, nullptr, zxh, NPAD, DM);
  conv_kernel<<<(MR * CONVD) / 256, 256, 0, stream>>>(zxh, cw, cb, xhb, Cm, Bmh, Cmh);
  acs_kernel<<<512, 256, 0, stream>>>(zxh, alog, dtb, acs, ctot, dt);
  gemm_s_kernel<<<dim3(2, 2, 16), 256, 0, stream>>>(Cmh, Bmh, SL);
  states2_kernel<<<512, 256, 0, stream>>>(xhb, Bmh, dt, acs, states);
  scan_kernel<<<(2 * 32 * 8192) / 256, 256, 0, stream>>>(states, ctot, initsb);
  yk2_kernel<<<1024, 256, 0, stream>>>(SL, Cm, xhb, zxh, dt, acs, initsb, Dp, yg, ssqp);
  gnorm2_kernel<<<MR, 256, 0, stream>>>(yg, ssqp, gw, yn);
  gemm64_kernel<64, true, false><<<dim3(MR / 128, DM / 64), 256, 0, stream>>>(
      yn, w2b, x, out, DM, DI);
}

// Round 5
// 296.756 us; speedup vs baseline: 3.2226x; 1.0324x over previous
//
#include <hip/hip_runtime.h>
#include <hip/hip_bf16.h>

typedef __hip_bfloat16 bf16_t;
typedef __attribute__((ext_vector_type(8))) short bfrag8;   // 8 bf16 (4 VGPRs)
typedef __attribute__((ext_vector_type(4))) float floatx4;  // MFMA acc

#define DM     1024
#define DI     2048
#define NHD    32
#define HD     64
#define DSTATE 128
#define CONVD  2304
#define NPROJ  4384
#define NPAD   4480
#define MR     4096      // B*L
#define LL     2048
#define EPSF   1e-5f
#define PSTR   40        // LDS row stride (bf16) for P tiles

__device__ __forceinline__ void gl_lds16(const void* g, void* l) {
  __builtin_amdgcn_global_load_lds((const __attribute__((address_space(1))) void*)g,
                                   (__attribute__((address_space(3))) void*)l, 16, 0, 0);
}
__device__ __forceinline__ unsigned pack_bf16_rn(float a, float b) {
  unsigned ua = (__float_as_uint(a) + 0x8000u) >> 16;
  unsigned ub = (__float_as_uint(b) + 0x8000u) >> 16;
  return ua | (ub << 16);
}
__device__ __forceinline__ unsigned short bf16u(float a) {
  return (unsigned short)((__float_as_uint(a) + 0x8000u) >> 16);
}
__device__ __forceinline__ float blo(unsigned u){ return __uint_as_float(u << 16); }
__device__ __forceinline__ float bhi(unsigned u){ return __uint_as_float(u & 0xffff0000u); }
__device__ __forceinline__ void unp8(uint4 u, float* v) {
  v[0]=blo(u.x); v[1]=bhi(u.x); v[2]=blo(u.y); v[3]=bhi(u.y);
  v[4]=blo(u.z); v[5]=bhi(u.z); v[6]=blo(u.w); v[7]=bhi(u.w);
}

// ---------------- rmsnorm(x) -> u (bf16) ----------------
__global__ void rms1_kernel(const float* __restrict__ x, const float* __restrict__ w,
                            bf16_t* __restrict__ ub) {
  int row = blockIdx.x, t = threadIdx.x;
  float4 v = ((const float4*)(x + (long)row * DM))[t];
  float ss = v.x*v.x + v.y*v.y + v.z*v.z + v.w*v.w;
#pragma unroll
  for (int off = 32; off > 0; off >>= 1) ss += __shfl_down(ss, off, 64);
  __shared__ float red[4];
  if ((t & 63) == 0) red[t >> 6] = ss;
  __syncthreads();
  float tot = red[0] + red[1] + red[2] + red[3];
  float rs = rsqrtf(tot * (1.f / DM) + EPSF);
  float4 wv = ((const float4*)w)[t];
  bf16_t* o = ub + (long)row * DM + t * 4;
  o[0] = __float2bfloat16(v.x * rs * wv.x);
  o[1] = __float2bfloat16(v.y * rs * wv.y);
  o[2] = __float2bfloat16(v.z * rs * wv.z);
  o[3] = __float2bfloat16(v.w * rs * wv.w);
}

// ---------------- weights fp32->bf16 (merged) ----------------
#define W1CNT (NPAD * DM / 4)
#define W2CNT (DM * DI / 4)
__global__ void cvtw_kernel(const float* __restrict__ w1, const float* __restrict__ w2,
                            bf16_t* __restrict__ o1, bf16_t* __restrict__ o2) {
  int i4 = blockIdx.x * 256 + threadIdx.x;
  if (i4 < W1CNT) {
    int idx = i4 * 4;
    int row = idx >> 10;
    float4 v = make_float4(0.f, 0.f, 0.f, 0.f);
    if (row < NPROJ) v = *(const float4*)(w1 + idx);
    bf16_t* d = o1 + idx;
    d[0] = __float2bfloat16(v.x); d[1] = __float2bfloat16(v.y);
    d[2] = __float2bfloat16(v.z); d[3] = __float2bfloat16(v.w);
  } else {
    int idx = (i4 - W1CNT) * 4;
    float4 v = *(const float4*)(w2 + idx);
    bf16_t* d = o2 + idx;
    d[0] = __float2bfloat16(v.x); d[1] = __float2bfloat16(v.y);
    d[2] = __float2bfloat16(v.z); d[3] = __float2bfloat16(v.w);
  }
}

// ---------------- BK=64 swizzled MFMA GEMM: C[M,N] = A[M,K] @ B[N,K]^T ----------------
template<int TN, bool DO_RES, bool OUT_BF16>
__global__ __launch_bounds__(256) void gemm64_kernel(const bf16_t* __restrict__ A,
    const bf16_t* __restrict__ Bw, const float* __restrict__ resid,
    void* __restrict__ Cout, int N, int K) {
  __shared__ bf16_t As[128 * 64];
  __shared__ bf16_t Bs[TN * 64];
  const int tid = threadIdx.x;
  const int lane = tid & 63;
  const int wv = tid >> 6;
  const int l15 = lane & 15;
  const int l4 = lane >> 4;
  constexpr int MF = (TN == 128) ? 4 : 2;
  const int wm = (TN == 128) ? ((wv >> 1) << 6) : (wv << 5);
  const int wn = (TN == 128) ? ((wv & 1) << 6) : 0;
  const int tm = blockIdx.x << 7;
  const int tn = blockIdx.y * TN;

  floatx4 acc[MF][4];
#pragma unroll
  for (int i = 0; i < MF; i++)
#pragma unroll
    for (int j = 0; j < 4; j++) acc[i][j] = (floatx4){0.f, 0.f, 0.f, 0.f};

  const int r = tid >> 3;
  const int c8 = tid & 7;
  const int scol = ((c8 ^ (r & 7)) << 3);
  const bf16_t* Ag = A + (long)(tm + r) * K + scol;
  const bf16_t* Bg = Bw + (long)(tn + r) * K + scol;
  const int swz = l15 & 7;

  for (int k0 = 0; k0 < K; k0 += 64) {
#pragma unroll
    for (int q = 0; q < 4; q++)
      gl_lds16(Ag + (long)(q * 32) * K + k0, &As[q * 2048 + tid * 8]);
#pragma unroll
    for (int q = 0; q < TN / 32; q++)
      gl_lds16(Bg + (long)(q * 32) * K + k0, &Bs[q * 2048 + tid * 8]);
    __syncthreads();
#pragma unroll
    for (int kk = 0; kk < 2; kk++) {
      bfrag8 af[MF], bfr[4];
      const int ch = ((kk << 2) | l4) ^ swz;
#pragma unroll
      for (int j = 0; j < 4; j++)
        bfr[j] = *(const bfrag8*)&Bs[(wn + j * 16 + l15) * 64 + ch * 8];
#pragma unroll
      for (int i = 0; i < MF; i++)
        af[i] = *(const bfrag8*)&As[(wm + i * 16 + l15) * 64 + ch * 8];
#pragma unroll
      for (int i = 0; i < MF; i++)
#pragma unroll
        for (int j = 0; j < 4; j++)
          acc[i][j] = __builtin_amdgcn_mfma_f32_16x16x32_bf16(af[i], bfr[j], acc[i][j], 0, 0, 0);
    }
    __syncthreads();
  }
#pragma unroll
  for (int i = 0; i < MF; i++)
#pragma unroll
    for (int j = 0; j < 4; j++)
#pragma unroll
      for (int r2 = 0; r2 < 4; r2++) {
        int row = tm + wm + i * 16 + l4 * 4 + r2;
        int col = tn + wn + j * 16 + l15;
        float v = acc[i][j][r2];
        if (OUT_BF16) {
          ((bf16_t*)Cout)[(long)row * N + col] = __float2bfloat16(v);
        } else {
          if (DO_RES) v += resid[(long)row * N + col];
          ((float*)Cout)[(long)row * N + col] = v;
        }
      }
}

// ---------------- batched S GEMM: SL[bc][l][s] = Cm[l].Bm[s] (M=N=256,K=128) ----------
__global__ __launch_bounds__(256) void gemm_s_kernel(const bf16_t* __restrict__ Cmh,
                const bf16_t* __restrict__ Bmh, float* __restrict__ SL) {
  __shared__ bf16_t As[128 * 32];
  __shared__ bf16_t Bs[128 * 32];
  const int tid = threadIdx.x;
  const int lane = tid & 63;
  const int wv = tid >> 6;
  const int wm = (wv >> 1) << 6;
  const int wn = (wv & 1) << 6;
  const int bc = blockIdx.z;
  const int tm = blockIdx.x << 7;
  const int tn = blockIdx.y << 7;
  const int l15 = lane & 15;
  const int l4 = lane >> 4;
  floatx4 acc[4][4];
#pragma unroll
  for (int i = 0; i < 4; i++)
#pragma unroll
    for (int j = 0; j < 4; j++) acc[i][j] = (floatx4){0.f, 0.f, 0.f, 0.f};
  const int arow = tid >> 2;
  const int acol = (tid & 3) << 3;
  const bf16_t* Ag = Cmh + (long)bc * 256 * DSTATE + (long)(tm + arow) * DSTATE + acol;
  const bf16_t* Bg = Bmh + (long)bc * 256 * DSTATE + (long)(tn + arow) * DSTATE + acol;
  const long k64 = (long)64 * DSTATE;
  for (int k0 = 0; k0 < DSTATE; k0 += 32) {
    gl_lds16(Ag + k0, &As[tid * 8]);
    gl_lds16(Ag + k64 + k0, &As[2048 + tid * 8]);
    gl_lds16(Bg + k0, &Bs[tid * 8]);
    gl_lds16(Bg + k64 + k0, &Bs[2048 + tid * 8]);
    __syncthreads();
    bfrag8 af[4], bfr[4];
#pragma unroll
    for (int i = 0; i < 4; i++)
      af[i] = *(const bfrag8*)&As[(wm + i * 16 + l15) * 32 + l4 * 8];
#pragma unroll
    for (int j = 0; j < 4; j++)
      bfr[j] = *(const bfrag8*)&Bs[(wn + j * 16 + l15) * 32 + l4 * 8];
#pragma unroll
    for (int i = 0; i < 4; i++)
#pragma unroll
      for (int j = 0; j < 4; j++)
        acc[i][j] = __builtin_amdgcn_mfma_f32_16x16x32_bf16(af[i], bfr[j], acc[i][j], 0, 0, 0);
    __syncthreads();
  }
  float* Cb = SL + (long)bc * 65536;
#pragma unroll
  for (int i = 0; i < 4; i++)
#pragma unroll
    for (int j = 0; j < 4; j++)
#pragma unroll
      for (int r = 0; r < 4; r++)
        Cb[(long)(tm + wm + i * 16 + l4 * 4 + r) * 256 + tn + wn + j * 16 + l15] = acc[i][j][r];
}

// ---------------- vectorized conv4 + bias + silu: 8 channels x 4 rows / thread -------
__global__ __launch_bounds__(256) void conv4_kernel(const bf16_t* __restrict__ zxh,
    const float* __restrict__ cw, const float* __restrict__ cb,
    bf16_t* __restrict__ xhb, bf16_t* __restrict__ Bmh, bf16_t* __restrict__ Cmh) {
  int g = blockIdx.x * 256 + threadIdx.x;    // < 1024*288
  int cg = g % 288;
  int blt = g / 288;
  int c0 = cg * 8;
  long bl0 = (long)blt * 4;
  int l0 = (int)(bl0 & (LL - 1));
  const bf16_t* base = zxh + bl0 * NPAD + DI + c0;
  float rv[7][8];
#pragma unroll
  for (int j = 0; j < 7; j++) {
    int dj = j - 3;
    if (l0 + dj >= 0) {
      uint4 u = *(const uint4*)(base + (long)dj * NPAD);
      unp8(u, rv[j]);
    } else {
#pragma unroll
      for (int q = 0; q < 8; q++) rv[j][q] = 0.f;
    }
  }
  float4 wq[8];
#pragma unroll
  for (int q = 0; q < 8; q++) wq[q] = ((const float4*)cw)[c0 + q];
  float bias[8];
  *(float4*)&bias[0] = *(const float4*)(cb + c0);
  *(float4*)&bias[4] = *(const float4*)(cb + c0 + 4);
#pragma unroll
  for (int i = 0; i < 4; i++) {
    unsigned o[4];
#pragma unroll
    for (int q2 = 0; q2 < 4; q2++) {
      float rr[2];
#pragma unroll
      for (int e = 0; e < 2; e++) {
        int q = q2 * 2 + e;
        float a = bias[q] + wq[q].x * rv[i][q] + wq[q].y * rv[i + 1][q]
                + wq[q].z * rv[i + 2][q] + wq[q].w * rv[i + 3][q];
        rr[e] = a / (1.f + __expf(-a));
      }
      o[q2] = pack_bf16_rn(rr[0], rr[1]);
    }
    uint4 ov = make_uint4(o[0], o[1], o[2], o[3]);
    long bl = bl0 + i;
    if (c0 < DI)               *(uint4*)(xhb + bl * DI + c0) = ov;
    else if (c0 < DI + DSTATE) *(uint4*)(Bmh + bl * DSTATE + (c0 - DI)) = ov;
    else                       *(uint4*)(Cmh + bl * DSTATE + (c0 - DI - DSTATE)) = ov;
  }
}

// ---------------- softplus(dt)+cumsum(dt*A) per (b,c,h) — shfl scan ----------------
__global__ void acs_kernel(const bf16_t* __restrict__ zxh, const float* __restrict__ A_log,
                           const float* __restrict__ dtb,
                           float* __restrict__ acs, float* __restrict__ ctot,
                           float* __restrict__ dtout) {
  int blk = blockIdx.x;           // (b*8+c)*32+h
  int h = blk & 31, bc = blk >> 5;
  int t = threadIdx.x, lane = t & 63, w = t >> 6;
  float Ah = -__expf(A_log[h]);
  int gl = bc * 256 + t;
  float vv = __bfloat162float(zxh[(long)gl * NPAD + (NPROJ - 32) + h]) + dtb[h];
  float sp = fmaxf(vv, 0.f) + log1pf(__expf(-fabsf(vv)));
  dtout[gl * 32 + h] = sp;
  float a = sp * Ah;
#pragma unroll
  for (int off = 1; off < 64; off <<= 1) {
    float v = __shfl_up(a, off, 64);
    if (lane >= off) a += v;
  }
  __shared__ float wsum[4];
  if (lane == 63) wsum[w] = a;
  __syncthreads();
  float base = 0.f;
  for (int i = 0; i < 4; i++) base += (i < w) ? wsum[i] : 0.f;
  a += base;
  acs[blk * 256 + t] = a;
  if (t == 255) ctot[blk] = a;
}

// ---------------- transposes: xdT[p][l]=x*dt, xdTe[p][l]=x*dt*decay, BmT[n][l] -------
__global__ __launch_bounds__(256) void xdt_kernel(const bf16_t* __restrict__ xhb,
    const bf16_t* __restrict__ Bmh, const float* __restrict__ dt,
    const float* __restrict__ acs, bf16_t* __restrict__ xdT,
    bf16_t* __restrict__ xdTe, bf16_t* __restrict__ BmT) {
  __shared__ unsigned short Tb[9216];   // 2x 64x72 (xdt) or 1x 128x72 (bmt)
  int blk = blockIdx.x;
  int t = threadIdx.x;
  if (blk < 512) {
    unsigned short* T1 = Tb;
    unsigned short* T2 = Tb + 4608;
    int h = blk & 31, bc = blk >> 5;
    float atot = acs[blk * 256 + 255];
    int l_loc = t >> 2, pg = t & 3;
    for (int lt = 0; lt < 4; lt++) {
      int gl = bc * 256 + lt * 64 + l_loc;
      float w1 = dt[gl * 32 + h];
      float w2 = w1 * __expf(atot - acs[blk * 256 + lt * 64 + l_loc]);
      const uint4* src = (const uint4*)(xhb + (long)gl * DI + h * HD + pg * 16);
      uint4 u0 = src[0], u1 = src[1];
      float v[16];
      unp8(u0, v); unp8(u1, v + 8);
      __syncthreads();
#pragma unroll
      for (int q = 0; q < 16; q++) {
        T1[(pg * 16 + q) * 72 + l_loc] = bf16u(v[q] * w1);
        T2[(pg * 16 + q) * 72 + l_loc] = bf16u(v[q] * w2);
      }
      __syncthreads();
      long orow = ((long)blk * 64 + l_loc) * 256 + lt * 64 + pg * 16;  // reuse t split: p=l_loc, lg=pg
      *(uint4*)(xdT + orow)      = *(uint4*)&T1[l_loc * 72 + pg * 16];
      *(uint4*)(xdT + orow + 8)  = *(uint4*)&T1[l_loc * 72 + pg * 16 + 8];
      *(uint4*)(xdTe + orow)     = *(uint4*)&T2[l_loc * 72 + pg * 16];
      *(uint4*)(xdTe + orow + 8) = *(uint4*)&T2[l_loc * 72 + pg * 16 + 8];
    }
  } else {
    unsigned short* T = Tb;
    int bc = blk - 512;
    int l_loc = t >> 2, ng = t & 3;
    for (int lt = 0; lt < 4; lt++) {
      int gl = bc * 256 + lt * 64 + l_loc;
      const uint4* src = (const uint4*)(Bmh + (long)gl * DSTATE + ng * 32);
      uint4 u[4];
#pragma unroll
      for (int q = 0; q < 4; q++) u[q] = src[q];
      __syncthreads();
      const unsigned short* us = (const unsigned short*)u;
#pragma unroll
      for (int e = 0; e < 32; e++)
        T[(ng * 32 + e) * 72 + l_loc] = us[e];
      __syncthreads();
      int n = t >> 1, lg2 = t & 1;
      long orow = ((long)bc * 128 + n) * 256 + lt * 64 + lg2 * 32;
#pragma unroll
      for (int q = 0; q < 4; q++)
        *(uint4*)(BmT + orow + q * 8) = *(uint4*)&T[n * 72 + lg2 * 32 + q * 8];
    }
  }
}

// ---------------- chunk states: pure register MFMA GEMM (no LDS, no barriers) --------
__global__ __launch_bounds__(256) void states3_kernel(const bf16_t* __restrict__ xdTe,
    const bf16_t* __restrict__ BmT, bf16_t* __restrict__ states) {
  int blk = blockIdx.x;    // bc*32+h
  int bc = blk >> 5;
  int t = threadIdx.x, lane = t & 63, wv = t >> 6;
  int l15 = lane & 15, l4 = lane >> 4;
  floatx4 acc[2][4];
#pragma unroll
  for (int i = 0; i < 2; i++)
#pragma unroll
    for (int j = 0; j < 4; j++) acc[i][j] = (floatx4){0.f, 0.f, 0.f, 0.f};
  const bf16_t* arow = BmT + (long)bc * 128 * 256;
  const bf16_t* brow = xdTe + (long)blk * 64 * 256;
#pragma unroll
  for (int kt = 0; kt < 8; kt++) {
    bfrag8 af[2], bfr[4];
#pragma unroll
    for (int i = 0; i < 2; i++)
      af[i] = *(const bfrag8*)(arow + (long)(wv * 32 + i * 16 + l15) * 256 + kt * 32 + l4 * 8);
#pragma unroll
    for (int j = 0; j < 4; j++)
      bfr[j] = *(const bfrag8*)(brow + (long)(j * 16 + l15) * 256 + kt * 32 + l4 * 8);
#pragma unroll
    for (int i = 0; i < 2; i++)
#pragma unroll
      for (int j = 0; j < 4; j++)
        acc[i][j] = __builtin_amdgcn_mfma_f32_16x16x32_bf16(af[i], bfr[j], acc[i][j], 0, 0, 0);
  }
  // D rows = n, cols = p ; states[p][n] bf16
#pragma unroll
  for (int i = 0; i < 2; i++)
#pragma unroll
    for (int j = 0; j < 4; j++) {
      int n_base = wv * 32 + i * 16 + l4 * 4;
      int p = j * 16 + l15;
      unsigned lo = pack_bf16_rn(acc[i][j][0], acc[i][j][1]);
      unsigned hi = pack_bf16_rn(acc[i][j][2], acc[i][j][3]);
      *(uint2*)(states + (long)blk * 8192 + p * 128 + n_base) = make_uint2(lo, hi);
    }
}

// ---------------- inter-chunk scan -> init states (bf16 in/out) ----------------
__global__ void scan_kernel(const bf16_t* __restrict__ states, const float* __restrict__ ctot,
                            bf16_t* __restrict__ initsb) {
  int id = blockIdx.x * 256 + threadIdx.x;   // < 2*32*8192
  int pn = id & 8191;
  int bh = id >> 13;
  int b = bh >> 5, h = bh & 31;
  float S = 0.f;
#pragma unroll
  for (int c = 0; c < 8; c++) {
    int blk = (b * 8 + c) * 32 + h;
    initsb[(long)blk * 8192 + pn] = __float2bfloat16(S);
    S = __expf(ctot[blk]) * S + __bfloat162float(states[(long)blk * 8192 + pn]);
  }
}

// ---------------- MFMA Y (global B-frags) + LDS-roundtrip fused gating epilogue ------
__global__ __launch_bounds__(256, 4) void yk2_kernel(const float* __restrict__ SL,
     const bf16_t* __restrict__ Cmh, const bf16_t* __restrict__ xhb,
     const bf16_t* __restrict__ zxh, const float* __restrict__ acs,
     const bf16_t* __restrict__ initsb, const bf16_t* __restrict__ xdT,
     const float* __restrict__ Dp, bf16_t* __restrict__ yg, float* __restrict__ ssqp) {
  int bi = blockIdx.x;
  int mh = bi & 1, h = (bi >> 1) & 31, bc = bi >> 6;
  int ablk = bc * 32 + h;
  int t = threadIdx.x;
  int lane = t & 63, wv = t >> 6;
  int l15 = lane & 15, l4 = lane >> 4;
  __shared__ float acsS[256];
  __shared__ __align__(16) char ubuf[128 * 66 * 4];   // union: Ps / Ytile
  bf16_t* Ps = (bf16_t*)ubuf;                          // [128][PSTR]
  float* Yt = (float*)ubuf;                            // [128][66]

  acsS[t] = acs[ablk * 256 + t];
  __syncthreads();
  const int l_loc = t >> 1, half = t & 1;
  const int l = mh * 128 + l_loc;
  const float al = acsS[l];
  const float eAl = __expf(al);
  const int rowbase = bc * 256;
  const float* SLb = SL + (long)bc * 65536 + (long)l * 256;
  const bf16_t* xrow = xdT + (long)ablk * 64 * 256;

  floatx4 acc[2][4];
#pragma unroll
  for (int i = 0; i < 2; i++)
#pragma unroll
    for (int j = 0; j < 4; j++) acc[i][j] = (floatx4){0.f, 0.f, 0.f, 0.f};

  const int nkd = (mh + 1) * 4;
  for (int kt = 0; kt < nkd + 4; kt++) {
    __syncthreads();
    if (kt < nkd) {
      int s0 = kt * 32 + half * 16;
      unsigned pk[8];
      const float4* Sg = (const float4*)(SLb + s0);
#pragma unroll
      for (int q = 0; q < 4; q++) {
        float4 v = Sg[q];
        int sb = s0 + q * 4;
        float p0 = (sb + 0 <= l) ? v.x * __expf(al - acsS[sb + 0]) : 0.f;
        float p1 = (sb + 1 <= l) ? v.y * __expf(al - acsS[sb + 1]) : 0.f;
        float p2 = (sb + 2 <= l) ? v.z * __expf(al - acsS[sb + 2]) : 0.f;
        float p3 = (sb + 3 <= l) ? v.w * __expf(al - acsS[sb + 3]) : 0.f;
        pk[q * 2 + 0] = pack_bf16_rn(p0, p1);
        pk[q * 2 + 1] = pack_bf16_rn(p2, p3);
      }
      uint4* pw = (uint4*)&Ps[l_loc * PSTR + half * 16];
      pw[0] = make_uint4(pk[0], pk[1], pk[2], pk[3]);
      pw[1] = make_uint4(pk[4], pk[5], pk[6], pk[7]);
    } else {
      int n0 = (kt - nkd) * 32;
      unsigned pk[8];
      const uint4* Cg = (const uint4*)(Cmh + (long)(rowbase + l) * DSTATE + n0 + half * 16);
      uint4 u0 = Cg[0], u1 = Cg[1];
      float cv[16];
      unp8(u0, cv); unp8(u1, cv + 8);
#pragma unroll
      for (int q = 0; q < 8; q++)
        pk[q] = pack_bf16_rn(cv[q * 2] * eAl, cv[q * 2 + 1] * eAl);
      uint4* pw = (uint4*)&Ps[l_loc * PSTR + half * 16];
      pw[0] = make_uint4(pk[0], pk[1], pk[2], pk[3]);
      pw[1] = make_uint4(pk[4], pk[5], pk[6], pk[7]);
    }
    __syncthreads();
    bfrag8 bfr[4];
    if (kt < nkd) {
#pragma unroll
      for (int j = 0; j < 4; j++)
        bfr[j] = *(const bfrag8*)(xrow + (long)(j * 16 + l15) * 256 + kt * 32 + l4 * 8);
    } else {
      int n0 = (kt - nkd) * 32;
#pragma unroll
      for (int j = 0; j < 4; j++)
        bfr[j] = *(const bfrag8*)(initsb + (long)ablk * 8192 + (j * 16 + l15) * 128 + n0 + l4 * 8);
    }
#pragma unroll
    for (int i = 0; i < 2; i++) {
      bfrag8 af = *(const bfrag8*)&Ps[(wv * 32 + i * 16 + l15) * PSTR + l4 * 8];
#pragma unroll
      for (int j = 0; j < 4; j++)
        acc[i][j] = __builtin_amdgcn_mfma_f32_16x16x32_bf16(af, bfr[j], acc[i][j], 0, 0, 0);
    }
  }
  // ---- epilogue: dump Y to LDS, re-read row-major, vectorized gating ----
  __syncthreads();
#pragma unroll
  for (int i = 0; i < 2; i++)
#pragma unroll
    for (int j = 0; j < 4; j++)
#pragma unroll
      for (int r = 0; r < 4; r++)
        Yt[(wv * 32 + i * 16 + l4 * 4 + r) * 66 + j * 16 + l15] = acc[i][j][r];
  __syncthreads();
  {
    int row_l = t >> 1;
    int ch = (t & 1) * 32;
    long rowg = rowbase + mh * 128 + row_l;
    float Dh = Dp[h];
    float ss = 0.f;
#pragma unroll
    for (int it = 0; it < 4; it++) {
      int c = ch + it * 8;
      float4 y0 = *(const float4*)&Yt[row_l * 66 + c];
      float4 y1 = *(const float4*)&Yt[row_l * 66 + c + 4];
      uint4 ux = *(const uint4*)(xhb + rowg * DI + h * HD + c);
      uint4 uz = *(const uint4*)(zxh + rowg * NPAD + h * HD + c);
      float xv[8], zv[8];
      unp8(ux, xv); unp8(uz, zv);
      float yv[8] = {y0.x, y0.y, y0.z, y0.w, y1.x, y1.y, y1.z, y1.w};
      unsigned o[4];
#pragma unroll
      for (int q = 0; q < 4; q++) {
        float v0 = (yv[q * 2 + 0] + Dh * xv[q * 2 + 0]) *
                   (zv[q * 2 + 0] / (1.f + __expf(-zv[q * 2 + 0])));
        float v1 = (yv[q * 2 + 1] + Dh * xv[q * 2 + 1]) *
                   (zv[q * 2 + 1] / (1.f + __expf(-zv[q * 2 + 1])));
        ss += v0 * v0 + v1 * v1;
        o[q] = pack_bf16_rn(v0, v1);
      }
      *(uint4*)(yg + rowg * DI + h * HD + c) = make_uint4(o[0], o[1], o[2], o[3]);
    }
    ss += __shfl_xor(ss, 1, 64);
    if ((t & 1) == 0) ssqp[rowg * 32 + h] = ss;
  }
}

// ---------------- light gated-rmsnorm finish ----------------
__global__ void gnorm2_kernel(const bf16_t* __restrict__ yg, const float* __restrict__ ssqp,
                              const float* __restrict__ gw, bf16_t* __restrict__ yn) {
  int row = blockIdx.x, t = threadIdx.x;
  __shared__ float rsS;
  if (t < 64) {
    float v = (t < 32) ? ssqp[row * 32 + t] : 0.f;
#pragma unroll
    for (int off = 16; off > 0; off >>= 1) v += __shfl_down(v, off, 64);
    if (t == 0) rsS = rsqrtf(v * (1.f / DI) + EPSF);
  }
  __syncthreads();
  float rs = rsS;
  uint4 u = *(const uint4*)(yg + (long)row * DI + t * 8);
  float4 g0 = ((const float4*)gw)[t * 2];
  float4 g1 = ((const float4*)gw)[t * 2 + 1];
  unsigned o0 = pack_bf16_rn(blo(u.x) * rs * g0.x, bhi(u.x) * rs * g0.y);
  unsigned o1 = pack_bf16_rn(blo(u.y) * rs * g0.z, bhi(u.y) * rs * g0.w);
  unsigned o2 = pack_bf16_rn(blo(u.z) * rs * g1.x, bhi(u.z) * rs * g1.y);
  unsigned o3 = pack_bf16_rn(blo(u.w) * rs * g1.z, bhi(u.w) * rs * g1.w);
  *(uint4*)(yn + (long)row * DI + t * 8) = make_uint4(o0, o1, o2, o3);
}

extern "C" void kernel_launch(void* const* d_in, const int* in_sizes, int n_in,
                              void* d_out, int out_size, void* d_ws, size_t ws_size,
                              hipStream_t stream) {
  const float* x    = (const float*)d_in[0];
  const float* nw   = (const float*)d_in[1];
  const float* w1   = (const float*)d_in[2];
  const float* cw   = (const float*)d_in[3];
  const float* cb   = (const float*)d_in[4];
  const float* dtb  = (const float*)d_in[5];
  const float* alog = (const float*)d_in[6];
  const float* Dp   = (const float*)d_in[7];
  const float* gw   = (const float*)d_in[8];
  const float* w2   = (const float*)d_in[9];
  float* out = (float*)d_out;

  char* ws = (char*)d_ws;
  size_t off = 0;
  auto alloc = [&](size_t bytes) -> void* {
    void* p = ws + off;
    off += (bytes + 255) & ~(size_t)255;
    return p;
  };
  bf16_t* ub     = (bf16_t*)alloc((size_t)MR * DM * 2);
  bf16_t* w1b    = (bf16_t*)alloc((size_t)NPAD * DM * 2);
  bf16_t* w2b    = (bf16_t*)alloc((size_t)DM * DI * 2);
  bf16_t* zxh    = (bf16_t*)alloc((size_t)MR * NPAD * 2);
  bf16_t* xhb    = (bf16_t*)alloc((size_t)MR * DI * 2);
  bf16_t* Bmh    = (bf16_t*)alloc((size_t)MR * DSTATE * 2);
  bf16_t* Cmh    = (bf16_t*)alloc((size_t)MR * DSTATE * 2);
  float* SL      = (float*)alloc((size_t)16 * 256 * 256 * 4);
  float* dt      = (float*)alloc((size_t)MR * NHD * 4);
  float* acs     = (float*)alloc((size_t)512 * 256 * 4);
  float* ctot    = (float*)alloc((size_t)512 * 4);
  bf16_t* states = (bf16_t*)alloc((size_t)512 * 8192 * 2);
  bf16_t* initsb = (bf16_t*)alloc((size_t)512 * 8192 * 2);
  bf16_t* xdT    = (bf16_t*)alloc((size_t)512 * 64 * 256 * 2);
  bf16_t* xdTe   = (bf16_t*)alloc((size_t)512 * 64 * 256 * 2);
  bf16_t* BmT    = (bf16_t*)alloc((size_t)16 * 128 * 256 * 2);
  bf16_t* yg     = (bf16_t*)alloc((size_t)MR * DI * 2);
  float* ssqp    = (float*)alloc((size_t)MR * NHD * 4);
  bf16_t* yn     = (bf16_t*)alloc((size_t)MR * DI * 2);
  if (off > ws_size) return;

  rms1_kernel<<<MR, 256, 0, stream>>>(x, nw, ub);
  cvtw_kernel<<<(W1CNT + W2CNT) / 256, 256, 0, stream>>>(w1, w2, w1b, w2b);
  gemm64_kernel<128, false, true><<<dim3(MR / 128, NPAD / 128), 256, 0, stream>>>(
      ub, w1b, nullptr, zxh, NPAD, DM);
  conv4_kernel<<<(1024 * 288) / 256, 256, 0, stream>>>(zxh, cw, cb, xhb, Bmh, Cmh);
  acs_kernel<<<512, 256, 0, stream>>>(zxh, alog, dtb, acs, ctot, dt);
  xdt_kernel<<<528, 256, 0, stream>>>(xhb, Bmh, dt, acs, xdT, xdTe, BmT);
  gemm_s_kernel<<<dim3(2, 2, 16), 256, 0, stream>>>(Cmh, Bmh, SL);
  states3_kernel<<<512, 256, 0, stream>>>(xdTe, BmT, states);
  scan_kernel<<<(2 * 32 * 8192) / 256, 256, 0, stream>>>(states, ctot, initsb);
  yk2_kernel<<<1024, 256, 0, stream>>>(SL, Cmh, xhb, zxh, acs, initsb, xdT, Dp, yg, ssqp);
  gnorm2_kernel<<<MR, 256, 0, stream>>>(yg, ssqp, gw, yn);
  gemm64_kernel<64, true, false><<<dim3(MR / 128, DM / 64), 256, 0, stream>>>(
      yn, w2b, x, out, DM, DI);
}

// Round 6
// 290.633 us; speedup vs baseline: 3.2905x; 1.0211x over previous
//
#include <hip/hip_runtime.h>
#include <hip/hip_bf16.h>

typedef __hip_bfloat16 bf16_t;
typedef __attribute__((ext_vector_type(8))) short bfrag8;   // 8 bf16 (4 VGPRs)
typedef __attribute__((ext_vector_type(4))) float floatx4;  // MFMA acc

#define DM     1024
#define DI     2048
#define NHD    32
#define HD     64
#define DSTATE 128
#define CONVD  2304
#define NPROJ  4384
#define NPAD   4480
#define MR     4096      // B*L
#define LL     2048
#define EPSF   1e-5f
#define PSTR   40        // LDS row stride (bf16) for P tiles
#define LOG2E  1.44269504088896f

__device__ __forceinline__ void gl_lds16(const void* g, void* l) {
  __builtin_amdgcn_global_load_lds((const __attribute__((address_space(1))) void*)g,
                                   (__attribute__((address_space(3))) void*)l, 16, 0, 0);
}
__device__ __forceinline__ unsigned pack_bf16_rn(float a, float b) {
  unsigned ua = (__float_as_uint(a) + 0x8000u) >> 16;
  unsigned ub = (__float_as_uint(b) + 0x8000u) >> 16;
  return ua | (ub << 16);
}
__device__ __forceinline__ unsigned short bf16u(float a) {
  return (unsigned short)((__float_as_uint(a) + 0x8000u) >> 16);
}
__device__ __forceinline__ float blo(unsigned u){ return __uint_as_float(u << 16); }
__device__ __forceinline__ float bhi(unsigned u){ return __uint_as_float(u & 0xffff0000u); }
__device__ __forceinline__ void unp8(uint4 u, float* v) {
  v[0]=blo(u.x); v[1]=bhi(u.x); v[2]=blo(u.y); v[3]=bhi(u.y);
  v[4]=blo(u.z); v[5]=bhi(u.z); v[6]=blo(u.w); v[7]=bhi(u.w);
}

// ---------------- rmsnorm(x) -> u (bf16) ----------------
__global__ void rms1_kernel(const float* __restrict__ x, const float* __restrict__ w,
                            bf16_t* __restrict__ ub) {
  int row = blockIdx.x, t = threadIdx.x;
  float4 v = ((const float4*)(x + (long)row * DM))[t];
  float ss = v.x*v.x + v.y*v.y + v.z*v.z + v.w*v.w;
#pragma unroll
  for (int off = 32; off > 0; off >>= 1) ss += __shfl_down(ss, off, 64);
  __shared__ float red[4];
  if ((t & 63) == 0) red[t >> 6] = ss;
  __syncthreads();
  float tot = red[0] + red[1] + red[2] + red[3];
  float rs = rsqrtf(tot * (1.f / DM) + EPSF);
  float4 wv = ((const float4*)w)[t];
  bf16_t* o = ub + (long)row * DM + t * 4;
  o[0] = __float2bfloat16(v.x * rs * wv.x);
  o[1] = __float2bfloat16(v.y * rs * wv.y);
  o[2] = __float2bfloat16(v.z * rs * wv.z);
  o[3] = __float2bfloat16(v.w * rs * wv.w);
}

// ---------------- weights fp32->bf16 (merged) ----------------
#define W1CNT (NPAD * DM / 4)
#define W2CNT (DM * DI / 4)
__global__ void cvtw_kernel(const float* __restrict__ w1, const float* __restrict__ w2,
                            bf16_t* __restrict__ o1, bf16_t* __restrict__ o2) {
  int i4 = blockIdx.x * 256 + threadIdx.x;
  if (i4 < W1CNT) {
    int idx = i4 * 4;
    int row = idx >> 10;
    float4 v = make_float4(0.f, 0.f, 0.f, 0.f);
    if (row < NPROJ) v = *(const float4*)(w1 + idx);
    bf16_t* d = o1 + idx;
    d[0] = __float2bfloat16(v.x); d[1] = __float2bfloat16(v.y);
    d[2] = __float2bfloat16(v.z); d[3] = __float2bfloat16(v.w);
  } else {
    int idx = (i4 - W1CNT) * 4;
    float4 v = *(const float4*)(w2 + idx);
    bf16_t* d = o2 + idx;
    d[0] = __float2bfloat16(v.x); d[1] = __float2bfloat16(v.y);
    d[2] = __float2bfloat16(v.z); d[3] = __float2bfloat16(v.w);
  }
}

// ---------------- BK=64 swizzled MFMA GEMM: C[M,N] = A[M,K] @ B[N,K]^T ----------------
template<int TN, bool DO_RES, bool OUT_BF16>
__global__ __launch_bounds__(256) void gemm64_kernel(const bf16_t* __restrict__ A,
    const bf16_t* __restrict__ Bw, const float* __restrict__ resid,
    void* __restrict__ Cout, int N, int K) {
  __shared__ bf16_t As[128 * 64];
  __shared__ bf16_t Bs[TN * 64];
  const int tid = threadIdx.x;
  const int lane = tid & 63;
  const int wv = tid >> 6;
  const int l15 = lane & 15;
  const int l4 = lane >> 4;
  constexpr int MF = (TN == 128) ? 4 : 2;
  const int wm = (TN == 128) ? ((wv >> 1) << 6) : (wv << 5);
  const int wn = (TN == 128) ? ((wv & 1) << 6) : 0;
  const int tm = blockIdx.x << 7;
  const int tn = blockIdx.y * TN;

  floatx4 acc[MF][4];
#pragma unroll
  for (int i = 0; i < MF; i++)
#pragma unroll
    for (int j = 0; j < 4; j++) acc[i][j] = (floatx4){0.f, 0.f, 0.f, 0.f};

  const int r = tid >> 3;
  const int c8 = tid & 7;
  const int scol = ((c8 ^ (r & 7)) << 3);
  const bf16_t* Ag = A + (long)(tm + r) * K + scol;
  const bf16_t* Bg = Bw + (long)(tn + r) * K + scol;
  const int swz = l15 & 7;

  for (int k0 = 0; k0 < K; k0 += 64) {
#pragma unroll
    for (int q = 0; q < 4; q++)
      gl_lds16(Ag + (long)(q * 32) * K + k0, &As[q * 2048 + tid * 8]);
#pragma unroll
    for (int q = 0; q < TN / 32; q++)
      gl_lds16(Bg + (long)(q * 32) * K + k0, &Bs[q * 2048 + tid * 8]);
    __syncthreads();
#pragma unroll
    for (int kk = 0; kk < 2; kk++) {
      bfrag8 af[MF], bfr[4];
      const int ch = ((kk << 2) | l4) ^ swz;
#pragma unroll
      for (int j = 0; j < 4; j++)
        bfr[j] = *(const bfrag8*)&Bs[(wn + j * 16 + l15) * 64 + ch * 8];
#pragma unroll
      for (int i = 0; i < MF; i++)
        af[i] = *(const bfrag8*)&As[(wm + i * 16 + l15) * 64 + ch * 8];
#pragma unroll
      for (int i = 0; i < MF; i++)
#pragma unroll
        for (int j = 0; j < 4; j++)
          acc[i][j] = __builtin_amdgcn_mfma_f32_16x16x32_bf16(af[i], bfr[j], acc[i][j], 0, 0, 0);
    }
    __syncthreads();
  }
#pragma unroll
  for (int i = 0; i < MF; i++)
#pragma unroll
    for (int j = 0; j < 4; j++)
#pragma unroll
      for (int r2 = 0; r2 < 4; r2++) {
        int row = tm + wm + i * 16 + l4 * 4 + r2;
        int col = tn + wn + j * 16 + l15;
        float v = acc[i][j][r2];
        if (OUT_BF16) {
          ((bf16_t*)Cout)[(long)row * N + col] = __float2bfloat16(v);
        } else {
          if (DO_RES) v += resid[(long)row * N + col];
          ((float*)Cout)[(long)row * N + col] = v;
        }
      }
}

// ---------------- batched S GEMM: SL[bc][l][s] = Cm[l].Bm[s] (M=N=256,K=128) ----------
__global__ __launch_bounds__(256) void gemm_s_kernel(const bf16_t* __restrict__ Cmh,
                const bf16_t* __restrict__ Bmh, float* __restrict__ SL) {
  __shared__ bf16_t As[128 * 32];
  __shared__ bf16_t Bs[128 * 32];
  const int tid = threadIdx.x;
  const int lane = tid & 63;
  const int wv = tid >> 6;
  const int wm = (wv >> 1) << 6;
  const int wn = (wv & 1) << 6;
  const int bc = blockIdx.z;
  const int tm = blockIdx.x << 7;
  const int tn = blockIdx.y << 7;
  const int l15 = lane & 15;
  const int l4 = lane >> 4;
  floatx4 acc[4][4];
#pragma unroll
  for (int i = 0; i < 4; i++)
#pragma unroll
    for (int j = 0; j < 4; j++) acc[i][j] = (floatx4){0.f, 0.f, 0.f, 0.f};
  const int arow = tid >> 2;
  const int acol = (tid & 3) << 3;
  const bf16_t* Ag = Cmh + (long)bc * 256 * DSTATE + (long)(tm + arow) * DSTATE + acol;
  const bf16_t* Bg = Bmh + (long)bc * 256 * DSTATE + (long)(tn + arow) * DSTATE + acol;
  const long k64 = (long)64 * DSTATE;
  for (int k0 = 0; k0 < DSTATE; k0 += 32) {
    gl_lds16(Ag + k0, &As[tid * 8]);
    gl_lds16(Ag + k64 + k0, &As[2048 + tid * 8]);
    gl_lds16(Bg + k0, &Bs[tid * 8]);
    gl_lds16(Bg + k64 + k0, &Bs[2048 + tid * 8]);
    __syncthreads();
    bfrag8 af[4], bfr[4];
#pragma unroll
    for (int i = 0; i < 4; i++)
      af[i] = *(const bfrag8*)&As[(wm + i * 16 + l15) * 32 + l4 * 8];
#pragma unroll
    for (int j = 0; j < 4; j++)
      bfr[j] = *(const bfrag8*)&Bs[(wn + j * 16 + l15) * 32 + l4 * 8];
#pragma unroll
    for (int i = 0; i < 4; i++)
#pragma unroll
      for (int j = 0; j < 4; j++)
        acc[i][j] = __builtin_amdgcn_mfma_f32_16x16x32_bf16(af[i], bfr[j], acc[i][j], 0, 0, 0);
    __syncthreads();
  }
  float* Cb = SL + (long)bc * 65536;
#pragma unroll
  for (int i = 0; i < 4; i++)
#pragma unroll
    for (int j = 0; j < 4; j++)
#pragma unroll
      for (int r = 0; r < 4; r++)
        Cb[(long)(tm + wm + i * 16 + l4 * 4 + r) * 256 + tn + wn + j * 16 + l15] = acc[i][j][r];
}

// ---------------- vectorized conv4 + bias + silu: 8 channels x 4 rows / thread -------
__global__ __launch_bounds__(256) void conv4_kernel(const bf16_t* __restrict__ zxh,
    const float* __restrict__ cw, const float* __restrict__ cb,
    bf16_t* __restrict__ xhb, bf16_t* __restrict__ Bmh, bf16_t* __restrict__ Cmh) {
  int g = blockIdx.x * 256 + threadIdx.x;    // < 1024*288
  int cg = g % 288;
  int blt = g / 288;
  int c0 = cg * 8;
  long bl0 = (long)blt * 4;
  int l0 = (int)(bl0 & (LL - 1));
  const bf16_t* base = zxh + bl0 * NPAD + DI + c0;
  float rv[7][8];
#pragma unroll
  for (int j = 0; j < 7; j++) {
    int dj = j - 3;
    if (l0 + dj >= 0) {
      uint4 u = *(const uint4*)(base + (long)dj * NPAD);
      unp8(u, rv[j]);
    } else {
#pragma unroll
      for (int q = 0; q < 8; q++) rv[j][q] = 0.f;
    }
  }
  float4 wq[8];
#pragma unroll
  for (int q = 0; q < 8; q++) wq[q] = ((const float4*)cw)[c0 + q];
  float bias[8];
  *(float4*)&bias[0] = *(const float4*)(cb + c0);
  *(float4*)&bias[4] = *(const float4*)(cb + c0 + 4);
#pragma unroll
  for (int i = 0; i < 4; i++) {
    unsigned o[4];
#pragma unroll
    for (int q2 = 0; q2 < 4; q2++) {
      float rr[2];
#pragma unroll
      for (int e = 0; e < 2; e++) {
        int q = q2 * 2 + e;
        float a = bias[q] + wq[q].x * rv[i][q] + wq[q].y * rv[i + 1][q]
                + wq[q].z * rv[i + 2][q] + wq[q].w * rv[i + 3][q];
        rr[e] = a / (1.f + __expf(-a));
      }
      o[q2] = pack_bf16_rn(rr[0], rr[1]);
    }
    uint4 ov = make_uint4(o[0], o[1], o[2], o[3]);
    long bl = bl0 + i;
    if (c0 < DI)               *(uint4*)(xhb + bl * DI + c0) = ov;
    else if (c0 < DI + DSTATE) *(uint4*)(Bmh + bl * DSTATE + (c0 - DI)) = ov;
    else                       *(uint4*)(Cmh + bl * DSTATE + (c0 - DI - DSTATE)) = ov;
  }
}

// -------- softplus(dt)+cumsum(dt*A*log2e) per (b,c,h) — shfl scan; acs is LOG2-scaled --
__global__ void acs_kernel(const bf16_t* __restrict__ zxh, const float* __restrict__ A_log,
                           const float* __restrict__ dtb,
                           float* __restrict__ acs, float* __restrict__ ctot,
                           float* __restrict__ dtout) {
  int blk = blockIdx.x;           // (b*8+c)*32+h
  int h = blk & 31, bc = blk >> 5;
  int t = threadIdx.x, lane = t & 63, w = t >> 6;
  float Ah = -__expf(A_log[h]) * LOG2E;
  int gl = bc * 256 + t;
  float vv = __bfloat162float(zxh[(long)gl * NPAD + (NPROJ - 32) + h]) + dtb[h];
  float sp = fmaxf(vv, 0.f) + log1pf(__expf(-fabsf(vv)));
  dtout[gl * 32 + h] = sp;
  float a = sp * Ah;
#pragma unroll
  for (int off = 1; off < 64; off <<= 1) {
    float v = __shfl_up(a, off, 64);
    if (lane >= off) a += v;
  }
  __shared__ float wsum[4];
  if (lane == 63) wsum[w] = a;
  __syncthreads();
  float base = 0.f;
  for (int i = 0; i < 4; i++) base += (i < w) ? wsum[i] : 0.f;
  a += base;
  acs[blk * 256 + t] = a;
  if (t == 255) ctot[blk] = a;
}

// ---------------- transposes: xdT[p][l]=x*dt, xdTe[p][l]=x*dt*decay, BmT[n][l] -------
__global__ __launch_bounds__(256) void xdt_kernel(const bf16_t* __restrict__ xhb,
    const bf16_t* __restrict__ Bmh, const float* __restrict__ dt,
    const float* __restrict__ acs, bf16_t* __restrict__ xdT,
    bf16_t* __restrict__ xdTe, bf16_t* __restrict__ BmT) {
  __shared__ unsigned short Tb[9216];   // 2x 64x72 (xdt) or 1x 128x72 (bmt)
  int blk = blockIdx.x;
  int t = threadIdx.x;
  if (blk < 512) {
    unsigned short* T1 = Tb;
    unsigned short* T2 = Tb + 4608;
    int h = blk & 31, bc = blk >> 5;
    float atot = acs[blk * 256 + 255];
    int l_loc = t >> 2, pg = t & 3;
    for (int lt = 0; lt < 4; lt++) {
      int gl = bc * 256 + lt * 64 + l_loc;
      float w1 = dt[gl * 32 + h];
      float w2 = w1 * exp2f(atot - acs[blk * 256 + lt * 64 + l_loc]);
      const uint4* src = (const uint4*)(xhb + (long)gl * DI + h * HD + pg * 16);
      uint4 u0 = src[0], u1 = src[1];
      float v[16];
      unp8(u0, v); unp8(u1, v + 8);
      __syncthreads();
#pragma unroll
      for (int q = 0; q < 16; q++) {
        T1[(pg * 16 + q) * 72 + l_loc] = bf16u(v[q] * w1);
        T2[(pg * 16 + q) * 72 + l_loc] = bf16u(v[q] * w2);
      }
      __syncthreads();
      long orow = ((long)blk * 64 + l_loc) * 256 + lt * 64 + pg * 16;
      *(uint4*)(xdT + orow)      = *(uint4*)&T1[l_loc * 72 + pg * 16];
      *(uint4*)(xdT + orow + 8)  = *(uint4*)&T1[l_loc * 72 + pg * 16 + 8];
      *(uint4*)(xdTe + orow)     = *(uint4*)&T2[l_loc * 72 + pg * 16];
      *(uint4*)(xdTe + orow + 8) = *(uint4*)&T2[l_loc * 72 + pg * 16 + 8];
    }
  } else {
    unsigned short* T = Tb;
    int bc = blk - 512;
    int l_loc = t >> 2, ng = t & 3;
    for (int lt = 0; lt < 4; lt++) {
      int gl = bc * 256 + lt * 64 + l_loc;
      const uint4* src = (const uint4*)(Bmh + (long)gl * DSTATE + ng * 32);
      uint4 u[4];
#pragma unroll
      for (int q = 0; q < 4; q++) u[q] = src[q];
      __syncthreads();
      const unsigned short* us = (const unsigned short*)u;
#pragma unroll
      for (int e = 0; e < 32; e++)
        T[(ng * 32 + e) * 72 + l_loc] = us[e];
      __syncthreads();
      int n = t >> 1, lg2 = t & 1;
      long orow = ((long)bc * 128 + n) * 256 + lt * 64 + lg2 * 32;
#pragma unroll
      for (int q = 0; q < 4; q++)
        *(uint4*)(BmT + orow + q * 8) = *(uint4*)&T[n * 72 + lg2 * 32 + q * 8];
    }
  }
}

// ---------------- chunk states: pure register MFMA GEMM (no LDS, no barriers) --------
__global__ __launch_bounds__(256) void states3_kernel(const bf16_t* __restrict__ xdTe,
    const bf16_t* __restrict__ BmT, bf16_t* __restrict__ states) {
  int blk = blockIdx.x;    // bc*32+h
  int bc = blk >> 5;
  int t = threadIdx.x, lane = t & 63, wv = t >> 6;
  int l15 = lane & 15, l4 = lane >> 4;
  floatx4 acc[2][4];
#pragma unroll
  for (int i = 0; i < 2; i++)
#pragma unroll
    for (int j = 0; j < 4; j++) acc[i][j] = (floatx4){0.f, 0.f, 0.f, 0.f};
  const bf16_t* arow = BmT + (long)bc * 128 * 256;
  const bf16_t* brow = xdTe + (long)blk * 64 * 256;
#pragma unroll
  for (int kt = 0; kt < 8; kt++) {
    bfrag8 af[2], bfr[4];
#pragma unroll
    for (int i = 0; i < 2; i++)
      af[i] = *(const bfrag8*)(arow + (long)(wv * 32 + i * 16 + l15) * 256 + kt * 32 + l4 * 8);
#pragma unroll
    for (int j = 0; j < 4; j++)
      bfr[j] = *(const bfrag8*)(brow + (long)(j * 16 + l15) * 256 + kt * 32 + l4 * 8);
#pragma unroll
    for (int i = 0; i < 2; i++)
#pragma unroll
      for (int j = 0; j < 4; j++)
        acc[i][j] = __builtin_amdgcn_mfma_f32_16x16x32_bf16(af[i], bfr[j], acc[i][j], 0, 0, 0);
  }
#pragma unroll
  for (int i = 0; i < 2; i++)
#pragma unroll
    for (int j = 0; j < 4; j++) {
      int n_base = wv * 32 + i * 16 + l4 * 4;
      int p = j * 16 + l15;
      unsigned lo = pack_bf16_rn(acc[i][j][0], acc[i][j][1]);
      unsigned hi = pack_bf16_rn(acc[i][j][2], acc[i][j][3]);
      *(uint2*)(states + (long)blk * 8192 + p * 128 + n_base) = make_uint2(lo, hi);
    }
}

// ---------------- inter-chunk scan -> init states (bf16 in/out; ctot log2-scaled) -----
__global__ void scan_kernel(const bf16_t* __restrict__ states, const float* __restrict__ ctot,
                            bf16_t* __restrict__ initsb) {
  int id = blockIdx.x * 256 + threadIdx.x;   // < 2*32*8192
  int pn = id & 8191;
  int bh = id >> 13;
  int b = bh >> 5, h = bh & 31;
  float S = 0.f;
#pragma unroll
  for (int c = 0; c < 8; c++) {
    int blk = (b * 8 + c) * 32 + h;
    initsb[(long)blk * 8192 + pn] = __float2bfloat16(S);
    S = exp2f(ctot[blk]) * S + __bfloat162float(states[(long)blk * 8192 + pn]);
  }
}

// ------- MFMA Y: DMA-staged swizzled B tiles in LDS + fused gating epilogue ----------
__global__ __launch_bounds__(256) void yk3_kernel(const float* __restrict__ SL,
     const bf16_t* __restrict__ Cmh, const bf16_t* __restrict__ xhb,
     const bf16_t* __restrict__ zxh, const float* __restrict__ acs,
     const bf16_t* __restrict__ initsb, const bf16_t* __restrict__ xdT,
     const float* __restrict__ Dp, bf16_t* __restrict__ yg, float* __restrict__ ssqp) {
  int bi = blockIdx.x;
  int mh = bi & 1, h = (bi >> 1) & 31, bc = bi >> 6;
  int ablk = bc * 32 + h;
  int t = threadIdx.x;
  int lane = t & 63, wv = t >> 6;
  int l15 = lane & 15, l4 = lane >> 4;
  __shared__ float acsS[256];
  __shared__ bf16_t Ps[128 * PSTR];
  __shared__ __align__(16) char bbuf[49152];           // union: {xds 32KB + ins 16KB} / Yt
  bf16_t* xds = (bf16_t*)bbuf;                         // [64][256] swizzled (slot^= p&7)
  bf16_t* ins = (bf16_t*)(bbuf + 32768);               // [64][128] swizzled
  float* Yt = (float*)bbuf;                            // [128][66]

  // ---- DMA-stage B operands (coalesced, swizzled) ----
  {
    const bf16_t* xrow_g = xdT + (long)ablk * 64 * 256;
#pragma unroll
    for (int it = 0; it < 8; it++) {
      int sl = it * 256 + t;            // (p, s): p=sl>>5, s=sl&31
      int p = sl >> 5, s = sl & 31;
      int c = (s & 24) | ((s & 7) ^ (p & 7));
      gl_lds16(xrow_g + p * 256 + c * 8, &xds[sl * 8]);
    }
    const bf16_t* irow_g = initsb + (long)ablk * 8192;
#pragma unroll
    for (int it = 0; it < 4; it++) {
      int sl = it * 256 + t;            // (p, s): p=sl>>4, s=sl&15
      int p = sl >> 4, s = sl & 15;
      int c = (s & 8) | ((s & 7) ^ (p & 7));
      gl_lds16(irow_g + p * 128 + c * 8, &ins[sl * 8]);
    }
  }
  acsS[t] = acs[ablk * 256 + t];
  __syncthreads();

  const int l_loc = t >> 1, half = t & 1;
  const int l = mh * 128 + l_loc;
  const float al = acsS[l];
  const float eAl = exp2f(al);
  const int rowbase = bc * 256;
  const float* SLb = SL + (long)bc * 65536 + (long)l * 256;

  floatx4 acc[2][4];
#pragma unroll
  for (int i = 0; i < 2; i++)
#pragma unroll
    for (int j = 0; j < 4; j++) acc[i][j] = (floatx4){0.f, 0.f, 0.f, 0.f};

  const int nkd = (mh + 1) * 4;
  float4 slv[4];
#pragma unroll
  for (int q = 0; q < 4; q++) slv[q] = ((const float4*)(SLb + half * 16))[q];

  for (int kt = 0; kt < nkd + 4; kt++) {
    unsigned pk[8];
    if (kt < nkd) {
      int s0 = kt * 32 + half * 16;
#pragma unroll
      for (int q = 0; q < 4; q++) {
        float4 v = slv[q];
        int sb = s0 + q * 4;
        float p0 = (sb + 0 <= l) ? v.x * exp2f(al - acsS[sb + 0]) : 0.f;
        float p1 = (sb + 1 <= l) ? v.y * exp2f(al - acsS[sb + 1]) : 0.f;
        float p2 = (sb + 2 <= l) ? v.z * exp2f(al - acsS[sb + 2]) : 0.f;
        float p3 = (sb + 3 <= l) ? v.w * exp2f(al - acsS[sb + 3]) : 0.f;
        pk[q * 2 + 0] = pack_bf16_rn(p0, p1);
        pk[q * 2 + 1] = pack_bf16_rn(p2, p3);
      }
    } else {
      int n0 = (kt - nkd) * 32;
      const uint4* Cg = (const uint4*)(Cmh + (long)(rowbase + l) * DSTATE + n0 + half * 16);
      uint4 u0 = Cg[0], u1 = Cg[1];
      float cv[16];
      unp8(u0, cv); unp8(u1, cv + 8);
#pragma unroll
      for (int q = 0; q < 8; q++)
        pk[q] = pack_bf16_rn(cv[q * 2] * eAl, cv[q * 2 + 1] * eAl);
    }
    {
      uint4* pw = (uint4*)&Ps[l_loc * PSTR + half * 16];
      pw[0] = make_uint4(pk[0], pk[1], pk[2], pk[3]);
      pw[1] = make_uint4(pk[4], pk[5], pk[6], pk[7]);
    }
    // prefetch next diagonal SL tile across the barrier
    if (kt + 1 < nkd) {
#pragma unroll
      for (int q = 0; q < 4; q++)
        slv[q] = ((const float4*)(SLb + (kt + 1) * 32 + half * 16))[q];
    }
    __syncthreads();
    bfrag8 bfr[4];
    if (kt < nkd) {
      int ch = kt * 4 + l4;
#pragma unroll
      for (int j = 0; j < 4; j++) {
        int p = j * 16 + l15;
        int sw = (ch & 24) | ((ch & 7) ^ (p & 7));
        bfr[j] = *(const bfrag8*)&xds[(p * 32 + sw) * 8];
      }
    } else {
      int ch = (kt - nkd) * 4 + l4;
#pragma unroll
      for (int j = 0; j < 4; j++) {
        int p = j * 16 + l15;
        int sw = (ch & 8) | ((ch & 7) ^ (p & 7));
        bfr[j] = *(const bfrag8*)&ins[(p * 16 + sw) * 8];
      }
    }
#pragma unroll
    for (int i = 0; i < 2; i++) {
      bfrag8 af = *(const bfrag8*)&Ps[(wv * 32 + i * 16 + l15) * PSTR + l4 * 8];
#pragma unroll
      for (int j = 0; j < 4; j++)
        acc[i][j] = __builtin_amdgcn_mfma_f32_16x16x32_bf16(af, bfr[j], acc[i][j], 0, 0, 0);
    }
    __syncthreads();
  }
  // ---- epilogue: dump Y to LDS (union over xds/ins), re-read row-major, gate ----
#pragma unroll
  for (int i = 0; i < 2; i++)
#pragma unroll
    for (int j = 0; j < 4; j++)
#pragma unroll
      for (int r = 0; r < 4; r++)
        Yt[(wv * 32 + i * 16 + l4 * 4 + r) * 66 + j * 16 + l15] = acc[i][j][r];
  __syncthreads();
  {
    int row_l = t >> 1;
    int ch = (t & 1) * 32;
    long rowg = rowbase + mh * 128 + row_l;
    float Dh = Dp[h];
    float ss = 0.f;
#pragma unroll
    for (int it = 0; it < 4; it++) {
      int c = ch + it * 8;
      float4 y0 = *(const float4*)&Yt[row_l * 66 + c];
      float4 y1 = *(const float4*)&Yt[row_l * 66 + c + 4];
      uint4 ux = *(const uint4*)(xhb + rowg * DI + h * HD + c);
      uint4 uz = *(const uint4*)(zxh + rowg * NPAD + h * HD + c);
      float xv[8], zv[8];
      unp8(ux, xv); unp8(uz, zv);
      float yv[8] = {y0.x, y0.y, y0.z, y0.w, y1.x, y1.y, y1.z, y1.w};
      unsigned o[4];
#pragma unroll
      for (int q = 0; q < 4; q++) {
        float v0 = (yv[q * 2 + 0] + Dh * xv[q * 2 + 0]) *
                   (zv[q * 2 + 0] / (1.f + __expf(-zv[q * 2 + 0])));
        float v1 = (yv[q * 2 + 1] + Dh * xv[q * 2 + 1]) *
                   (zv[q * 2 + 1] / (1.f + __expf(-zv[q * 2 + 1])));
        ss += v0 * v0 + v1 * v1;
        o[q] = pack_bf16_rn(v0, v1);
      }
      *(uint4*)(yg + rowg * DI + h * HD + c) = make_uint4(o[0], o[1], o[2], o[3]);
    }
    ss += __shfl_xor(ss, 1, 64);
    if ((t & 1) == 0) ssqp[rowg * 32 + h] = ss;
  }
}

// ---------------- light gated-rmsnorm finish ----------------
__global__ void gnorm2_kernel(const bf16_t* __restrict__ yg, const float* __restrict__ ssqp,
                              const float* __restrict__ gw, bf16_t* __restrict__ yn) {
  int row = blockIdx.x, t = threadIdx.x;
  __shared__ float rsS;
  if (t < 64) {
    float v = (t < 32) ? ssqp[row * 32 + t] : 0.f;
#pragma unroll
    for (int off = 16; off > 0; off >>= 1) v += __shfl_down(v, off, 64);
    if (t == 0) rsS = rsqrtf(v * (1.f / DI) + EPSF);
  }
  __syncthreads();
  float rs = rsS;
  uint4 u = *(const uint4*)(yg + (long)row * DI + t * 8);
  float4 g0 = ((const float4*)gw)[t * 2];
  float4 g1 = ((const float4*)gw)[t * 2 + 1];
  unsigned o0 = pack_bf16_rn(blo(u.x) * rs * g0.x, bhi(u.x) * rs * g0.y);
  unsigned o1 = pack_bf16_rn(blo(u.y) * rs * g0.z, bhi(u.y) * rs * g0.w);
  unsigned o2 = pack_bf16_rn(blo(u.z) * rs * g1.x, bhi(u.z) * rs * g1.y);
  unsigned o3 = pack_bf16_rn(blo(u.w) * rs * g1.z, bhi(u.w) * rs * g1.w);
  *(uint4*)(yn + (long)row * DI + t * 8) = make_uint4(o0, o1, o2, o3);
}

extern "C" void kernel_launch(void* const* d_in, const int* in_sizes, int n_in,
                              void* d_out, int out_size, void* d_ws, size_t ws_size,
                              hipStream_t stream) {
  const float* x    = (const float*)d_in[0];
  const float* nw   = (const float*)d_in[1];
  const float* w1   = (const float*)d_in[2];
  const float* cw   = (const float*)d_in[3];
  const float* cb   = (const float*)d_in[4];
  const float* dtb  = (const float*)d_in[5];
  const float* alog = (const float*)d_in[6];
  const float* Dp   = (const float*)d_in[7];
  const float* gw   = (const float*)d_in[8];
  const float* w2   = (const float*)d_in[9];
  float* out = (float*)d_out;

  char* ws = (char*)d_ws;
  size_t off = 0;
  auto alloc = [&](size_t bytes) -> void* {
    void* p = ws + off;
    off += (bytes + 255) & ~(size_t)255;
    return p;
  };
  bf16_t* ub     = (bf16_t*)alloc((size_t)MR * DM * 2);
  bf16_t* w1b    = (bf16_t*)alloc((size_t)NPAD * DM * 2);
  bf16_t* w2b    = (bf16_t*)alloc((size_t)DM * DI * 2);
  bf16_t* zxh    = (bf16_t*)alloc((size_t)MR * NPAD * 2);
  bf16_t* xhb    = (bf16_t*)alloc((size_t)MR * DI * 2);
  bf16_t* Bmh    = (bf16_t*)alloc((size_t)MR * DSTATE * 2);
  bf16_t* Cmh    = (bf16_t*)alloc((size_t)MR * DSTATE * 2);
  float* SL      = (float*)alloc((size_t)16 * 256 * 256 * 4);
  float* dt      = (float*)alloc((size_t)MR * NHD * 4);
  float* acs     = (float*)alloc((size_t)512 * 256 * 4);
  float* ctot    = (float*)alloc((size_t)512 * 4);
  bf16_t* states = (bf16_t*)alloc((size_t)512 * 8192 * 2);
  bf16_t* initsb = (bf16_t*)alloc((size_t)512 * 8192 * 2);
  bf16_t* xdT    = (bf16_t*)alloc((size_t)512 * 64 * 256 * 2);
  bf16_t* xdTe   = (bf16_t*)alloc((size_t)512 * 64 * 256 * 2);
  bf16_t* BmT    = (bf16_t*)alloc((size_t)16 * 128 * 256 * 2);
  bf16_t* yg     = (bf16_t*)alloc((size_t)MR * DI * 2);
  float* ssqp    = (float*)alloc((size_t)MR * NHD * 4);
  bf16_t* yn     = (bf16_t*)alloc((size_t)MR * DI * 2);
  if (off > ws_size) return;

  rms1_kernel<<<MR, 256, 0, stream>>>(x, nw, ub);
  cvtw_kernel<<<(W1CNT + W2CNT) / 256, 256, 0, stream>>>(w1, w2, w1b, w2b);
  gemm64_kernel<128, false, true><<<dim3(MR / 128, NPAD / 128), 256, 0, stream>>>(
      ub, w1b, nullptr, zxh, NPAD, DM);
  conv4_kernel<<<(1024 * 288) / 256, 256, 0, stream>>>(zxh, cw, cb, xhb, Bmh, Cmh);
  acs_kernel<<<512, 256, 0, stream>>>(zxh, alog, dtb, acs, ctot, dt);
  xdt_kernel<<<528, 256, 0, stream>>>(xhb, Bmh, dt, acs, xdT, xdTe, BmT);
  gemm_s_kernel<<<dim3(2, 2, 16), 256, 0, stream>>>(Cmh, Bmh, SL);
  states3_kernel<<<512, 256, 0, stream>>>(xdTe, BmT, states);
  scan_kernel<<<(2 * 32 * 8192) / 256, 256, 0, stream>>>(states, ctot, initsb);
  yk3_kernel<<<1024, 256, 0, stream>>>(SL, Cmh, xhb, zxh, acs, initsb, xdT, Dp, yg, ssqp);
  gnorm2_kernel<<<MR, 256, 0, stream>>>(yg, ssqp, gw, yn);
  gemm64_kernel<64, true, false><<<dim3(MR / 128, DM / 64), 256, 0, stream>>>(
      yn, w2b, x, out, DM, DI);
}

// Round 7
// 282.718 us; speedup vs baseline: 3.3826x; 1.0280x over previous
//
#include <hip/hip_runtime.h>
#include <hip/hip_bf16.h>

typedef __hip_bfloat16 bf16_t;
typedef __attribute__((ext_vector_type(8))) short bfrag8;   // 8 bf16 (4 VGPRs)
typedef __attribute__((ext_vector_type(4))) float floatx4;  // MFMA acc

#define DM     1024
#define DI     2048
#define NHD    32
#define HD     64
#define DSTATE 128
#define CONVD  2304
#define NPROJ  4384
#define NPAD   4480
#define MR     4096      // B*L
#define LL     2048
#define EPSF   1e-5f
#define PSTR   40        // LDS row stride (bf16) for P tiles
#define LOG2E  1.44269504088896f

__device__ __forceinline__ void gl_lds16(const void* g, void* l) {
  __builtin_amdgcn_global_load_lds((const __attribute__((address_space(1))) void*)g,
                                   (__attribute__((address_space(3))) void*)l, 16, 0, 0);
}
__device__ __forceinline__ unsigned pack_bf16_rn(float a, float b) {
  unsigned ua = (__float_as_uint(a) + 0x8000u) >> 16;
  unsigned ub = (__float_as_uint(b) + 0x8000u) >> 16;
  return ua | (ub << 16);
}
__device__ __forceinline__ unsigned short bf16u(float a) {
  return (unsigned short)((__float_as_uint(a) + 0x8000u) >> 16);
}
__device__ __forceinline__ float blo(unsigned u){ return __uint_as_float(u << 16); }
__device__ __forceinline__ float bhi(unsigned u){ return __uint_as_float(u & 0xffff0000u); }
__device__ __forceinline__ void unp8(uint4 u, float* v) {
  v[0]=blo(u.x); v[1]=bhi(u.x); v[2]=blo(u.y); v[3]=bhi(u.y);
  v[4]=blo(u.z); v[5]=bhi(u.z); v[6]=blo(u.w); v[7]=bhi(u.w);
}

// ---------------- rmsnorm(x) -> u (bf16) ----------------
__global__ void rms1_kernel(const float* __restrict__ x, const float* __restrict__ w,
                            bf16_t* __restrict__ ub) {
  int row = blockIdx.x, t = threadIdx.x;
  float4 v = ((const float4*)(x + (long)row * DM))[t];
  float ss = v.x*v.x + v.y*v.y + v.z*v.z + v.w*v.w;
#pragma unroll
  for (int off = 32; off > 0; off >>= 1) ss += __shfl_down(ss, off, 64);
  __shared__ float red[4];
  if ((t & 63) == 0) red[t >> 6] = ss;
  __syncthreads();
  float tot = red[0] + red[1] + red[2] + red[3];
  float rs = rsqrtf(tot * (1.f / DM) + EPSF);
  float4 wv = ((const float4*)w)[t];
  bf16_t* o = ub + (long)row * DM + t * 4;
  o[0] = __float2bfloat16(v.x * rs * wv.x);
  o[1] = __float2bfloat16(v.y * rs * wv.y);
  o[2] = __float2bfloat16(v.z * rs * wv.z);
  o[3] = __float2bfloat16(v.w * rs * wv.w);
}

// ---------------- weights fp32->bf16 (merged; gnorm_w folded into w2) ----------------
#define W1CNT (NPAD * DM / 4)
#define W2CNT (DM * DI / 4)
__global__ void cvtw_kernel(const float* __restrict__ w1, const float* __restrict__ w2,
                            const float* __restrict__ gw,
                            bf16_t* __restrict__ o1, bf16_t* __restrict__ o2) {
  int i4 = blockIdx.x * 256 + threadIdx.x;
  if (i4 < W1CNT) {
    int idx = i4 * 4;
    int row = idx >> 10;
    float4 v = make_float4(0.f, 0.f, 0.f, 0.f);
    if (row < NPROJ) v = *(const float4*)(w1 + idx);
    bf16_t* d = o1 + idx;
    d[0] = __float2bfloat16(v.x); d[1] = __float2bfloat16(v.y);
    d[2] = __float2bfloat16(v.z); d[3] = __float2bfloat16(v.w);
  } else {
    int idx = (i4 - W1CNT) * 4;
    int k = idx & (DI - 1);
    float4 v = *(const float4*)(w2 + idx);
    float4 g = *(const float4*)(gw + k);
    bf16_t* d = o2 + idx;
    d[0] = __float2bfloat16(v.x * g.x); d[1] = __float2bfloat16(v.y * g.y);
    d[2] = __float2bfloat16(v.z * g.z); d[3] = __float2bfloat16(v.w * g.w);
  }
}

// ---------------- BK=64 swizzled MFMA GEMM: C[M,N] = A[M,K] @ B[N,K]^T ----------------
// DO_RES path also applies per-row scale rs_row (gated rmsnorm fold): C = acc*rs + resid
template<int TN, bool DO_RES, bool OUT_BF16>
__global__ __launch_bounds__(256) void gemm64_kernel(const bf16_t* __restrict__ A,
    const bf16_t* __restrict__ Bw, const float* __restrict__ resid,
    const float* __restrict__ rs_row, void* __restrict__ Cout, int N, int K) {
  __shared__ bf16_t As[128 * 64];
  __shared__ bf16_t Bs[TN * 64];
  const int tid = threadIdx.x;
  const int lane = tid & 63;
  const int wv = tid >> 6;
  const int l15 = lane & 15;
  const int l4 = lane >> 4;
  constexpr int MF = (TN == 128) ? 4 : 2;
  const int wm = (TN == 128) ? ((wv >> 1) << 6) : (wv << 5);
  const int wn = (TN == 128) ? ((wv & 1) << 6) : 0;
  const int tm = blockIdx.x << 7;
  const int tn = blockIdx.y * TN;

  floatx4 acc[MF][4];
#pragma unroll
  for (int i = 0; i < MF; i++)
#pragma unroll
    for (int j = 0; j < 4; j++) acc[i][j] = (floatx4){0.f, 0.f, 0.f, 0.f};

  const int r = tid >> 3;
  const int c8 = tid & 7;
  const int scol = ((c8 ^ (r & 7)) << 3);
  const bf16_t* Ag = A + (long)(tm + r) * K + scol;
  const bf16_t* Bg = Bw + (long)(tn + r) * K + scol;
  const int swz = l15 & 7;

  for (int k0 = 0; k0 < K; k0 += 64) {
#pragma unroll
    for (int q = 0; q < 4; q++)
      gl_lds16(Ag + (long)(q * 32) * K + k0, &As[q * 2048 + tid * 8]);
#pragma unroll
    for (int q = 0; q < TN / 32; q++)
      gl_lds16(Bg + (long)(q * 32) * K + k0, &Bs[q * 2048 + tid * 8]);
    __syncthreads();
#pragma unroll
    for (int kk = 0; kk < 2; kk++) {
      bfrag8 af[MF], bfr[4];
      const int ch = ((kk << 2) | l4) ^ swz;
#pragma unroll
      for (int j = 0; j < 4; j++)
        bfr[j] = *(const bfrag8*)&Bs[(wn + j * 16 + l15) * 64 + ch * 8];
#pragma unroll
      for (int i = 0; i < MF; i++)
        af[i] = *(const bfrag8*)&As[(wm + i * 16 + l15) * 64 + ch * 8];
#pragma unroll
      for (int i = 0; i < MF; i++)
#pragma unroll
        for (int j = 0; j < 4; j++)
          acc[i][j] = __builtin_amdgcn_mfma_f32_16x16x32_bf16(af[i], bfr[j], acc[i][j], 0, 0, 0);
    }
    __syncthreads();
  }
#pragma unroll
  for (int i = 0; i < MF; i++)
#pragma unroll
    for (int j = 0; j < 4; j++)
#pragma unroll
      for (int r2 = 0; r2 < 4; r2++) {
        int row = tm + wm + i * 16 + l4 * 4 + r2;
        int col = tn + wn + j * 16 + l15;
        float v = acc[i][j][r2];
        if (OUT_BF16) {
          ((bf16_t*)Cout)[(long)row * N + col] = __float2bfloat16(v);
        } else {
          if (DO_RES) v = v * rs_row[row] + resid[(long)row * N + col];
          ((float*)Cout)[(long)row * N + col] = v;
        }
      }
}

// ---------------- batched S GEMM: SL[bc][l][s] = Cm[l].Bm[s] (M=N=256,K=128) ----------
__global__ __launch_bounds__(256) void gemm_s_kernel(const bf16_t* __restrict__ Cmh,
                const bf16_t* __restrict__ Bmh, float* __restrict__ SL) {
  __shared__ bf16_t As[128 * 32];
  __shared__ bf16_t Bs[128 * 32];
  const int tid = threadIdx.x;
  const int lane = tid & 63;
  const int wv = tid >> 6;
  const int wm = (wv >> 1) << 6;
  const int wn = (wv & 1) << 6;
  const int bc = blockIdx.z;
  const int tm = blockIdx.x << 7;
  const int tn = blockIdx.y << 7;
  const int l15 = lane & 15;
  const int l4 = lane >> 4;
  floatx4 acc[4][4];
#pragma unroll
  for (int i = 0; i < 4; i++)
#pragma unroll
    for (int j = 0; j < 4; j++) acc[i][j] = (floatx4){0.f, 0.f, 0.f, 0.f};
  const int arow = tid >> 2;
  const int acol = (tid & 3) << 3;
  const bf16_t* Ag = Cmh + (long)bc * 256 * DSTATE + (long)(tm + arow) * DSTATE + acol;
  const bf16_t* Bg = Bmh + (long)bc * 256 * DSTATE + (long)(tn + arow) * DSTATE + acol;
  const long k64 = (long)64 * DSTATE;
  for (int k0 = 0; k0 < DSTATE; k0 += 32) {
    gl_lds16(Ag + k0, &As[tid * 8]);
    gl_lds16(Ag + k64 + k0, &As[2048 + tid * 8]);
    gl_lds16(Bg + k0, &Bs[tid * 8]);
    gl_lds16(Bg + k64 + k0, &Bs[2048 + tid * 8]);
    __syncthreads();
    bfrag8 af[4], bfr[4];
#pragma unroll
    for (int i = 0; i < 4; i++)
      af[i] = *(const bfrag8*)&As[(wm + i * 16 + l15) * 32 + l4 * 8];
#pragma unroll
    for (int j = 0; j < 4; j++)
      bfr[j] = *(const bfrag8*)&Bs[(wn + j * 16 + l15) * 32 + l4 * 8];
#pragma unroll
    for (int i = 0; i < 4; i++)
#pragma unroll
      for (int j = 0; j < 4; j++)
        acc[i][j] = __builtin_amdgcn_mfma_f32_16x16x32_bf16(af[i], bfr[j], acc[i][j], 0, 0, 0);
    __syncthreads();
  }
  float* Cb = SL + (long)bc * 65536;
#pragma unroll
  for (int i = 0; i < 4; i++)
#pragma unroll
    for (int j = 0; j < 4; j++)
#pragma unroll
      for (int r = 0; r < 4; r++)
        Cb[(long)(tm + wm + i * 16 + l4 * 4 + r) * 256 + tn + wn + j * 16 + l15] = acc[i][j][r];
}

// ---------------- vectorized conv4 + bias + silu: 8 channels x 4 rows / thread -------
__global__ __launch_bounds__(256) void conv4_kernel(const bf16_t* __restrict__ zxh,
    const float* __restrict__ cw, const float* __restrict__ cb,
    bf16_t* __restrict__ xhb, bf16_t* __restrict__ Bmh, bf16_t* __restrict__ Cmh) {
  int g = blockIdx.x * 256 + threadIdx.x;    // < 1024*288
  int cg = g % 288;
  int blt = g / 288;
  int c0 = cg * 8;
  long bl0 = (long)blt * 4;
  int l0 = (int)(bl0 & (LL - 1));
  const bf16_t* base = zxh + bl0 * NPAD + DI + c0;
  float rv[7][8];
#pragma unroll
  for (int j = 0; j < 7; j++) {
    int dj = j - 3;
    if (l0 + dj >= 0) {
      uint4 u = *(const uint4*)(base + (long)dj * NPAD);
      unp8(u, rv[j]);
    } else {
#pragma unroll
      for (int q = 0; q < 8; q++) rv[j][q] = 0.f;
    }
  }
  float4 wq[8];
#pragma unroll
  for (int q = 0; q < 8; q++) wq[q] = ((const float4*)cw)[c0 + q];
  float bias[8];
  *(float4*)&bias[0] = *(const float4*)(cb + c0);
  *(float4*)&bias[4] = *(const float4*)(cb + c0 + 4);
#pragma unroll
  for (int i = 0; i < 4; i++) {
    unsigned o[4];
#pragma unroll
    for (int q2 = 0; q2 < 4; q2++) {
      float rr[2];
#pragma unroll
      for (int e = 0; e < 2; e++) {
        int q = q2 * 2 + e;
        float a = bias[q] + wq[q].x * rv[i][q] + wq[q].y * rv[i + 1][q]
                + wq[q].z * rv[i + 2][q] + wq[q].w * rv[i + 3][q];
        rr[e] = a / (1.f + __expf(-a));
      }
      o[q2] = pack_bf16_rn(rr[0], rr[1]);
    }
    uint4 ov = make_uint4(o[0], o[1], o[2], o[3]);
    long bl = bl0 + i;
    if (c0 < DI)               *(uint4*)(xhb + bl * DI + c0) = ov;
    else if (c0 < DI + DSTATE) *(uint4*)(Bmh + bl * DSTATE + (c0 - DI)) = ov;
    else                       *(uint4*)(Cmh + bl * DSTATE + (c0 - DI - DSTATE)) = ov;
  }
}

// ------- fused: softplus(dt)+cumsum (per b,c,h) + transposes xdT/xdTe; BmT branch ----
__global__ __launch_bounds__(256) void xdt_kernel(const bf16_t* __restrict__ xhb,
    const bf16_t* __restrict__ Bmh, const bf16_t* __restrict__ zxh,
    const float* __restrict__ A_log, const float* __restrict__ dtb,
    float* __restrict__ acs, float* __restrict__ ctot,
    bf16_t* __restrict__ xdT, bf16_t* __restrict__ xdTe, bf16_t* __restrict__ BmT) {
  __shared__ unsigned short Tb[9216];   // 2x 64x72 (xdt) or 1x 128x72 (bmt)
  __shared__ float acsL[256];
  __shared__ float dtsL[256];
  __shared__ float wsum[4];
  int blk = blockIdx.x;
  int t = threadIdx.x;
  if (blk < 512) {
    int h = blk & 31, bc = blk >> 5;
    {   // ---- fused softplus + log2-scaled cumsum ----
      int lane = t & 63, w = t >> 6;
      float Ah = -__expf(A_log[h]) * LOG2E;
      int gl = bc * 256 + t;
      float vv = __bfloat162float(zxh[(long)gl * NPAD + (NPROJ - 32) + h]) + dtb[h];
      float sp = fmaxf(vv, 0.f) + log1pf(__expf(-fabsf(vv)));
      float a = sp * Ah;
#pragma unroll
      for (int off = 1; off < 64; off <<= 1) {
        float v = __shfl_up(a, off, 64);
        if (lane >= off) a += v;
      }
      if (lane == 63) wsum[w] = a;
      __syncthreads();
      float base = 0.f;
      for (int i = 0; i < 4; i++) base += (i < w) ? wsum[i] : 0.f;
      a += base;
      acsL[t] = a;
      dtsL[t] = sp;
      acs[blk * 256 + t] = a;
      if (t == 255) ctot[blk] = a;
      __syncthreads();
    }
    float atot = acsL[255];
    unsigned short* T1 = Tb;
    unsigned short* T2 = Tb + 4608;
    int l_loc = t >> 2, pg = t & 3;
    for (int lt = 0; lt < 4; lt++) {
      int ll = lt * 64 + l_loc;
      int gl = bc * 256 + ll;
      float w1 = dtsL[ll];
      float w2 = w1 * exp2f(atot - acsL[ll]);
      const uint4* src = (const uint4*)(xhb + (long)gl * DI + h * HD + pg * 16);
      uint4 u0 = src[0], u1 = src[1];
      float v[16];
      unp8(u0, v); unp8(u1, v + 8);
      __syncthreads();
#pragma unroll
      for (int q = 0; q < 16; q++) {
        T1[(pg * 16 + q) * 72 + l_loc] = bf16u(v[q] * w1);
        T2[(pg * 16 + q) * 72 + l_loc] = bf16u(v[q] * w2);
      }
      __syncthreads();
      long orow = ((long)blk * 64 + l_loc) * 256 + lt * 64 + pg * 16;
      *(uint4*)(xdT + orow)      = *(uint4*)&T1[l_loc * 72 + pg * 16];
      *(uint4*)(xdT + orow + 8)  = *(uint4*)&T1[l_loc * 72 + pg * 16 + 8];
      *(uint4*)(xdTe + orow)     = *(uint4*)&T2[l_loc * 72 + pg * 16];
      *(uint4*)(xdTe + orow + 8) = *(uint4*)&T2[l_loc * 72 + pg * 16 + 8];
    }
  } else {
    unsigned short* T = Tb;
    int bc = blk - 512;
    int l_loc = t >> 2, ng = t & 3;
    for (int lt = 0; lt < 4; lt++) {
      int gl = bc * 256 + lt * 64 + l_loc;
      const uint4* src = (const uint4*)(Bmh + (long)gl * DSTATE + ng * 32);
      uint4 u[4];
#pragma unroll
      for (int q = 0; q < 4; q++) u[q] = src[q];
      __syncthreads();
      const unsigned short* us = (const unsigned short*)u;
#pragma unroll
      for (int e = 0; e < 32; e++)
        T[(ng * 32 + e) * 72 + l_loc] = us[e];
      __syncthreads();
      int n = t >> 1, lg2 = t & 1;
      long orow = ((long)bc * 128 + n) * 256 + lt * 64 + lg2 * 32;
#pragma unroll
      for (int q = 0; q < 4; q++)
        *(uint4*)(BmT + orow + q * 8) = *(uint4*)&T[n * 72 + lg2 * 32 + q * 8];
    }
  }
}

// ---------------- chunk states: pure register MFMA GEMM (no LDS, no barriers) --------
__global__ __launch_bounds__(256) void states3_kernel(const bf16_t* __restrict__ xdTe,
    const bf16_t* __restrict__ BmT, bf16_t* __restrict__ states) {
  int blk = blockIdx.x;    // bc*32+h
  int bc = blk >> 5;
  int t = threadIdx.x, lane = t & 63, wv = t >> 6;
  int l15 = lane & 15, l4 = lane >> 4;
  floatx4 acc[2][4];
#pragma unroll
  for (int i = 0; i < 2; i++)
#pragma unroll
    for (int j = 0; j < 4; j++) acc[i][j] = (floatx4){0.f, 0.f, 0.f, 0.f};
  const bf16_t* arow = BmT + (long)bc * 128 * 256;
  const bf16_t* brow = xdTe + (long)blk * 64 * 256;
#pragma unroll
  for (int kt = 0; kt < 8; kt++) {
    bfrag8 af[2], bfr[4];
#pragma unroll
    for (int i = 0; i < 2; i++)
      af[i] = *(const bfrag8*)(arow + (long)(wv * 32 + i * 16 + l15) * 256 + kt * 32 + l4 * 8);
#pragma unroll
    for (int j = 0; j < 4; j++)
      bfr[j] = *(const bfrag8*)(brow + (long)(j * 16 + l15) * 256 + kt * 32 + l4 * 8);
#pragma unroll
    for (int i = 0; i < 2; i++)
#pragma unroll
      for (int j = 0; j < 4; j++)
        acc[i][j] = __builtin_amdgcn_mfma_f32_16x16x32_bf16(af[i], bfr[j], acc[i][j], 0, 0, 0);
  }
#pragma unroll
  for (int i = 0; i < 2; i++)
#pragma unroll
    for (int j = 0; j < 4; j++) {
      int n_base = wv * 32 + i * 16 + l4 * 4;
      int p = j * 16 + l15;
      unsigned lo = pack_bf16_rn(acc[i][j][0], acc[i][j][1]);
      unsigned hi = pack_bf16_rn(acc[i][j][2], acc[i][j][3]);
      *(uint2*)(states + (long)blk * 8192 + p * 128 + n_base) = make_uint2(lo, hi);
    }
}

// ---------------- inter-chunk scan -> init states (bf16 in/out; ctot log2-scaled) -----
__global__ void scan_kernel(const bf16_t* __restrict__ states, const float* __restrict__ ctot,
                            bf16_t* __restrict__ initsb) {
  int id = blockIdx.x * 256 + threadIdx.x;   // < 2*32*8192
  int pn = id & 8191;
  int bh = id >> 13;
  int b = bh >> 5, h = bh & 31;
  float S = 0.f;
#pragma unroll
  for (int c = 0; c < 8; c++) {
    int blk = (b * 8 + c) * 32 + h;
    initsb[(long)blk * 8192 + pn] = __float2bfloat16(S);
    S = exp2f(ctot[blk]) * S + __bfloat162float(states[(long)blk * 8192 + pn]);
  }
}

// ------- MFMA Y: DMA-staged swizzled B tiles in LDS + fused gating epilogue ----------
__global__ __launch_bounds__(256) void yk3_kernel(const float* __restrict__ SL,
     const bf16_t* __restrict__ Cmh, const bf16_t* __restrict__ xhb,
     const bf16_t* __restrict__ zxh, const float* __restrict__ acs,
     const bf16_t* __restrict__ initsb, const bf16_t* __restrict__ xdT,
     const float* __restrict__ Dp, bf16_t* __restrict__ yg, float* __restrict__ ssqp) {
  int bi = blockIdx.x;
  int mh = bi & 1, h = (bi >> 1) & 31, bc = bi >> 6;
  int ablk = bc * 32 + h;
  int t = threadIdx.x;
  int lane = t & 63, wv = t >> 6;
  int l15 = lane & 15, l4 = lane >> 4;
  __shared__ float acsS[256];
  __shared__ bf16_t Ps[128 * PSTR];
  __shared__ __align__(16) char bbuf[49152];           // union: {xds 32KB + ins 16KB} / Yt
  bf16_t* xds = (bf16_t*)bbuf;                         // [64][256] swizzled (slot^= p&7)
  bf16_t* ins = (bf16_t*)(bbuf + 32768);               // [64][128] swizzled
  float* Yt = (float*)bbuf;                            // [128][66]

  {
    const bf16_t* xrow_g = xdT + (long)ablk * 64 * 256;
#pragma unroll
    for (int it = 0; it < 8; it++) {
      int sl = it * 256 + t;
      int p = sl >> 5, s = sl & 31;
      int c = (s & 24) | ((s & 7) ^ (p & 7));
      gl_lds16(xrow_g + p * 256 + c * 8, &xds[sl * 8]);
    }
    const bf16_t* irow_g = initsb + (long)ablk * 8192;
#pragma unroll
    for (int it = 0; it < 4; it++) {
      int sl = it * 256 + t;
      int p = sl >> 4, s = sl & 15;
      int c = (s & 8) | ((s & 7) ^ (p & 7));
      gl_lds16(irow_g + p * 128 + c * 8, &ins[sl * 8]);
    }
  }
  acsS[t] = acs[ablk * 256 + t];
  __syncthreads();

  const int l_loc = t >> 1, half = t & 1;
  const int l = mh * 128 + l_loc;
  const float al = acsS[l];
  const float eAl = exp2f(al);
  const int rowbase = bc * 256;
  const float* SLb = SL + (long)bc * 65536 + (long)l * 256;

  floatx4 acc[2][4];
#pragma unroll
  for (int i = 0; i < 2; i++)
#pragma unroll
    for (int j = 0; j < 4; j++) acc[i][j] = (floatx4){0.f, 0.f, 0.f, 0.f};

  const int nkd = (mh + 1) * 4;
  float4 slv[4];
#pragma unroll
  for (int q = 0; q < 4; q++) slv[q] = ((const float4*)(SLb + half * 16))[q];

  for (int kt = 0; kt < nkd + 4; kt++) {
    unsigned pk[8];
    if (kt < nkd) {
      int s0 = kt * 32 + half * 16;
#pragma unroll
      for (int q = 0; q < 4; q++) {
        float4 v = slv[q];
        int sb = s0 + q * 4;
        float p0 = (sb + 0 <= l) ? v.x * exp2f(al - acsS[sb + 0]) : 0.f;
        float p1 = (sb + 1 <= l) ? v.y * exp2f(al - acsS[sb + 1]) : 0.f;
        float p2 = (sb + 2 <= l) ? v.z * exp2f(al - acsS[sb + 2]) : 0.f;
        float p3 = (sb + 3 <= l) ? v.w * exp2f(al - acsS[sb + 3]) : 0.f;
        pk[q * 2 + 0] = pack_bf16_rn(p0, p1);
        pk[q * 2 + 1] = pack_bf16_rn(p2, p3);
      }
    } else {
      int n0 = (kt - nkd) * 32;
      const uint4* Cg = (const uint4*)(Cmh + (long)(rowbase + l) * DSTATE + n0 + half * 16);
      uint4 u0 = Cg[0], u1 = Cg[1];
      float cv[16];
      unp8(u0, cv); unp8(u1, cv + 8);
#pragma unroll
      for (int q = 0; q < 8; q++)
        pk[q] = pack_bf16_rn(cv[q * 2] * eAl, cv[q * 2 + 1] * eAl);
    }
    {
      uint4* pw = (uint4*)&Ps[l_loc * PSTR + half * 16];
      pw[0] = make_uint4(pk[0], pk[1], pk[2], pk[3]);
      pw[1] = make_uint4(pk[4], pk[5], pk[6], pk[7]);
    }
    if (kt + 1 < nkd) {
#pragma unroll
      for (int q = 0; q < 4; q++)
        slv[q] = ((const float4*)(SLb + (kt + 1) * 32 + half * 16))[q];
    }
    __syncthreads();
    bfrag8 bfr[4];
    if (kt < nkd) {
      int ch = kt * 4 + l4;
#pragma unroll
      for (int j = 0; j < 4; j++) {
        int p = j * 16 + l15;
        int sw = (ch & 24) | ((ch & 7) ^ (p & 7));
        bfr[j] = *(const bfrag8*)&xds[(p * 32 + sw) * 8];
      }
    } else {
      int ch = (kt - nkd) * 4 + l4;
#pragma unroll
      for (int j = 0; j < 4; j++) {
        int p = j * 16 + l15;
        int sw = (ch & 8) | ((ch & 7) ^ (p & 7));
        bfr[j] = *(const bfrag8*)&ins[(p * 16 + sw) * 8];
      }
    }
#pragma unroll
    for (int i = 0; i < 2; i++) {
      bfrag8 af = *(const bfrag8*)&Ps[(wv * 32 + i * 16 + l15) * PSTR + l4 * 8];
#pragma unroll
      for (int j = 0; j < 4; j++)
        acc[i][j] = __builtin_amdgcn_mfma_f32_16x16x32_bf16(af, bfr[j], acc[i][j], 0, 0, 0);
    }
    __syncthreads();
  }
#pragma unroll
  for (int i = 0; i < 2; i++)
#pragma unroll
    for (int j = 0; j < 4; j++)
#pragma unroll
      for (int r = 0; r < 4; r++)
        Yt[(wv * 32 + i * 16 + l4 * 4 + r) * 66 + j * 16 + l15] = acc[i][j][r];
  __syncthreads();
  {
    int row_l = t >> 1;
    int ch = (t & 1) * 32;
    long rowg = rowbase + mh * 128 + row_l;
    float Dh = Dp[h];
    float ss = 0.f;
#pragma unroll
    for (int it = 0; it < 4; it++) {
      int c = ch + it * 8;
      float4 y0 = *(const float4*)&Yt[row_l * 66 + c];
      float4 y1 = *(const float4*)&Yt[row_l * 66 + c + 4];
      uint4 ux = *(const uint4*)(xhb + rowg * DI + h * HD + c);
      uint4 uz = *(const uint4*)(zxh + rowg * NPAD + h * HD + c);
      float xv[8], zv[8];
      unp8(ux, xv); unp8(uz, zv);
      float yv[8] = {y0.x, y0.y, y0.z, y0.w, y1.x, y1.y, y1.z, y1.w};
      unsigned o[4];
#pragma unroll
      for (int q = 0; q < 4; q++) {
        float v0 = (yv[q * 2 + 0] + Dh * xv[q * 2 + 0]) *
                   (zv[q * 2 + 0] / (1.f + __expf(-zv[q * 2 + 0])));
        float v1 = (yv[q * 2 + 1] + Dh * xv[q * 2 + 1]) *
                   (zv[q * 2 + 1] / (1.f + __expf(-zv[q * 2 + 1])));
        ss += v0 * v0 + v1 * v1;
        o[q] = pack_bf16_rn(v0, v1);
      }
      *(uint4*)(yg + rowg * DI + h * HD + c) = make_uint4(o[0], o[1], o[2], o[3]);
    }
    ss += __shfl_xor(ss, 1, 64);
    if ((t & 1) == 0) ssqp[rowg * 32 + h] = ss;
  }
}

// ---------------- per-row 1/rms from ssq partials ----------------
__global__ void rsred_kernel(const float* __restrict__ ssqp, float* __restrict__ rs) {
  int row = blockIdx.x * 256 + threadIdx.x;   // < MR
  const float4* p = (const float4*)(ssqp + row * 32);
  float s = 0.f;
#pragma unroll
  for (int q = 0; q < 8; q++) {
    float4 v = p[q];
    s += v.x + v.y + v.z + v.w;
  }
  rs[row] = rsqrtf(s * (1.f / DI) + EPSF);
}

extern "C" void kernel_launch(void* const* d_in, const int* in_sizes, int n_in,
                              void* d_out, int out_size, void* d_ws, size_t ws_size,
                              hipStream_t stream) {
  const float* x    = (const float*)d_in[0];
  const float* nw   = (const float*)d_in[1];
  const float* w1   = (const float*)d_in[2];
  const float* cw   = (const float*)d_in[3];
  const float* cb   = (const float*)d_in[4];
  const float* dtb  = (const float*)d_in[5];
  const float* alog = (const float*)d_in[6];
  const float* Dp   = (const float*)d_in[7];
  const float* gw   = (const float*)d_in[8];
  const float* w2   = (const float*)d_in[9];
  float* out = (float*)d_out;

  char* ws = (char*)d_ws;
  size_t off = 0;
  auto alloc = [&](size_t bytes) -> void* {
    void* p = ws + off;
    off += (bytes + 255) & ~(size_t)255;
    return p;
  };
  bf16_t* ub     = (bf16_t*)alloc((size_t)MR * DM * 2);
  bf16_t* w1b    = (bf16_t*)alloc((size_t)NPAD * DM * 2);
  bf16_t* w2b    = (bf16_t*)alloc((size_t)DM * DI * 2);
  bf16_t* zxh    = (bf16_t*)alloc((size_t)MR * NPAD * 2);
  bf16_t* xhb    = (bf16_t*)alloc((size_t)MR * DI * 2);
  bf16_t* Bmh    = (bf16_t*)alloc((size_t)MR * DSTATE * 2);
  bf16_t* Cmh    = (bf16_t*)alloc((size_t)MR * DSTATE * 2);
  float* SL      = (float*)alloc((size_t)16 * 256 * 256 * 4);
  float* acs     = (float*)alloc((size_t)512 * 256 * 4);
  float* ctot    = (float*)alloc((size_t)512 * 4);
  bf16_t* states = (bf16_t*)alloc((size_t)512 * 8192 * 2);
  bf16_t* initsb = (bf16_t*)alloc((size_t)512 * 8192 * 2);
  bf16_t* xdT    = (bf16_t*)alloc((size_t)512 * 64 * 256 * 2);
  bf16_t* xdTe   = (bf16_t*)alloc((size_t)512 * 64 * 256 * 2);
  bf16_t* BmT    = (bf16_t*)alloc((size_t)16 * 128 * 256 * 2);
  bf16_t* yg     = (bf16_t*)alloc((size_t)MR * DI * 2);
  float* ssqp    = (float*)alloc((size_t)MR * NHD * 4);
  float* rs      = (float*)alloc((size_t)MR * 4);
  if (off > ws_size) return;

  rms1_kernel<<<MR, 256, 0, stream>>>(x, nw, ub);
  cvtw_kernel<<<(W1CNT + W2CNT) / 256, 256, 0, stream>>>(w1, w2, gw, w1b, w2b);
  gemm64_kernel<128, false, true><<<dim3(MR / 128, NPAD / 128), 256, 0, stream>>>(
      ub, w1b, nullptr, nullptr, zxh, NPAD, DM);
  conv4_kernel<<<(1024 * 288) / 256, 256, 0, stream>>>(zxh, cw, cb, xhb, Bmh, Cmh);
  xdt_kernel<<<528, 256, 0, stream>>>(xhb, Bmh, zxh, alog, dtb, acs, ctot, xdT, xdTe, BmT);
  gemm_s_kernel<<<dim3(2, 2, 16), 256, 0, stream>>>(Cmh, Bmh, SL);
  states3_kernel<<<512, 256, 0, stream>>>(xdTe, BmT, states);
  scan_kernel<<<(2 * 32 * 8192) / 256, 256, 0, stream>>>(states, ctot, initsb);
  yk3_kernel<<<1024, 256, 0, stream>>>(SL, Cmh, xhb, zxh, acs, initsb, xdT, Dp, yg, ssqp);
  rsred_kernel<<<MR / 256, 256, 0, stream>>>(ssqp, rs);
  gemm64_kernel<64, true, false><<<dim3(MR / 128, DM / 64), 256, 0, stream>>>(
      yg, w2b, x, rs, out, DM, DI);
}

// Round 8
// 265.834 us; speedup vs baseline: 3.5974x; 1.0635x over previous
//
#include <hip/hip_runtime.h>
#include <hip/hip_bf16.h>

typedef __hip_bfloat16 bf16_t;
typedef __attribute__((ext_vector_type(8))) short bfrag8;   // 8 bf16 (4 VGPRs)
typedef __attribute__((ext_vector_type(4))) float floatx4;  // MFMA acc

#define DM     1024
#define DI     2048
#define NHD    32
#define HD     64
#define DSTATE 128
#define CONVD  2304
#define NPROJ  4384
#define NPAD   4480
#define MR     4096      // B*L
#define LL     2048
#define EPSF   1e-5f
#define LOG2E  1.44269504088896f

__device__ __forceinline__ void gl_lds16(const void* g, void* l) {
  __builtin_amdgcn_global_load_lds((const __attribute__((address_space(1))) void*)g,
                                   (__attribute__((address_space(3))) void*)l, 16, 0, 0);
}
__device__ __forceinline__ unsigned pack_bf16_rn(float a, float b) {
  unsigned ua = (__float_as_uint(a) + 0x8000u) >> 16;
  unsigned ub = (__float_as_uint(b) + 0x8000u) >> 16;
  return ua | (ub << 16);
}
__device__ __forceinline__ unsigned short bf16u(float a) {
  return (unsigned short)((__float_as_uint(a) + 0x8000u) >> 16);
}
__device__ __forceinline__ float blo(unsigned u){ return __uint_as_float(u << 16); }
__device__ __forceinline__ float bhi(unsigned u){ return __uint_as_float(u & 0xffff0000u); }
__device__ __forceinline__ void unp8(uint4 u, float* v) {
  v[0]=blo(u.x); v[1]=bhi(u.x); v[2]=blo(u.y); v[3]=bhi(u.y);
  v[4]=blo(u.z); v[5]=bhi(u.z); v[6]=blo(u.w); v[7]=bhi(u.w);
}
typedef union { unsigned u[4]; bfrag8 f; } fragu;

// ---------------- rmsnorm(x) -> u (bf16) ----------------
__global__ void rms1_kernel(const float* __restrict__ x, const float* __restrict__ w,
                            bf16_t* __restrict__ ub) {
  int row = blockIdx.x, t = threadIdx.x;
  float4 v = ((const float4*)(x + (long)row * DM))[t];
  float ss = v.x*v.x + v.y*v.y + v.z*v.z + v.w*v.w;
#pragma unroll
  for (int off = 32; off > 0; off >>= 1) ss += __shfl_down(ss, off, 64);
  __shared__ float red[4];
  if ((t & 63) == 0) red[t >> 6] = ss;
  __syncthreads();
  float tot = red[0] + red[1] + red[2] + red[3];
  float rs = rsqrtf(tot * (1.f / DM) + EPSF);
  float4 wv = ((const float4*)w)[t];
  bf16_t* o = ub + (long)row * DM + t * 4;
  o[0] = __float2bfloat16(v.x * rs * wv.x);
  o[1] = __float2bfloat16(v.y * rs * wv.y);
  o[2] = __float2bfloat16(v.z * rs * wv.z);
  o[3] = __float2bfloat16(v.w * rs * wv.w);
}

// ---------------- weights fp32->bf16 (merged; gnorm_w folded into w2) ----------------
#define W1CNT (NPAD * DM / 4)
#define W2CNT (DM * DI / 4)
__global__ void cvtw_kernel(const float* __restrict__ w1, const float* __restrict__ w2,
                            const float* __restrict__ gw,
                            bf16_t* __restrict__ o1, bf16_t* __restrict__ o2) {
  int i4 = blockIdx.x * 256 + threadIdx.x;
  if (i4 < W1CNT) {
    int idx = i4 * 4;
    int row = idx >> 10;
    float4 v = make_float4(0.f, 0.f, 0.f, 0.f);
    if (row < NPROJ) v = *(const float4*)(w1 + idx);
    bf16_t* d = o1 + idx;
    d[0] = __float2bfloat16(v.x); d[1] = __float2bfloat16(v.y);
    d[2] = __float2bfloat16(v.z); d[3] = __float2bfloat16(v.w);
  } else {
    int idx = (i4 - W1CNT) * 4;
    int k = idx & (DI - 1);
    float4 v = *(const float4*)(w2 + idx);
    float4 g = *(const float4*)(gw + k);
    bf16_t* d = o2 + idx;
    d[0] = __float2bfloat16(v.x * g.x); d[1] = __float2bfloat16(v.y * g.y);
    d[2] = __float2bfloat16(v.z * g.z); d[3] = __float2bfloat16(v.w * g.w);
  }
}

// ---------------- BK=64 swizzled MFMA GEMM: C[M,N] = A[M,K] @ B[N,K]^T ----------------
template<int TN, bool DO_RES, bool OUT_BF16>
__global__ __launch_bounds__(256) void gemm64_kernel(const bf16_t* __restrict__ A,
    const bf16_t* __restrict__ Bw, const float* __restrict__ resid,
    const float* __restrict__ rs_row, void* __restrict__ Cout, int N, int K) {
  __shared__ bf16_t As[128 * 64];
  __shared__ bf16_t Bs[TN * 64];
  const int tid = threadIdx.x;
  const int lane = tid & 63;
  const int wv = tid >> 6;
  const int l15 = lane & 15;
  const int l4 = lane >> 4;
  constexpr int MF = (TN == 128) ? 4 : 2;
  const int wm = (TN == 128) ? ((wv >> 1) << 6) : (wv << 5);
  const int wn = (TN == 128) ? ((wv & 1) << 6) : 0;
  const int tm = blockIdx.x << 7;
  const int tn = blockIdx.y * TN;

  floatx4 acc[MF][4];
#pragma unroll
  for (int i = 0; i < MF; i++)
#pragma unroll
    for (int j = 0; j < 4; j++) acc[i][j] = (floatx4){0.f, 0.f, 0.f, 0.f};

  const int r = tid >> 3;
  const int c8 = tid & 7;
  const int scol = ((c8 ^ (r & 7)) << 3);
  const bf16_t* Ag = A + (long)(tm + r) * K + scol;
  const bf16_t* Bg = Bw + (long)(tn + r) * K + scol;
  const int swz = l15 & 7;

  for (int k0 = 0; k0 < K; k0 += 64) {
#pragma unroll
    for (int q = 0; q < 4; q++)
      gl_lds16(Ag + (long)(q * 32) * K + k0, &As[q * 2048 + tid * 8]);
#pragma unroll
    for (int q = 0; q < TN / 32; q++)
      gl_lds16(Bg + (long)(q * 32) * K + k0, &Bs[q * 2048 + tid * 8]);
    __syncthreads();
#pragma unroll
    for (int kk = 0; kk < 2; kk++) {
      bfrag8 af[MF], bfr[4];
      const int ch = ((kk << 2) | l4) ^ swz;
#pragma unroll
      for (int j = 0; j < 4; j++)
        bfr[j] = *(const bfrag8*)&Bs[(wn + j * 16 + l15) * 64 + ch * 8];
#pragma unroll
      for (int i = 0; i < MF; i++)
        af[i] = *(const bfrag8*)&As[(wm + i * 16 + l15) * 64 + ch * 8];
#pragma unroll
      for (int i = 0; i < MF; i++)
#pragma unroll
        for (int j = 0; j < 4; j++)
          acc[i][j] = __builtin_amdgcn_mfma_f32_16x16x32_bf16(af[i], bfr[j], acc[i][j], 0, 0, 0);
    }
    __syncthreads();
  }
#pragma unroll
  for (int i = 0; i < MF; i++)
#pragma unroll
    for (int j = 0; j < 4; j++)
#pragma unroll
      for (int r2 = 0; r2 < 4; r2++) {
        int row = tm + wm + i * 16 + l4 * 4 + r2;
        int col = tn + wn + j * 16 + l15;
        float v = acc[i][j][r2];
        if (OUT_BF16) {
          ((bf16_t*)Cout)[(long)row * N + col] = __float2bfloat16(v);
        } else {
          if (DO_RES) v = v * rs_row[row] + resid[(long)row * N + col];
          ((float*)Cout)[(long)row * N + col] = v;
        }
      }
}

// ---------------- batched S GEMM: SL[bc][l][s] = Cm[l].Bm[s] (M=N=256,K=128) ----------
__global__ __launch_bounds__(256) void gemm_s_kernel(const bf16_t* __restrict__ Cmh,
                const bf16_t* __restrict__ Bmh, float* __restrict__ SL) {
  __shared__ bf16_t As[128 * 32];
  __shared__ bf16_t Bs[128 * 32];
  const int tid = threadIdx.x;
  const int lane = tid & 63;
  const int wv = tid >> 6;
  const int wm = (wv >> 1) << 6;
  const int wn = (wv & 1) << 6;
  const int bc = blockIdx.z;
  const int tm = blockIdx.x << 7;
  const int tn = blockIdx.y << 7;
  const int l15 = lane & 15;
  const int l4 = lane >> 4;
  floatx4 acc[4][4];
#pragma unroll
  for (int i = 0; i < 4; i++)
#pragma unroll
    for (int j = 0; j < 4; j++) acc[i][j] = (floatx4){0.f, 0.f, 0.f, 0.f};
  const int arow = tid >> 2;
  const int acol = (tid & 3) << 3;
  const bf16_t* Ag = Cmh + (long)bc * 256 * DSTATE + (long)(tm + arow) * DSTATE + acol;
  const bf16_t* Bg = Bmh + (long)bc * 256 * DSTATE + (long)(tn + arow) * DSTATE + acol;
  const long k64 = (long)64 * DSTATE;
  for (int k0 = 0; k0 < DSTATE; k0 += 32) {
    gl_lds16(Ag + k0, &As[tid * 8]);
    gl_lds16(Ag + k64 + k0, &As[2048 + tid * 8]);
    gl_lds16(Bg + k0, &Bs[tid * 8]);
    gl_lds16(Bg + k64 + k0, &Bs[2048 + tid * 8]);
    __syncthreads();
    bfrag8 af[4], bfr[4];
#pragma unroll
    for (int i = 0; i < 4; i++)
      af[i] = *(const bfrag8*)&As[(wm + i * 16 + l15) * 32 + l4 * 8];
#pragma unroll
    for (int j = 0; j < 4; j++)
      bfr[j] = *(const bfrag8*)&Bs[(wn + j * 16 + l15) * 32 + l4 * 8];
#pragma unroll
    for (int i = 0; i < 4; i++)
#pragma unroll
      for (int j = 0; j < 4; j++)
        acc[i][j] = __builtin_amdgcn_mfma_f32_16x16x32_bf16(af[i], bfr[j], acc[i][j], 0, 0, 0);
    __syncthreads();
  }
  float* Cb = SL + (long)bc * 65536;
#pragma unroll
  for (int i = 0; i < 4; i++)
#pragma unroll
    for (int j = 0; j < 4; j++)
#pragma unroll
      for (int r = 0; r < 4; r++)
        Cb[(long)(tm + wm + i * 16 + l4 * 4 + r) * 256 + tn + wn + j * 16 + l15] = acc[i][j][r];
}

// ---------------- vectorized conv4 + bias + silu: 8 channels x 4 rows / thread -------
__global__ __launch_bounds__(256) void conv4_kernel(const bf16_t* __restrict__ zxh,
    const float* __restrict__ cw, const float* __restrict__ cb,
    bf16_t* __restrict__ xhb, bf16_t* __restrict__ Bmh, bf16_t* __restrict__ Cmh) {
  int g = blockIdx.x * 256 + threadIdx.x;    // < 1024*288
  int cg = g % 288;
  int blt = g / 288;
  int c0 = cg * 8;
  long bl0 = (long)blt * 4;
  int l0 = (int)(bl0 & (LL - 1));
  const bf16_t* base = zxh + bl0 * NPAD + DI + c0;
  float rv[7][8];
#pragma unroll
  for (int j = 0; j < 7; j++) {
    int dj = j - 3;
    if (l0 + dj >= 0) {
      uint4 u = *(const uint4*)(base + (long)dj * NPAD);
      unp8(u, rv[j]);
    } else {
#pragma unroll
      for (int q = 0; q < 8; q++) rv[j][q] = 0.f;
    }
  }
  float4 wq[8];
#pragma unroll
  for (int q = 0; q < 8; q++) wq[q] = ((const float4*)cw)[c0 + q];
  float bias[8];
  *(float4*)&bias[0] = *(const float4*)(cb + c0);
  *(float4*)&bias[4] = *(const float4*)(cb + c0 + 4);
#pragma unroll
  for (int i = 0; i < 4; i++) {
    unsigned o[4];
#pragma unroll
    for (int q2 = 0; q2 < 4; q2++) {
      float rr[2];
#pragma unroll
      for (int e = 0; e < 2; e++) {
        int q = q2 * 2 + e;
        float a = bias[q] + wq[q].x * rv[i][q] + wq[q].y * rv[i + 1][q]
                + wq[q].z * rv[i + 2][q] + wq[q].w * rv[i + 3][q];
        rr[e] = a / (1.f + __expf(-a));
      }
      o[q2] = pack_bf16_rn(rr[0], rr[1]);
    }
    uint4 ov = make_uint4(o[0], o[1], o[2], o[3]);
    long bl = bl0 + i;
    if (c0 < DI)               *(uint4*)(xhb + bl * DI + c0) = ov;
    else if (c0 < DI + DSTATE) *(uint4*)(Bmh + bl * DSTATE + (c0 - DI)) = ov;
    else                       *(uint4*)(Cmh + bl * DSTATE + (c0 - DI - DSTATE)) = ov;
  }
}

// ------- fused: softplus(dt)+cumsum (per b,c,h) + transposes xdT/xdTe; BmT branch ----
__global__ __launch_bounds__(256) void xdt_kernel(const bf16_t* __restrict__ xhb,
    const bf16_t* __restrict__ Bmh, const bf16_t* __restrict__ zxh,
    const float* __restrict__ A_log, const float* __restrict__ dtb,
    float* __restrict__ acs, float* __restrict__ ctot,
    bf16_t* __restrict__ xdT, bf16_t* __restrict__ xdTe, bf16_t* __restrict__ BmT) {
  __shared__ unsigned short Tb[9216];   // 2x 64x72 (xdt) or 1x 128x72 (bmt)
  __shared__ float acsL[256];
  __shared__ float dtsL[256];
  __shared__ float wsum[4];
  int blk = blockIdx.x;
  int t = threadIdx.x;
  if (blk < 512) {
    int h = blk & 31, bc = blk >> 5;
    {   // ---- fused softplus + log2-scaled cumsum ----
      int lane = t & 63, w = t >> 6;
      float Ah = -__expf(A_log[h]) * LOG2E;
      int gl = bc * 256 + t;
      float vv = __bfloat162float(zxh[(long)gl * NPAD + (NPROJ - 32) + h]) + dtb[h];
      float sp = fmaxf(vv, 0.f) + log1pf(__expf(-fabsf(vv)));
      float a = sp * Ah;
#pragma unroll
      for (int off = 1; off < 64; off <<= 1) {
        float v = __shfl_up(a, off, 64);
        if (lane >= off) a += v;
      }
      if (lane == 63) wsum[w] = a;
      __syncthreads();
      float base = 0.f;
      for (int i = 0; i < 4; i++) base += (i < w) ? wsum[i] : 0.f;
      a += base;
      acsL[t] = a;
      dtsL[t] = sp;
      acs[blk * 256 + t] = a;
      if (t == 255) ctot[blk] = a;
      __syncthreads();
    }
    float atot = acsL[255];
    unsigned short* T1 = Tb;
    unsigned short* T2 = Tb + 4608;
    int l_loc = t >> 2, pg = t & 3;
    for (int lt = 0; lt < 4; lt++) {
      int ll = lt * 64 + l_loc;
      int gl = bc * 256 + ll;
      float w1 = dtsL[ll];
      float w2 = w1 * exp2f(atot - acsL[ll]);
      const uint4* src = (const uint4*)(xhb + (long)gl * DI + h * HD + pg * 16);
      uint4 u0 = src[0], u1 = src[1];
      float v[16];
      unp8(u0, v); unp8(u1, v + 8);
      __syncthreads();
#pragma unroll
      for (int q = 0; q < 16; q++) {
        T1[(pg * 16 + q) * 72 + l_loc] = bf16u(v[q] * w1);
        T2[(pg * 16 + q) * 72 + l_loc] = bf16u(v[q] * w2);
      }
      __syncthreads();
      long orow = ((long)blk * 64 + l_loc) * 256 + lt * 64 + pg * 16;
      *(uint4*)(xdT + orow)      = *(uint4*)&T1[l_loc * 72 + pg * 16];
      *(uint4*)(xdT + orow + 8)  = *(uint4*)&T1[l_loc * 72 + pg * 16 + 8];
      *(uint4*)(xdTe + orow)     = *(uint4*)&T2[l_loc * 72 + pg * 16];
      *(uint4*)(xdTe + orow + 8) = *(uint4*)&T2[l_loc * 72 + pg * 16 + 8];
    }
  } else {
    unsigned short* T = Tb;
    int bc = blk - 512;
    int l_loc = t >> 2, ng = t & 3;
    for (int lt = 0; lt < 4; lt++) {
      int gl = bc * 256 + lt * 64 + l_loc;
      const uint4* src = (const uint4*)(Bmh + (long)gl * DSTATE + ng * 32);
      uint4 u[4];
#pragma unroll
      for (int q = 0; q < 4; q++) u[q] = src[q];
      __syncthreads();
      const unsigned short* us = (const unsigned short*)u;
#pragma unroll
      for (int e = 0; e < 32; e++)
        T[(ng * 32 + e) * 72 + l_loc] = us[e];
      __syncthreads();
      int n = t >> 1, lg2 = t & 1;
      long orow = ((long)bc * 128 + n) * 256 + lt * 64 + lg2 * 32;
#pragma unroll
      for (int q = 0; q < 4; q++)
        *(uint4*)(BmT + orow + q * 8) = *(uint4*)&T[n * 72 + lg2 * 32 + q * 8];
    }
  }
}

// ---------------- chunk states: pure register MFMA GEMM (no LDS, no barriers) --------
__global__ __launch_bounds__(256) void states3_kernel(const bf16_t* __restrict__ xdTe,
    const bf16_t* __restrict__ BmT, bf16_t* __restrict__ states) {
  int blk = blockIdx.x;    // bc*32+h
  int bc = blk >> 5;
  int t = threadIdx.x, lane = t & 63, wv = t >> 6;
  int l15 = lane & 15, l4 = lane >> 4;
  floatx4 acc[2][4];
#pragma unroll
  for (int i = 0; i < 2; i++)
#pragma unroll
    for (int j = 0; j < 4; j++) acc[i][j] = (floatx4){0.f, 0.f, 0.f, 0.f};
  const bf16_t* arow = BmT + (long)bc * 128 * 256;
  const bf16_t* brow = xdTe + (long)blk * 64 * 256;
#pragma unroll
  for (int kt = 0; kt < 8; kt++) {
    bfrag8 af[2], bfr[4];
#pragma unroll
    for (int i = 0; i < 2; i++)
      af[i] = *(const bfrag8*)(arow + (long)(wv * 32 + i * 16 + l15) * 256 + kt * 32 + l4 * 8);
#pragma unroll
    for (int j = 0; j < 4; j++)
      bfr[j] = *(const bfrag8*)(brow + (long)(j * 16 + l15) * 256 + kt * 32 + l4 * 8);
#pragma unroll
    for (int i = 0; i < 2; i++)
#pragma unroll
      for (int j = 0; j < 4; j++)
        acc[i][j] = __builtin_amdgcn_mfma_f32_16x16x32_bf16(af[i], bfr[j], acc[i][j], 0, 0, 0);
  }
#pragma unroll
  for (int i = 0; i < 2; i++)
#pragma unroll
    for (int j = 0; j < 4; j++) {
      int n_base = wv * 32 + i * 16 + l4 * 4;
      int p = j * 16 + l15;
      unsigned lo = pack_bf16_rn(acc[i][j][0], acc[i][j][1]);
      unsigned hi = pack_bf16_rn(acc[i][j][2], acc[i][j][3]);
      *(uint2*)(states + (long)blk * 8192 + p * 128 + n_base) = make_uint2(lo, hi);
    }
}

// ---------------- inter-chunk scan -> init states (bf16 in/out; ctot log2-scaled) -----
__global__ void scan_kernel(const bf16_t* __restrict__ states, const float* __restrict__ ctot,
                            bf16_t* __restrict__ initsb) {
  int id = blockIdx.x * 256 + threadIdx.x;   // < 2*32*8192
  int pn = id & 8191;
  int bh = id >> 13;
  int b = bh >> 5, h = bh & 31;
  float S = 0.f;
#pragma unroll
  for (int c = 0; c < 8; c++) {
    int blk = (b * 8 + c) * 32 + h;
    initsb[(long)blk * 8192 + pn] = __float2bfloat16(S);
    S = exp2f(ctot[blk]) * S + __bfloat162float(states[(long)blk * 8192 + pn]);
  }
}

// ------- MFMA Y: register A-frags (P computed in-layout), no per-tile barriers -------
// 512 threads: waves 0-3 rows 0-127 (mh=0), waves 4-7 rows 128-255 (mh=1).
__global__ __launch_bounds__(512, 4) void yk4_kernel(const float* __restrict__ SL,
     const bf16_t* __restrict__ Cmh, const bf16_t* __restrict__ xhb,
     const bf16_t* __restrict__ zxh, const float* __restrict__ acs,
     const bf16_t* __restrict__ initsb, const bf16_t* __restrict__ xdT,
     const float* __restrict__ Dp, bf16_t* __restrict__ yg, float* __restrict__ ssqp) {
  int bi = blockIdx.x;                       // XCD-swizzled mapping
  int bc = (bi & 7) * 2 + ((bi >> 3) & 1);
  int h = bi >> 4;
  int ablk = bc * 32 + h;
  int t = threadIdx.x;
  int wv = t >> 6;
  int mh = wv >> 2, wsub = wv & 3;
  int lane = t & 63;
  int l15 = lane & 15, l4 = lane >> 4;

  __shared__ float acsS[256];
  __shared__ __align__(16) char bbuf[49152];   // union: {xds 32KB + ins 16KB} / Yt 33.8KB
  bf16_t* xds = (bf16_t*)bbuf;                 // [64][256] swizzled
  bf16_t* ins = (bf16_t*)(bbuf + 32768);       // [64][128] swizzled
  float* Yt = (float*)bbuf;                    // [128][66]

  {
    const bf16_t* xrow_g = xdT + (long)ablk * 64 * 256;
#pragma unroll
    for (int it = 0; it < 4; it++) {
      int sl = it * 512 + t;
      int p = sl >> 5, s = sl & 31;
      int c = (s & 24) | ((s & 7) ^ (p & 7));
      gl_lds16(xrow_g + p * 256 + c * 8, &xds[sl * 8]);
    }
    const bf16_t* irow_g = initsb + (long)ablk * 8192;
#pragma unroll
    for (int it = 0; it < 2; it++) {
      int sl = it * 512 + t;
      int p = sl >> 4, s = sl & 15;
      int c = (s & 8) | ((s & 7) ^ (p & 7));
      gl_lds16(irow_g + p * 128 + c * 8, &ins[sl * 8]);
    }
  }
  if (t < 256) acsS[t] = acs[ablk * 256 + t];
  __syncthreads();

  const int rowbase = bc * 256;
  const int l0 = mh * 128 + wsub * 32 + l15;
  const int l1 = l0 + 16;
  const float al0 = acsS[l0], al1 = acsS[l1];
  const float eA0 = exp2f(al0), eA1 = exp2f(al1);
  const float* SL0 = SL + (long)bc * 65536 + (long)l0 * 256;
  const float* SL1 = SL + (long)bc * 65536 + (long)l1 * 256;

  floatx4 acc[2][4];
#pragma unroll
  for (int i = 0; i < 2; i++)
#pragma unroll
    for (int j = 0; j < 4; j++) acc[i][j] = (floatx4){0.f, 0.f, 0.f, 0.f};

  const int nkd = (mh + 1) * 4;
  for (int kt = 0; kt < nkd; kt++) {           // diagonal tiles, no barriers
    int sbase = kt * 32 + l4 * 8;
    float as[8];
    *(float4*)&as[0] = *(const float4*)&acsS[sbase];
    *(float4*)&as[4] = *(const float4*)&acsS[sbase + 4];
    float sv0[8], sv1[8];
    *(float4*)&sv0[0] = *(const float4*)(SL0 + sbase);
    *(float4*)&sv0[4] = *(const float4*)(SL0 + sbase + 4);
    *(float4*)&sv1[0] = *(const float4*)(SL1 + sbase);
    *(float4*)&sv1[4] = *(const float4*)(SL1 + sbase + 4);
    fragu af0, af1;
#pragma unroll
    for (int q2 = 0; q2 < 4; q2++) {
      float p00, p01, p10, p11;
      {
        int s = sbase + q2 * 2;
        float d0 = al0 - as[q2 * 2], d1 = al0 - as[q2 * 2 + 1];
        p00 = (s <= l0) ? sv0[q2 * 2] * exp2f(fminf(d0, 0.f)) : 0.f;
        p01 = (s + 1 <= l0) ? sv0[q2 * 2 + 1] * exp2f(fminf(d1, 0.f)) : 0.f;
        float e0 = al1 - as[q2 * 2], e1 = al1 - as[q2 * 2 + 1];
        p10 = (s <= l1) ? sv1[q2 * 2] * exp2f(fminf(e0, 0.f)) : 0.f;
        p11 = (s + 1 <= l1) ? sv1[q2 * 2 + 1] * exp2f(fminf(e1, 0.f)) : 0.f;
      }
      af0.u[q2] = pack_bf16_rn(p00, p01);
      af1.u[q2] = pack_bf16_rn(p10, p11);
    }
    bfrag8 bfr[4];
    int ch = kt * 4 + l4;
#pragma unroll
    for (int j = 0; j < 4; j++) {
      int p = j * 16 + l15;
      int sw = (ch & 24) | ((ch & 7) ^ (p & 7));
      bfr[j] = *(const bfrag8*)&xds[(p * 32 + sw) * 8];
    }
#pragma unroll
    for (int j = 0; j < 4; j++) {
      acc[0][j] = __builtin_amdgcn_mfma_f32_16x16x32_bf16(af0.f, bfr[j], acc[0][j], 0, 0, 0);
      acc[1][j] = __builtin_amdgcn_mfma_f32_16x16x32_bf16(af1.f, bfr[j], acc[1][j], 0, 0, 0);
    }
  }
#pragma unroll
  for (int kt = 0; kt < 4; kt++) {             // off-diagonal (Y_off) tiles
    int n0 = kt * 32 + l4 * 8;
    uint4 c0 = *(const uint4*)(Cmh + (long)(rowbase + l0) * DSTATE + n0);
    uint4 c1 = *(const uint4*)(Cmh + (long)(rowbase + l1) * DSTATE + n0);
    float cv0[8], cv1[8];
    unp8(c0, cv0); unp8(c1, cv1);
    fragu af0, af1;
#pragma unroll
    for (int q2 = 0; q2 < 4; q2++) {
      af0.u[q2] = pack_bf16_rn(cv0[q2 * 2] * eA0, cv0[q2 * 2 + 1] * eA0);
      af1.u[q2] = pack_bf16_rn(cv1[q2 * 2] * eA1, cv1[q2 * 2 + 1] * eA1);
    }
    bfrag8 bfr[4];
    int ch = kt * 4 + l4;
#pragma unroll
    for (int j = 0; j < 4; j++) {
      int p = j * 16 + l15;
      int sw = (ch & 8) | ((ch & 7) ^ (p & 7));
      bfr[j] = *(const bfrag8*)&ins[(p * 16 + sw) * 8];
    }
#pragma unroll
    for (int j = 0; j < 4; j++) {
      acc[0][j] = __builtin_amdgcn_mfma_f32_16x16x32_bf16(af0.f, bfr[j], acc[0][j], 0, 0, 0);
      acc[1][j] = __builtin_amdgcn_mfma_f32_16x16x32_bf16(af1.f, bfr[j], acc[1][j], 0, 0, 0);
    }
  }
  // ---- two-pass epilogue through Yt (union over xds/ins) ----
  float Dh = Dp[h];
#pragma unroll
  for (int pass = 0; pass < 2; pass++) {
    __syncthreads();
    if (mh == pass) {
#pragma unroll
      for (int i = 0; i < 2; i++)
#pragma unroll
        for (int j = 0; j < 4; j++)
#pragma unroll
          for (int r = 0; r < 4; r++)
            Yt[(wsub * 32 + i * 16 + l4 * 4 + r) * 66 + j * 16 + l15] = acc[i][j][r];
    }
    __syncthreads();
    {
      int row_l = t >> 2;
      int chc = (t & 3) * 16;
      long rowg = rowbase + pass * 128 + row_l;
      float ss = 0.f;
#pragma unroll
      for (int it = 0; it < 2; it++) {
        int c = chc + it * 8;
        float4 y0 = *(const float4*)&Yt[row_l * 66 + c];
        float4 y1 = *(const float4*)&Yt[row_l * 66 + c + 4];
        uint4 ux = *(const uint4*)(xhb + rowg * DI + h * HD + c);
        uint4 uz = *(const uint4*)(zxh + rowg * NPAD + h * HD + c);
        float xv[8], zv[8];
        unp8(ux, xv); unp8(uz, zv);
        float yv[8] = {y0.x, y0.y, y0.z, y0.w, y1.x, y1.y, y1.z, y1.w};
        unsigned o[4];
#pragma unroll
        for (int q = 0; q < 4; q++) {
          float v0 = (yv[q * 2 + 0] + Dh * xv[q * 2 + 0]) *
                     (zv[q * 2 + 0] / (1.f + __expf(-zv[q * 2 + 0])));
          float v1 = (yv[q * 2 + 1] + Dh * xv[q * 2 + 1]) *
                     (zv[q * 2 + 1] / (1.f + __expf(-zv[q * 2 + 1])));
          ss += v0 * v0 + v1 * v1;
          o[q] = pack_bf16_rn(v0, v1);
        }
        *(uint4*)(yg + rowg * DI + h * HD + c) = make_uint4(o[0], o[1], o[2], o[3]);
      }
      ss += __shfl_xor(ss, 1, 64);
      ss += __shfl_xor(ss, 2, 64);
      if ((t & 3) == 0) ssqp[rowg * 32 + h] = ss;
    }
  }
}

// ---------------- per-row 1/rms from ssq partials ----------------
__global__ void rsred_kernel(const float* __restrict__ ssqp, float* __restrict__ rs) {
  int row = blockIdx.x * 256 + threadIdx.x;   // < MR
  const float4* p = (const float4*)(ssqp + row * 32);
  float s = 0.f;
#pragma unroll
  for (int q = 0; q < 8; q++) {
    float4 v = p[q];
    s += v.x + v.y + v.z + v.w;
  }
  rs[row] = rsqrtf(s * (1.f / DI) + EPSF);
}

extern "C" void kernel_launch(void* const* d_in, const int* in_sizes, int n_in,
                              void* d_out, int out_size, void* d_ws, size_t ws_size,
                              hipStream_t stream) {
  const float* x    = (const float*)d_in[0];
  const float* nw   = (const float*)d_in[1];
  const float* w1   = (const float*)d_in[2];
  const float* cw   = (const float*)d_in[3];
  const float* cb   = (const float*)d_in[4];
  const float* dtb  = (const float*)d_in[5];
  const float* alog = (const float*)d_in[6];
  const float* Dp   = (const float*)d_in[7];
  const float* gw   = (const float*)d_in[8];
  const float* w2   = (const float*)d_in[9];
  float* out = (float*)d_out;

  char* ws = (char*)d_ws;
  size_t off = 0;
  auto alloc = [&](size_t bytes) -> void* {
    void* p = ws + off;
    off += (bytes + 255) & ~(size_t)255;
    return p;
  };
  bf16_t* ub     = (bf16_t*)alloc((size_t)MR * DM * 2);
  bf16_t* w1b    = (bf16_t*)alloc((size_t)NPAD * DM * 2);
  bf16_t* w2b    = (bf16_t*)alloc((size_t)DM * DI * 2);
  bf16_t* zxh    = (bf16_t*)alloc((size_t)MR * NPAD * 2);
  bf16_t* xhb    = (bf16_t*)alloc((size_t)MR * DI * 2);
  bf16_t* Bmh    = (bf16_t*)alloc((size_t)MR * DSTATE * 2);
  bf16_t* Cmh    = (bf16_t*)alloc((size_t)MR * DSTATE * 2);
  float* SL      = (float*)alloc((size_t)16 * 256 * 256 * 4);
  float* acs     = (float*)alloc((size_t)512 * 256 * 4);
  float* ctot    = (float*)alloc((size_t)512 * 4);
  bf16_t* states = (bf16_t*)alloc((size_t)512 * 8192 * 2);
  bf16_t* initsb = (bf16_t*)alloc((size_t)512 * 8192 * 2);
  bf16_t* xdT    = (bf16_t*)alloc((size_t)512 * 64 * 256 * 2);
  bf16_t* xdTe   = (bf16_t*)alloc((size_t)512 * 64 * 256 * 2);
  bf16_t* BmT    = (bf16_t*)alloc((size_t)16 * 128 * 256 * 2);
  bf16_t* yg     = (bf16_t*)alloc((size_t)MR * DI * 2);
  float* ssqp    = (float*)alloc((size_t)MR * NHD * 4);
  float* rs      = (float*)alloc((size_t)MR * 4);
  if (off > ws_size) return;

  rms1_kernel<<<MR, 256, 0, stream>>>(x, nw, ub);
  cvtw_kernel<<<(W1CNT + W2CNT) / 256, 256, 0, stream>>>(w1, w2, gw, w1b, w2b);
  gemm64_kernel<128, false, true><<<dim3(MR / 128, NPAD / 128), 256, 0, stream>>>(
      ub, w1b, nullptr, nullptr, zxh, NPAD, DM);
  conv4_kernel<<<(1024 * 288) / 256, 256, 0, stream>>>(zxh, cw, cb, xhb, Bmh, Cmh);
  xdt_kernel<<<528, 256, 0, stream>>>(xhb, Bmh, zxh, alog, dtb, acs, ctot, xdT, xdTe, BmT);
  gemm_s_kernel<<<dim3(2, 2, 16), 256, 0, stream>>>(Cmh, Bmh, SL);
  states3_kernel<<<512, 256, 0, stream>>>(xdTe, BmT, states);
  scan_kernel<<<(2 * 32 * 8192) / 256, 256, 0, stream>>>(states, ctot, initsb);
  yk4_kernel<<<512, 512, 0, stream>>>(SL, Cmh, xhb, zxh, acs, initsb, xdT, Dp, yg, ssqp);
  rsred_kernel<<<MR / 256, 256, 0, stream>>>(ssqp, rs);
  gemm64_kernel<64, true, false><<<dim3(MR / 128, DM / 64), 256, 0, stream>>>(
      yg, w2b, x, rs, out, DM, DI);
}